// Round 3
// baseline (592.313 us; speedup 1.0000x reference)
//
#include <hip/hip_runtime.h>
#include <hip/hip_bf16.h>

#define HW 784
#define WD 28
#define NPX (56 * 784)         // 43904 deform/offconv pixels
#define PXBLK 172              // ceil(43904/256)
#define PLANE (56 * 64 * 784)  // 2,809,856 floats: one full plane
#define PADPX 1024             // 32x32 padded spatial (halo 2)

using short8 = __attribute__((ext_vector_type(8))) short;
using f32x4  = __attribute__((ext_vector_type(4))) float;

// ---------------------------------------------------------------------------
// Prep: fold BN into transposed weight layouts + MFMA-fragment-order bf16
// weights for the offset convs and the fused deform GEMM.
// wBs[tap][chunk][ntile][lane][j] (bf16): B[k=chunk*32+(lane>>4)*8+j][oc=ntile*16+(lane&15)]
// wBd: same frag layout, 34 taps (9 from def3_w, 25 from def5_w), NT=4.
// ---------------------------------------------------------------------------
__global__ void k_prep(
    const float* __restrict__ w_down, const float* __restrict__ b_down,
    const float* __restrict__ bn1_g, const float* __restrict__ bn1_b,
    const float* __restrict__ bn1_m, const float* __restrict__ bn1_v,
    const float* __restrict__ tconv_w, const float* __restrict__ tconv_b,
    const float* __restrict__ bnt_g, const float* __restrict__ bnt_b,
    const float* __restrict__ bnt_m, const float* __restrict__ bnt_v,
    const float* __restrict__ off3_w, const float* __restrict__ def3_w,
    const float* __restrict__ off5_w, const float* __restrict__ def5_w,
    const float* __restrict__ conv1_w, const float* __restrict__ conv1_b,
    const float* __restrict__ bn3_g, const float* __restrict__ bn3_b,
    const float* __restrict__ bn3_m, const float* __restrict__ bn3_v,
    const float* __restrict__ conv_w, const float* __restrict__ conv_b,
    const float* __restrict__ bn2_g, const float* __restrict__ bn2_b,
    const float* __restrict__ bn2_m, const float* __restrict__ bn2_v,
    float* __restrict__ wdownT, float* __restrict__ bias1,
    float* __restrict__ wtT, float* __restrict__ AtBt,
    __hip_bfloat16* __restrict__ wBs3, __hip_bfloat16* __restrict__ wBs5,
    __hip_bfloat16* __restrict__ wBd,
    float* __restrict__ c1T, float* __restrict__ B3,
    float* __restrict__ gwT, float* __restrict__ Bg)
{
  const int tid = blockIdx.x * blockDim.x + threadIdx.x;
  const int nth = gridDim.x * blockDim.x;
  for (int i = tid; i < 256 * 64; i += nth) {
    int c = i >> 6, cr = i & 63;
    float s = bn1_g[cr] / sqrtf(bn1_v[cr] + 1e-5f);
    wdownT[i] = w_down[cr * 256 + c] * s;
  }
  for (int i = tid; i < 64; i += nth) {
    float s = bn1_g[i] / sqrtf(bn1_v[i] + 1e-5f);
    bias1[i] = (b_down[i] - bn1_m[i]) * s + bn1_b[i];
  }
  for (int i = tid; i < 192 * 9 * 64; i += nth) {
    int cc = i / (9 * 64); int tap = (i / 64) % 9; int o = i & 63;
    int dt = cc >> 6, c = cc & 63;
    wtT[i] = tconv_w[o * 1728 + c * 27 + dt * 9 + tap];
  }
  for (int i = tid; i < 64; i += nth) {
    float s = bnt_g[i] / sqrtf(bnt_v[i] + 1e-5f);
    AtBt[i] = s * 0.125f;
    AtBt[64 + i] = (tconv_b[i] - bnt_m[i]) * s + bnt_b[i];
  }
  // off3 MFMA B-frags: K2=9, NT=2 (ocpad 32). total 9*2*2*512 = 18432
  for (int i = tid; i < 9 * 2 * 2 * 512; i += nth) {
    int j = i & 7; int lane = (i >> 3) & 63;
    int rest = i >> 9; int nt = rest % 2; rest /= 2;
    int chunk = rest & 1; int tap = rest >> 1;
    int c = chunk * 32 + ((lane >> 4) << 3) + j;
    int oc = nt * 16 + (lane & 15);
    float v = (oc < 18) ? off3_w[oc * 576 + c * 9 + tap] : 0.f;
    wBs3[i] = __float2bfloat16(v);
  }
  // off5 MFMA B-frags: K2=25, NT=4 (ocpad 64). total 25*2*4*512 = 102400
  for (int i = tid; i < 25 * 2 * 4 * 512; i += nth) {
    int j = i & 7; int lane = (i >> 3) & 63;
    int rest = i >> 9; int nt = rest % 4; rest /= 4;
    int chunk = rest & 1; int tap = rest >> 1;
    int c = chunk * 32 + ((lane >> 4) << 3) + j;
    int oc = nt * 16 + (lane & 15);
    float v = (oc < 50) ? off5_w[oc * 1600 + c * 25 + tap] : 0.f;
    wBs5[i] = __float2bfloat16(v);
  }
  // fused deform B-frags: 34 taps (0..8 = def3, 9..33 = def5), NT=4 (oc=64)
  for (int i = tid; i < 34 * 2 * 4 * 512; i += nth) {
    int j = i & 7; int lane = (i >> 3) & 63;
    int rest = i >> 9; int nt = rest & 3; rest >>= 2;
    int chunk = rest & 1; int tap = rest >> 1;
    int c = chunk * 32 + ((lane >> 4) << 3) + j;
    int oc = nt * 16 + (lane & 15);
    float v = (tap < 9) ? def3_w[oc * 576 + c * 9 + tap]
                        : def5_w[oc * 1600 + c * 25 + (tap - 9)];
    wBd[i] = __float2bfloat16(v);
  }
  for (int i = tid; i < 64 * 64; i += nth) {
    int c = i >> 6, o = i & 63;
    float s = bn3_g[o] / sqrtf(bn3_v[o] + 1e-5f);
    c1T[i] = conv1_w[o * 64 + c] * s;
  }
  for (int i = tid; i < 64; i += nth) {
    float s = bn3_g[i] / sqrtf(bn3_v[i] + 1e-5f);
    B3[i] = (conv1_b[i] - bn3_m[i]) * s + bn3_b[i];
  }
  for (int i = tid; i < 64 * 256; i += nth) {
    int c = i >> 8, co = i & 255;
    float s = bn2_g[co] / sqrtf(bn2_v[co] + 1e-5f);
    gwT[i] = conv_w[co * 64 + c] * s;
  }
  for (int i = tid; i < 256; i += nth) {
    float s = bn2_g[i] / sqrtf(bn2_v[i] + 1e-5f);
    Bg[i] = (conv_b[i] - bn2_m[i]) * s + bn2_b[i];
  }
}

// ---------------------------------------------------------------------------
// Zero the padded bf16 image (halo must be 0 every call; ws is re-poisoned).
// 56*1024*64 bf16 = 458752 float4.
// ---------------------------------------------------------------------------
__global__ void k_zerob(float4* __restrict__ p)
{
  p[blockIdx.x * 256 + threadIdx.x] = make_float4(0.f, 0.f, 0.f, 0.f);
}

// ---------------------------------------------------------------------------
// 1x1 down conv (256->64) + BN fold. px-flat grid (196, o-split 2).
// ---------------------------------------------------------------------------
__global__ __launch_bounds__(256) void k_down(
    const float* __restrict__ x, const float* __restrict__ wdownT,
    const float* __restrict__ bias1, float* __restrict__ out)
{
  __shared__ float wl[256 * 32];            // 32 KB
  const int tid = threadIdx.x;
  const int o0 = blockIdx.y * 32;
  for (int i = tid; i < 2048; i += 256) {
    int c = i >> 3, q = i & 7;
    ((float4*)wl)[i] = *(const float4*)(wdownT + c * 64 + o0 + q * 4);
  }
  __syncthreads();
  const int gpx = blockIdx.x * 256 + tid;   // < 50176 exact
  const int f = gpx / HW, px = gpx % HW;
  const float* xp = x + (size_t)f * 256 * HW + px;
  float acc[32];
#pragma unroll
  for (int j = 0; j < 32; j++) acc[j] = 0.f;
#pragma unroll 4
  for (int c = 0; c < 256; c++) {
    float xv = xp[c * HW];
    const float* wr = &wl[c * 32];
#pragma unroll
    for (int j = 0; j < 32; j++) acc[j] += xv * wr[j];
  }
  float* op = out + (size_t)f * 64 * HW + px;
#pragma unroll
  for (int j = 0; j < 32; j++) op[(o0 + j) * HW] = acc[j] + bias1[o0 + j];
}

// ---------------------------------------------------------------------------
// Transpose post frames to px-major: xT[n][px][c] (f32, for deform) and
// padded bf16 xTbP[n][(py+2)*32+(px+2)][c] (for MFMA offconvs).
// ---------------------------------------------------------------------------
__global__ __launch_bounds__(256) void k_xpose(
    const float* __restrict__ out_b, float* __restrict__ xT,
    __hip_bfloat16* __restrict__ xTbP)
{
  __shared__ float t[64 * 65];
  const int tid = threadIdx.x;
  const int lane = tid & 63, grp = tid >> 6;
  const int n = blockIdx.x;
  const int f = (n / 7) * 8 + (n % 7) + 1;
  const int px0 = blockIdx.y * 64;
  const float* sb = out_b + (size_t)f * 64 * HW;
#pragma unroll
  for (int c = grp; c < 64; c += 4) {
    int px = px0 + lane;
    t[c * 65 + lane] = (px < HW) ? sb[c * HW + px] : 0.f;
  }
  __syncthreads();
#pragma unroll
  for (int r = grp; r < 64; r += 4) {
    int px = px0 + r;
    if (px < HW) {
      float v = t[lane * 65 + r];
      xT[((size_t)n * HW + px) * 64 + lane] = v;
      int py = px / WD, pxc = px % WD;
      xTbP[((size_t)n * PADPX + (py + 2) * 32 + (pxc + 2)) * 64 + lane] =
          __float2bfloat16(v);
    }
  }
}

// ---------------------------------------------------------------------------
// U planes for collapsed temporal conv.
// ---------------------------------------------------------------------------
__global__ void k_makeU(const float* __restrict__ out, float* __restrict__ U)
{
  const int idx = blockIdx.x * 256 + threadIdx.x;
  const int b = idx / (64 * HW);
  const int r = idx % (64 * HW);
  const float* p = out + (size_t)b * 8 * 64 * HW + r;
  float v0 = p[0];
  float s = v0, v = v0;
#pragma unroll
  for (int t = 1; t < 8; t++) { v = p[t * 64 * HW]; s += v; }
  float* u = U + (size_t)b * 192 * HW + r;
  u[0] = s - v;
  u[64 * HW] = s;
  u[128 * HW] = s - v0;
}

// ---------------------------------------------------------------------------
// Collapsed temporal conv: 3x3, 192->64. o-groups of 4 (16 z-blocks).
// ---------------------------------------------------------------------------
__global__ __launch_bounds__(256) void k_tconv(
    const float* __restrict__ U, const float* __restrict__ wtT,
    const float* __restrict__ AtBt, float* __restrict__ t_out)
{
  __shared__ float wl[16 * 9 * 4];
  const int tid = threadIdx.x;
  const int b = blockIdx.x;
  const int px = blockIdx.y * 256 + tid;
  const int o0 = blockIdx.z * 4;
  const bool act = px < HW;
  const int pxe = act ? px : 0;
  const int y = pxe / WD, x = pxe % WD;
  int lin[9]; float msk[9];
#pragma unroll
  for (int t = 0; t < 9; t++) {
    int iy = y + t / 3 - 1, ix = x + t % 3 - 1;
    bool ok = iy >= 0 && iy < WD && ix >= 0 && ix < WD;
    lin[t] = min(max(iy, 0), WD - 1) * WD + min(max(ix, 0), WD - 1);
    msk[t] = ok ? 1.f : 0.f;
  }
  float acc[4];
#pragma unroll
  for (int j = 0; j < 4; j++) acc[j] = 0.f;
  const float* ub = U + (size_t)b * 192 * HW;
  for (int ccb = 0; ccb < 12; ccb++) {
    __syncthreads();
    for (int i = tid; i < 576; i += 256) {
      int ccL = i / 36; int rr = i % 36; int tap = rr >> 2; int j = rr & 3;
      wl[i] = wtT[((ccb * 16 + ccL) * 9 + tap) * 64 + o0 + j];
    }
    __syncthreads();
    for (int ccL = 0; ccL < 16; ccL++) {
      const float* p = ub + (ccb * 16 + ccL) * HW;
      float v[9];
#pragma unroll
      for (int t = 0; t < 9; t++) v[t] = p[lin[t]] * msk[t];
      const float* wr = &wl[ccL * 36];
#pragma unroll
      for (int t = 0; t < 9; t++)
#pragma unroll
        for (int j = 0; j < 4; j++) acc[j] += v[t] * wr[t * 4 + j];
    }
  }
  if (act) {
#pragma unroll
    for (int j = 0; j < 4; j++) {
      int o = o0 + j;
      t_out[(size_t)(b * 64 + o) * HW + px] = acc[j] * AtBt[o] + AtBt[64 + o];
    }
  }
}

// ---------------------------------------------------------------------------
// Offset convs as implicit-GEMM bf16 MFMA (16x16x32).
// ---------------------------------------------------------------------------
template <int KS, int PAD, int OC, int NT, int TAPBLK>
__global__ __launch_bounds__(256) void k_offconv_mfma(
    const __hip_bfloat16* __restrict__ xTbP,
    const __hip_bfloat16* __restrict__ wBs,
    const float* __restrict__ bias, float* __restrict__ dst)
{
  constexpr int K2 = KS * KS;
  __shared__ short bs[TAPBLK * NT * 1024];   // B frags, 2*NT KB per tap
  __shared__ float ct[NT * 16 * 65];         // C tile [ocpad][px(64)+pad]
  const int tid = threadIdx.x;
  const int w = tid >> 6, lane = tid & 63;
  const int quad = lane >> 4, mrow = lane & 15;
  const int gpx = blockIdx.x * 64 + w * 16 + mrow;   // A-row pixel
  const int n = gpx / HW, px = gpx % HW;
  const int y = px / WD, x = px % WD;
  const short* xb = (const short*)xTbP + ((size_t)n * PADPX) * 64;
  f32x4 acc[NT];
#pragma unroll
  for (int nt = 0; nt < NT; nt++) acc[nt] = (f32x4){0.f, 0.f, 0.f, 0.f};

  for (int tb = 0; tb < K2; tb += TAPBLK) {
    __syncthreads();
    for (int i = tid; i < TAPBLK * NT * 128; i += 256)
      ((float4*)bs)[i] = ((const float4*)(wBs + (size_t)tb * NT * 1024))[i];
    __syncthreads();
#pragma unroll
    for (int t2 = 0; t2 < TAPBLK; t2++) {
      int tap = tb + t2;
      if (K2 % TAPBLK != 0 && tap >= K2) break;
      int ty = tap / KS, tx = tap % KS;
      int sp = (y + ty + (2 - PAD)) * 32 + (x + tx + (2 - PAD));
      const short* ap = xb + sp * 64 + quad * 8;
      short8 a0 = *(const short8*)(ap);
      short8 a1 = *(const short8*)(ap + 32);
      const short* bp = bs + t2 * NT * 1024;
#pragma unroll
      for (int nt = 0; nt < NT; nt++) {
        short8 b0 = *(const short8*)(bp + nt * 512 + lane * 8);
        acc[nt] = __builtin_amdgcn_mfma_f32_16x16x32_bf16(a0, b0, acc[nt], 0, 0, 0);
      }
#pragma unroll
      for (int nt = 0; nt < NT; nt++) {
        short8 b1 = *(const short8*)(bp + (NT + nt) * 512 + lane * 8);
        acc[nt] = __builtin_amdgcn_mfma_f32_16x16x32_bf16(a1, b1, acc[nt], 0, 0, 0);
      }
    }
  }
  // C/D frag: col(oc) = lane&15, row(px) = quad*4 + reg
  __syncthreads();
#pragma unroll
  for (int nt = 0; nt < NT; nt++) {
    int oc_l = nt * 16 + mrow;
#pragma unroll
    for (int reg = 0; reg < 4; reg++) {
      int pxr = w * 16 + quad * 4 + reg;
      ct[oc_l * 65 + pxr] = acc[nt][reg];
    }
  }
  __syncthreads();
  for (int i = tid; i < OC * 64; i += 256) {
    int oc = i >> 6, p2 = i & 63;
    int g2 = blockIdx.x * 64 + p2;
    int n2 = g2 / HW, px2 = g2 % HW;
    dst[((size_t)n2 * OC + oc) * HW + px2] = ct[oc * 65 + p2] + bias[oc];
  }
}

// ---------------------------------------------------------------------------
// FUSED deformable conv (def3 + def5): direct-to-fragment gather + bf16 MFMA.
// Grid = 2744 blocks x 256 threads (4 waves). Block owns one 16px x 64oc
// tile (784 = 49*16, tile never crosses a frame). TAP-SPLIT: wave w handles
// taps {w, w+4, ...} (9/9/8/8 of 34); all four accumulate partial sums for
// the SAME output tile, reduced once via LDS at the end.
// Key change vs R1: lane = quad*16+row gathers EXACTLY its MFMA A-fragment
// (px = lane&15, channels = quad*8+j and +32) — bilinear result in registers
// IS the fragment; no LDS staging, no swizzle, no per-tap waitcnt chain.
// Corner reads are contiguous 256B runs across the 4 quads (coalesced).
// __launch_bounds__(256,4) caps VGPR at 128 -> 4 waves/SIMD resident.
// ---------------------------------------------------------------------------
__global__ __launch_bounds__(256, 4) void k_deform_mfma(
    const float* __restrict__ xT,
    const float* __restrict__ off3b, const float* __restrict__ off5b,
    const __hip_bfloat16* __restrict__ wBd,
    float* __restrict__ dsum)
{
  __shared__ __align__(16) float fsm[68 * 16];   // 68 offset planes x 16 px
  __shared__ __align__(16) float ct[4][64 * 17]; // per-wave partial C
  const int tid = threadIdx.x;
  const int ws = tid >> 6, lane = tid & 63;
  const int quad = lane >> 4, mrow = lane & 15;
  const int tile = blockIdx.x;
  const int n = tile / 49, px0 = (tile % 49) * 16;
  const int pxg = px0 + mrow;
  const int y_g = pxg / WD, x_g = pxg % WD;
  const float* pt = xT + (size_t)n * HW * 64;

  // stage all 68 offset planes for these 16 px (coalesced 64B runs)
  {
    const float* o3 = off3b + (size_t)n * 18 * HW + px0;
    const float* o5 = off5b + (size_t)n * 50 * HW + px0;
    for (int idx = tid; idx < 68 * 16; idx += 256) {
      int j = idx >> 4, p = idx & 15;
      fsm[idx] = (j < 18) ? o3[j * HW + p] : o5[(j - 18) * HW + p];
    }
  }
  __syncthreads();

  f32x4 acc[4];
#pragma unroll
  for (int nt = 0; nt < 4; nt++) acc[nt] = (f32x4){0.f, 0.f, 0.f, 0.f};

  for (int tap = ws; tap < 34; tap += 4) {
    // B frags for this tap (L2-resident, independent loads)
    const short* bw = (const short*)wBd + (size_t)tap * 4096 + lane * 8;
    short8 bfrag[8];
#pragma unroll
    for (int q = 0; q < 8; q++) bfrag[q] = *(const short8*)(bw + q * 512);

    int kk, ty, tx, PADl, jb;
    if (tap < 9) { kk = tap; ty = kk / 3; tx = kk % 3; PADl = 1; jb = 0; }
    else { kk = tap - 9; ty = kk / 5; tx = kk % 5; PADl = 2; jb = 18; }
    float offy = fsm[(jb + 2 * kk) * 16 + mrow];
    float offx = fsm[(jb + 2 * kk + 1) * 16 + mrow];
    float py = (float)(y_g + ty - PADl) + offy;
    float pxx = (float)(x_g + tx - PADl) + offx;
    float fy = floorf(py), fx = floorf(pxx);
    int y0 = (int)fy, x0 = (int)fx;
    float ly = py - fy, lx = pxx - fx;
    int y1 = y0 + 1, x1 = x0 + 1;
    float vy0 = (y0 >= 0 && y0 < WD) ? 1.f : 0.f;
    float vy1 = (y1 >= 0 && y1 < WD) ? 1.f : 0.f;
    float vx0 = (x0 >= 0 && x0 < WD) ? 1.f : 0.f;
    float vx1 = (x1 >= 0 && x1 < WD) ? 1.f : 0.f;
    float w00 = (1.f - ly) * (1.f - lx) * vy0 * vx0;
    float w01 = (1.f - ly) * lx * vy0 * vx1;
    float w10 = ly * (1.f - lx) * vy1 * vx0;
    float w11 = ly * lx * vy1 * vx1;
    int cy0 = min(max(y0, 0), WD - 1), cy1 = min(max(y1, 0), WD - 1);
    int cx0 = min(max(x0, 0), WD - 1), cx1 = min(max(x1, 0), WD - 1);
    // channel base: this lane's fragment channels = quad*8 + j (+32)
    const float* p00 = pt + (cy0 * WD + cx0) * 64 + quad * 8;
    const float* p01 = pt + (cy0 * WD + cx1) * 64 + quad * 8;
    const float* p10 = pt + (cy1 * WD + cx0) * 64 + quad * 8;
    const float* p11 = pt + (cy1 * WD + cx1) * 64 + quad * 8;
    float g[16];
#pragma unroll
    for (int h = 0; h < 2; h++) {        // h=0: chunk0 (c+0), h=1: chunk1 (c+32)
#pragma unroll
      for (int v4 = 0; v4 < 2; v4++) {
        const int o = h * 32 + v4 * 4;
        float4 a = *(const float4*)(p00 + o);
        float4 b = *(const float4*)(p01 + o);
        float4 c4 = *(const float4*)(p10 + o);
        float4 d = *(const float4*)(p11 + o);
        const int gi = h * 8 + v4 * 4;
        g[gi + 0] = a.x * w00 + b.x * w01 + c4.x * w10 + d.x * w11;
        g[gi + 1] = a.y * w00 + b.y * w01 + c4.y * w10 + d.y * w11;
        g[gi + 2] = a.z * w00 + b.z * w01 + c4.z * w10 + d.z * w11;
        g[gi + 3] = a.w * w00 + b.w * w01 + c4.w * w10 + d.w * w11;
      }
    }
    short8 a0, a1;
#pragma unroll
    for (int j = 0; j < 8; j++) {
      __hip_bfloat16 q0 = __float2bfloat16(g[j]);
      __hip_bfloat16 q1 = __float2bfloat16(g[8 + j]);
      a0[j] = *(short*)&q0;
      a1[j] = *(short*)&q1;
    }
#pragma unroll
    for (int nt = 0; nt < 4; nt++)
      acc[nt] = __builtin_amdgcn_mfma_f32_16x16x32_bf16(a0, bfrag[nt], acc[nt], 0, 0, 0);
#pragma unroll
    for (int nt = 0; nt < 4; nt++)
      acc[nt] = __builtin_amdgcn_mfma_f32_16x16x32_bf16(a1, bfrag[4 + nt], acc[nt], 0, 0, 0);
  }

  // C/D frag: col(oc) = lane&15, row(px) = quad*4 + reg
#pragma unroll
  for (int nt = 0; nt < 4; nt++) {
    int oc_l = nt * 16 + mrow;
#pragma unroll
    for (int reg = 0; reg < 4; reg++)
      ct[ws][oc_l * 17 + quad * 4 + reg] = acc[nt][reg];
  }
  __syncthreads();
  {
    const int oc = tid >> 2, pq = tid & 3;
    float v[4];
#pragma unroll
    for (int r = 0; r < 4; r++) {
      float s = ct[0][oc * 17 + pq * 4 + r];
#pragma unroll
      for (int w2 = 1; w2 < 4; w2++) s += ct[w2][oc * 17 + pq * 4 + r];
      v[r] = s;
    }
    *(float4*)(dsum + ((size_t)n * 64 + oc) * HW + px0 + pq * 4) =
        make_float4(v[0], v[1], v[2], v[3]);
  }
}

// ---------------------------------------------------------------------------
// maxpool 3x3 + 1x1 conv (BN folded) + diff epilogue (dsum holds d3+d5).
// ---------------------------------------------------------------------------
__global__ __launch_bounds__(256) void k_davg_diff(
    const float* __restrict__ frames, const float* __restrict__ c1T,
    const float* __restrict__ B3, float* __restrict__ dsum)
{
  __shared__ float wl[64 * 32];
  const int tid = threadIdx.x;
  const int o0 = blockIdx.y * 32;
  for (int i = tid; i < 512; i += 256) {
    int c = i >> 3, q = i & 7;
    ((float4*)wl)[i] = *(const float4*)(c1T + c * 64 + o0 + q * 4);
  }
  __syncthreads();
  const int gpx = blockIdx.x * 256 + tid;
  const bool act = gpx < NPX;
  const int gpe = act ? gpx : 0;
  const int n = gpe / HW, px = gpe % HW;
  const int b = n / 7, t = n % 7;
  const int fpost = b * 8 + t + 1, fpre = b * 8 + t;
  const int y = px / WD, x = px % WD;
  int lin[9]; bool okm[9];
#pragma unroll
  for (int t2 = 0; t2 < 9; t2++) {
    int iy = y + t2 / 3 - 1, ix = x + t2 % 3 - 1;
    okm[t2] = iy >= 0 && iy < WD && ix >= 0 && ix < WD;
    lin[t2] = min(max(iy, 0), WD - 1) * WD + min(max(ix, 0), WD - 1);
  }
  float acc[32];
#pragma unroll
  for (int j = 0; j < 32; j++) acc[j] = 0.f;
  const float* sb = frames + (size_t)fpost * 64 * HW;
  for (int c = 0; c < 64; c++) {
    const float* p = sb + c * HW;
    float m = -1e30f;
#pragma unroll
    for (int t2 = 0; t2 < 9; t2++) {
      float v = okm[t2] ? p[lin[t2]] : -1e30f;
      m = fmaxf(m, v);
    }
    const float* wr = &wl[c * 32];
#pragma unroll
    for (int j = 0; j < 32; j++) acc[j] += m * wr[j];
  }
  if (act) {
    const float* xpre = frames + (size_t)fpre * 64 * HW + px;
    float* dp = dsum + (size_t)n * 64 * HW + px;
#pragma unroll
    for (int j = 0; j < 32; j++) {
      int o = o0 + j;
      float d = dp[o * HW] + (acc[j] + B3[o]) - 3.f * xpre[o * HW];
      dp[o * HW] = fabsf(d);
    }
  }
}

// ---------------------------------------------------------------------------
// Spatial mean of cat = [diff frames | t_out] per (nt, c).
// ---------------------------------------------------------------------------
__global__ void k_gmean(const float* __restrict__ dsum,
                        const float* __restrict__ t_out,
                        float* __restrict__ gmean)
{
  const int nt = blockIdx.x, c = blockIdx.y;
  const int b = nt >> 3, tt = nt & 7;
  const float* p = (tt < 7) ? (dsum + (size_t)((b * 7 + tt) * 64 + c) * HW)
                            : (t_out + (size_t)(b * 64 + c) * HW);
  const int tid = threadIdx.x;
  float s = 0.f;
  for (int i = tid; i < HW; i += 64) s += p[i];
#pragma unroll
  for (int o = 32; o > 0; o >>= 1) s += __shfl_down(s, o, 64);
  if (tid == 0) gmean[nt * 64 + c] = s * (1.f / HW);
}

// ---------------------------------------------------------------------------
// Gate: 1x1 conv 64->256 + sigmoid; store mult.
// ---------------------------------------------------------------------------
__global__ __launch_bounds__(256) void k_gate(
    const float* __restrict__ gmean, const float* __restrict__ gwT,
    const float* __restrict__ Bg, float* __restrict__ mult)
{
  __shared__ float gm[64];
  const int nt = blockIdx.x, co = threadIdx.x;
  if (co < 64) gm[co] = gmean[nt * 64 + co];
  __syncthreads();
  float a = 0.f;
#pragma unroll 8
  for (int c = 0; c < 64; c++) a += gm[c] * gwT[c * 256 + co];
  float pre = a + Bg[co];
  mult[nt * 256 + co] = 0.5f + 1.f / (1.f + expf(-pre));
}

// ---------------------------------------------------------------------------
// out = x * mult[nt,co]
// ---------------------------------------------------------------------------
__global__ void k_apply(const float* __restrict__ x,
                        const float* __restrict__ mult,
                        float* __restrict__ outp)
{
  const int i = blockIdx.x * 256 + threadIdx.x;
  const int plane = i / 196;
  const float m = mult[plane];
  float4 v = ((const float4*)x)[i];
  v.x *= m; v.y *= m; v.z *= m; v.w *= m;
  ((float4*)outp)[i] = v;
}

// ---------------------------------------------------------------------------
extern "C" void kernel_launch(void* const* d_in, const int* in_sizes, int n_in,
                              void* d_out, int out_size, void* d_ws, size_t ws_size,
                              hipStream_t stream)
{
  const float* x       = (const float*)d_in[0];
  const float* w_down  = (const float*)d_in[1];
  const float* b_down  = (const float*)d_in[2];
  const float* bn1_g   = (const float*)d_in[3];
  const float* bn1_b   = (const float*)d_in[4];
  const float* bn1_m   = (const float*)d_in[5];
  const float* bn1_v   = (const float*)d_in[6];
  const float* tconv_w = (const float*)d_in[7];
  const float* tconv_b = (const float*)d_in[8];
  const float* bnt_g   = (const float*)d_in[9];
  const float* bnt_b   = (const float*)d_in[10];
  const float* bnt_m   = (const float*)d_in[11];
  const float* bnt_v   = (const float*)d_in[12];
  const float* off3_w  = (const float*)d_in[13];
  const float* off3_b  = (const float*)d_in[14];
  const float* def3_w  = (const float*)d_in[15];
  const float* off5_w  = (const float*)d_in[16];
  const float* off5_b  = (const float*)d_in[17];
  const float* def5_w  = (const float*)d_in[18];
  const float* conv1_w = (const float*)d_in[19];
  const float* conv1_b = (const float*)d_in[20];
  const float* bn3_g   = (const float*)d_in[21];
  const float* bn3_b   = (const float*)d_in[22];
  const float* bn3_m   = (const float*)d_in[23];
  const float* bn3_v   = (const float*)d_in[24];
  const float* conv_w  = (const float*)d_in[25];
  const float* conv_b  = (const float*)d_in[26];
  const float* bn2_g   = (const float*)d_in[27];
  const float* bn2_b   = (const float*)d_in[28];
  const float* bn2_m   = (const float*)d_in[29];
  const float* bn2_v   = (const float*)d_in[30];

  float* ws = (float*)d_ws;
  float* out_b  = ws; ws += 64 * 64 * HW;
  float* U      = ws; ws += 8 * 192 * HW;
  float* t_out  = ws; ws += 8 * 64 * HW;
  float* off3b  = ws; ws += 56 * 18 * HW;
  float* off5b  = ws; ws += 56 * 50 * HW;
  float* dsum   = ws; ws += PLANE;
  float* gmean  = ws; ws += 64 * 64;
  float* multb  = ws; ws += 64 * 256;
  float* wdownT = ws; ws += 256 * 64;
  float* bias1  = ws; ws += 64;
  float* wtT    = ws; ws += 192 * 9 * 64;
  float* AtBt   = ws; ws += 128;
  float* c1T    = ws; ws += 64 * 64;
  float* B3     = ws; ws += 64;
  float* gwT    = ws; ws += 64 * 256;
  float* Bg     = ws; ws += 256;
  float* xT     = ws; ws += PLANE;                      // px-major f32
  __hip_bfloat16* wBs3 = (__hip_bfloat16*)ws; ws += 9216;    // 18432 bf16
  __hip_bfloat16* wBs5 = (__hip_bfloat16*)ws; ws += 51200;   // 102400 bf16
  __hip_bfloat16* wBd  = (__hip_bfloat16*)ws; ws += 69632;   // 139264 bf16
  __hip_bfloat16* xTbP = (__hip_bfloat16*)ws; ws += 56 * PADPX * 64 / 2;

  k_prep<<<256, 256, 0, stream>>>(
      w_down, b_down, bn1_g, bn1_b, bn1_m, bn1_v,
      tconv_w, tconv_b, bnt_g, bnt_b, bnt_m, bnt_v,
      off3_w, def3_w, off5_w, def5_w,
      conv1_w, conv1_b, bn3_g, bn3_b, bn3_m, bn3_v,
      conv_w, conv_b, bn2_g, bn2_b, bn2_m, bn2_v,
      wdownT, bias1, wtT, AtBt, wBs3, wBs5, wBd,
      c1T, B3, gwT, Bg);
  k_zerob<<<1792, 256, 0, stream>>>((float4*)xTbP);

  k_down<<<dim3(196, 2), 256, 0, stream>>>(x, wdownT, bias1, out_b);
  k_xpose<<<dim3(56, 13), 256, 0, stream>>>(out_b, xT, xTbP);
  k_makeU<<<1568, 256, 0, stream>>>(out_b, U);
  k_tconv<<<dim3(8, 4, 16), 256, 0, stream>>>(U, wtT, AtBt, t_out);
  // 686 blocks of 64 px each (43904 = 686*64 exact)
  k_offconv_mfma<3, 1, 18, 2, 9><<<686, 256, 0, stream>>>(xTbP, wBs3, off3_b, off3b);
  k_offconv_mfma<5, 2, 50, 4, 5><<<686, 256, 0, stream>>>(xTbP, wBs5, off5_b, off5b);
  // 2744 tiles of 16 px (43904 = 2744*16 exact; 784 = 49*16), 4 waves/tile
  k_deform_mfma<<<2744, 256, 0, stream>>>(xT, off3b, off5b, wBd, dsum);
  k_davg_diff<<<dim3(PXBLK, 2), 256, 0, stream>>>(out_b, c1T, B3, dsum);
  k_gmean<<<dim3(64, 64), 64, 0, stream>>>(dsum, t_out, gmean);
  k_gate<<<64, 256, 0, stream>>>(gmean, gwT, Bg, multb);
  k_apply<<<12544, 256, 0, stream>>>(x, multb, (float*)d_out);
}

// Round 4
// 495.404 us; speedup vs baseline: 1.1956x; 1.1956x over previous
//
#include <hip/hip_runtime.h>
#include <hip/hip_bf16.h>

#define HW 784
#define WD 28
#define NPX (56 * 784)         // 43904 deform/offconv pixels
#define PXBLK 172              // ceil(43904/256)
#define PADPX 1024             // 32x32 padded spatial (halo 2)

using short8 = __attribute__((ext_vector_type(8))) short;
using f32x4  = __attribute__((ext_vector_type(4))) float;

__device__ __forceinline__ float b2f(short s)
{
  return __uint_as_float(((unsigned)(unsigned short)s) << 16);
}

// ---------------------------------------------------------------------------
// Prep: fold BN into transposed weight layouts + MFMA-fragment-order bf16
// weights for the offset convs and the fused deform GEMM.
// wBs[tap][chunk][ntile][lane][j] (bf16): B[k=chunk*32+(lane>>4)*8+j][oc=ntile*16+(lane&15)]
// wBd: same frag layout, 34 taps (9 from def3_w, 25 from def5_w), NT=4.
// ---------------------------------------------------------------------------
__global__ void k_prep(
    const float* __restrict__ w_down, const float* __restrict__ b_down,
    const float* __restrict__ bn1_g, const float* __restrict__ bn1_b,
    const float* __restrict__ bn1_m, const float* __restrict__ bn1_v,
    const float* __restrict__ tconv_w, const float* __restrict__ tconv_b,
    const float* __restrict__ bnt_g, const float* __restrict__ bnt_b,
    const float* __restrict__ bnt_m, const float* __restrict__ bnt_v,
    const float* __restrict__ off3_w, const float* __restrict__ def3_w,
    const float* __restrict__ off5_w, const float* __restrict__ def5_w,
    const float* __restrict__ conv1_w, const float* __restrict__ conv1_b,
    const float* __restrict__ bn3_g, const float* __restrict__ bn3_b,
    const float* __restrict__ bn3_m, const float* __restrict__ bn3_v,
    const float* __restrict__ conv_w, const float* __restrict__ conv_b,
    const float* __restrict__ bn2_g, const float* __restrict__ bn2_b,
    const float* __restrict__ bn2_m, const float* __restrict__ bn2_v,
    float* __restrict__ wdownT, float* __restrict__ bias1,
    float* __restrict__ wtT, float* __restrict__ AtBt,
    __hip_bfloat16* __restrict__ wBs3, __hip_bfloat16* __restrict__ wBs5,
    __hip_bfloat16* __restrict__ wBd,
    float* __restrict__ c1T, float* __restrict__ B3,
    float* __restrict__ gwT, float* __restrict__ Bg)
{
  const int tid = blockIdx.x * blockDim.x + threadIdx.x;
  const int nth = gridDim.x * blockDim.x;
  for (int i = tid; i < 256 * 64; i += nth) {
    int c = i >> 6, cr = i & 63;
    float s = bn1_g[cr] / sqrtf(bn1_v[cr] + 1e-5f);
    wdownT[i] = w_down[cr * 256 + c] * s;
  }
  for (int i = tid; i < 64; i += nth) {
    float s = bn1_g[i] / sqrtf(bn1_v[i] + 1e-5f);
    bias1[i] = (b_down[i] - bn1_m[i]) * s + bn1_b[i];
  }
  for (int i = tid; i < 192 * 9 * 64; i += nth) {
    int cc = i / (9 * 64); int tap = (i / 64) % 9; int o = i & 63;
    int dt = cc >> 6, c = cc & 63;
    wtT[i] = tconv_w[o * 1728 + c * 27 + dt * 9 + tap];
  }
  for (int i = tid; i < 64; i += nth) {
    float s = bnt_g[i] / sqrtf(bnt_v[i] + 1e-5f);
    AtBt[i] = s * 0.125f;
    AtBt[64 + i] = (tconv_b[i] - bnt_m[i]) * s + bnt_b[i];
  }
  // off3 MFMA B-frags: K2=9, NT=2 (ocpad 32). total 9*2*2*512 = 18432
  for (int i = tid; i < 9 * 2 * 2 * 512; i += nth) {
    int j = i & 7; int lane = (i >> 3) & 63;
    int rest = i >> 9; int nt = rest % 2; rest /= 2;
    int chunk = rest & 1; int tap = rest >> 1;
    int c = chunk * 32 + ((lane >> 4) << 3) + j;
    int oc = nt * 16 + (lane & 15);
    float v = (oc < 18) ? off3_w[oc * 576 + c * 9 + tap] : 0.f;
    wBs3[i] = __float2bfloat16(v);
  }
  // off5 MFMA B-frags: K2=25, NT=4 (ocpad 64). total 25*2*4*512 = 102400
  for (int i = tid; i < 25 * 2 * 4 * 512; i += nth) {
    int j = i & 7; int lane = (i >> 3) & 63;
    int rest = i >> 9; int nt = rest % 4; rest /= 4;
    int chunk = rest & 1; int tap = rest >> 1;
    int c = chunk * 32 + ((lane >> 4) << 3) + j;
    int oc = nt * 16 + (lane & 15);
    float v = (oc < 50) ? off5_w[oc * 1600 + c * 25 + tap] : 0.f;
    wBs5[i] = __float2bfloat16(v);
  }
  // fused deform B-frags: 34 taps (0..8 = def3, 9..33 = def5), NT=4 (oc=64)
  for (int i = tid; i < 34 * 2 * 4 * 512; i += nth) {
    int j = i & 7; int lane = (i >> 3) & 63;
    int rest = i >> 9; int nt = rest & 3; rest >>= 2;
    int chunk = rest & 1; int tap = rest >> 1;
    int c = chunk * 32 + ((lane >> 4) << 3) + j;
    int oc = nt * 16 + (lane & 15);
    float v = (tap < 9) ? def3_w[oc * 576 + c * 9 + tap]
                        : def5_w[oc * 1600 + c * 25 + (tap - 9)];
    wBd[i] = __float2bfloat16(v);
  }
  for (int i = tid; i < 64 * 64; i += nth) {
    int c = i >> 6, o = i & 63;
    float s = bn3_g[o] / sqrtf(bn3_v[o] + 1e-5f);
    c1T[i] = conv1_w[o * 64 + c] * s;
  }
  for (int i = tid; i < 64; i += nth) {
    float s = bn3_g[i] / sqrtf(bn3_v[i] + 1e-5f);
    B3[i] = (conv1_b[i] - bn3_m[i]) * s + bn3_b[i];
  }
  for (int i = tid; i < 64 * 256; i += nth) {
    int c = i >> 8, co = i & 255;
    float s = bn2_g[co] / sqrtf(bn2_v[co] + 1e-5f);
    gwT[i] = conv_w[co * 64 + c] * s;
  }
  for (int i = tid; i < 256; i += nth) {
    float s = bn2_g[i] / sqrtf(bn2_v[i] + 1e-5f);
    Bg[i] = (conv_b[i] - bn2_m[i]) * s + bn2_b[i];
  }
}

// ---------------------------------------------------------------------------
// Zero the padded bf16 image (halo must be 0 every call; ws is re-poisoned).
// 56*1024*64 bf16 = 458752 float4.
// ---------------------------------------------------------------------------
__global__ void k_zerob(float4* __restrict__ p)
{
  p[blockIdx.x * 256 + threadIdx.x] = make_float4(0.f, 0.f, 0.f, 0.f);
}

// ---------------------------------------------------------------------------
// 1x1 down conv (256->64) + BN fold. px-flat grid (196, o-split 2).
// ---------------------------------------------------------------------------
__global__ __launch_bounds__(256) void k_down(
    const float* __restrict__ x, const float* __restrict__ wdownT,
    const float* __restrict__ bias1, float* __restrict__ out)
{
  __shared__ float wl[256 * 32];            // 32 KB
  const int tid = threadIdx.x;
  const int o0 = blockIdx.y * 32;
  for (int i = tid; i < 2048; i += 256) {
    int c = i >> 3, q = i & 7;
    ((float4*)wl)[i] = *(const float4*)(wdownT + c * 64 + o0 + q * 4);
  }
  __syncthreads();
  const int gpx = blockIdx.x * 256 + tid;   // < 50176 exact
  const int f = gpx / HW, px = gpx % HW;
  const float* xp = x + (size_t)f * 256 * HW + px;
  float acc[32];
#pragma unroll
  for (int j = 0; j < 32; j++) acc[j] = 0.f;
#pragma unroll 4
  for (int c = 0; c < 256; c++) {
    float xv = xp[c * HW];
    const float* wr = &wl[c * 32];
#pragma unroll
    for (int j = 0; j < 32; j++) acc[j] += xv * wr[j];
  }
  float* op = out + (size_t)f * 64 * HW + px;
#pragma unroll
  for (int j = 0; j < 32; j++) op[(o0 + j) * HW] = acc[j] + bias1[o0 + j];
}

// ---------------------------------------------------------------------------
// Transpose post frames to padded px-major bf16 xTbP[n][(py+2)*32+(px+2)][c]
// (consumed by both the MFMA offconvs and the LDS-gather deform).
// ---------------------------------------------------------------------------
__global__ __launch_bounds__(256) void k_xpose(
    const float* __restrict__ out_b, __hip_bfloat16* __restrict__ xTbP)
{
  __shared__ float t[64 * 65];
  const int tid = threadIdx.x;
  const int lane = tid & 63, grp = tid >> 6;
  const int n = blockIdx.x;
  const int f = (n / 7) * 8 + (n % 7) + 1;
  const int px0 = blockIdx.y * 64;
  const float* sb = out_b + (size_t)f * 64 * HW;
#pragma unroll
  for (int c = grp; c < 64; c += 4) {
    int px = px0 + lane;
    t[c * 65 + lane] = (px < HW) ? sb[c * HW + px] : 0.f;
  }
  __syncthreads();
#pragma unroll
  for (int r = grp; r < 64; r += 4) {
    int px = px0 + r;
    if (px < HW) {
      float v = t[lane * 65 + r];
      int py = px / WD, pxc = px % WD;
      xTbP[((size_t)n * PADPX + (py + 2) * 32 + (pxc + 2)) * 64 + lane] =
          __float2bfloat16(v);
    }
  }
}

// ---------------------------------------------------------------------------
// U planes for collapsed temporal conv.
// ---------------------------------------------------------------------------
__global__ void k_makeU(const float* __restrict__ out, float* __restrict__ U)
{
  const int idx = blockIdx.x * 256 + threadIdx.x;
  const int b = idx / (64 * HW);
  const int r = idx % (64 * HW);
  const float* p = out + (size_t)b * 8 * 64 * HW + r;
  float v0 = p[0];
  float s = v0, v = v0;
#pragma unroll
  for (int t = 1; t < 8; t++) { v = p[t * 64 * HW]; s += v; }
  float* u = U + (size_t)b * 192 * HW + r;
  u[0] = s - v;
  u[64 * HW] = s;
  u[128 * HW] = s - v0;
}

// ---------------------------------------------------------------------------
// Collapsed temporal conv: 3x3, 192->64. o-groups of 4 (16 z-blocks).
// ---------------------------------------------------------------------------
__global__ __launch_bounds__(256) void k_tconv(
    const float* __restrict__ U, const float* __restrict__ wtT,
    const float* __restrict__ AtBt, float* __restrict__ t_out)
{
  __shared__ float wl[16 * 9 * 4];
  const int tid = threadIdx.x;
  const int b = blockIdx.x;
  const int px = blockIdx.y * 256 + tid;
  const int o0 = blockIdx.z * 4;
  const bool act = px < HW;
  const int pxe = act ? px : 0;
  const int y = pxe / WD, x = pxe % WD;
  int lin[9]; float msk[9];
#pragma unroll
  for (int t = 0; t < 9; t++) {
    int iy = y + t / 3 - 1, ix = x + t % 3 - 1;
    bool ok = iy >= 0 && iy < WD && ix >= 0 && ix < WD;
    lin[t] = min(max(iy, 0), WD - 1) * WD + min(max(ix, 0), WD - 1);
    msk[t] = ok ? 1.f : 0.f;
  }
  float acc[4];
#pragma unroll
  for (int j = 0; j < 4; j++) acc[j] = 0.f;
  const float* ub = U + (size_t)b * 192 * HW;
  for (int ccb = 0; ccb < 12; ccb++) {
    __syncthreads();
    for (int i = tid; i < 576; i += 256) {
      int ccL = i / 36; int rr = i % 36; int tap = rr >> 2; int j = rr & 3;
      wl[i] = wtT[((ccb * 16 + ccL) * 9 + tap) * 64 + o0 + j];
    }
    __syncthreads();
    for (int ccL = 0; ccL < 16; ccL++) {
      const float* p = ub + (ccb * 16 + ccL) * HW;
      float v[9];
#pragma unroll
      for (int t = 0; t < 9; t++) v[t] = p[lin[t]] * msk[t];
      const float* wr = &wl[ccL * 36];
#pragma unroll
      for (int t = 0; t < 9; t++)
#pragma unroll
        for (int j = 0; j < 4; j++) acc[j] += v[t] * wr[t * 4 + j];
    }
  }
  if (act) {
#pragma unroll
    for (int j = 0; j < 4; j++) {
      int o = o0 + j;
      t_out[(size_t)(b * 64 + o) * HW + px] = acc[j] * AtBt[o] + AtBt[64 + o];
    }
  }
}

// ---------------------------------------------------------------------------
// Offset convs as implicit-GEMM bf16 MFMA (16x16x32).
// ---------------------------------------------------------------------------
template <int KS, int PAD, int OC, int NT, int TAPBLK>
__global__ __launch_bounds__(256) void k_offconv_mfma(
    const __hip_bfloat16* __restrict__ xTbP,
    const __hip_bfloat16* __restrict__ wBs,
    const float* __restrict__ bias, float* __restrict__ dst)
{
  constexpr int K2 = KS * KS;
  __shared__ short bs[TAPBLK * NT * 1024];   // B frags, 2*NT KB per tap
  __shared__ float ct[NT * 16 * 65];         // C tile [ocpad][px(64)+pad]
  const int tid = threadIdx.x;
  const int w = tid >> 6, lane = tid & 63;
  const int quad = lane >> 4, mrow = lane & 15;
  const int gpx = blockIdx.x * 64 + w * 16 + mrow;   // A-row pixel
  const int n = gpx / HW, px = gpx % HW;
  const int y = px / WD, x = px % WD;
  const short* xb = (const short*)xTbP + ((size_t)n * PADPX) * 64;
  f32x4 acc[NT];
#pragma unroll
  for (int nt = 0; nt < NT; nt++) acc[nt] = (f32x4){0.f, 0.f, 0.f, 0.f};

  for (int tb = 0; tb < K2; tb += TAPBLK) {
    __syncthreads();
    for (int i = tid; i < TAPBLK * NT * 128; i += 256)
      ((float4*)bs)[i] = ((const float4*)(wBs + (size_t)tb * NT * 1024))[i];
    __syncthreads();
#pragma unroll
    for (int t2 = 0; t2 < TAPBLK; t2++) {
      int tap = tb + t2;
      if (K2 % TAPBLK != 0 && tap >= K2) break;
      int ty = tap / KS, tx = tap % KS;
      int sp = (y + ty + (2 - PAD)) * 32 + (x + tx + (2 - PAD));
      const short* ap = xb + sp * 64 + quad * 8;
      short8 a0 = *(const short8*)(ap);
      short8 a1 = *(const short8*)(ap + 32);
      const short* bp = bs + t2 * NT * 1024;
#pragma unroll
      for (int nt = 0; nt < NT; nt++) {
        short8 b0 = *(const short8*)(bp + nt * 512 + lane * 8);
        acc[nt] = __builtin_amdgcn_mfma_f32_16x16x32_bf16(a0, b0, acc[nt], 0, 0, 0);
      }
#pragma unroll
      for (int nt = 0; nt < NT; nt++) {
        short8 b1 = *(const short8*)(bp + (NT + nt) * 512 + lane * 8);
        acc[nt] = __builtin_amdgcn_mfma_f32_16x16x32_bf16(a1, b1, acc[nt], 0, 0, 0);
      }
    }
  }
  // C/D frag: col(oc) = lane&15, row(px) = quad*4 + reg
  __syncthreads();
#pragma unroll
  for (int nt = 0; nt < NT; nt++) {
    int oc_l = nt * 16 + mrow;
#pragma unroll
    for (int reg = 0; reg < 4; reg++) {
      int pxr = w * 16 + quad * 4 + reg;
      ct[oc_l * 65 + pxr] = acc[nt][reg];
    }
  }
  __syncthreads();
  for (int i = tid; i < OC * 64; i += 256) {
    int oc = i >> 6, p2 = i & 63;
    int g2 = blockIdx.x * 64 + p2;
    int n2 = g2 / HW, px2 = g2 % HW;
    dst[((size_t)n2 * OC + oc) * HW + px2] = ct[oc * 65 + p2] + bias[oc];
  }
}

// ---------------------------------------------------------------------------
// FUSED deformable conv (def3 + def5): LDS-resident frame gather + bf16 MFMA.
// Grid = (4 parts, 56 frames) x 512 threads (8 waves). Each block stages the
// whole 28x28x64 bf16 frame into LDS ONCE (100,352 B), chunk-XOR-swizzled
// (slot = k ^ (px&7)) so the scattered ds_read_b128 gathers are bank-spread.
// After one staging barrier, each wave privately processes 1-2 16px x 64oc
// tiles with ZERO further barriers: per tap, the 8 corner reads are ~120cy
// LDS ops (vs ~300-900cy global) — the latency chain that bound R1/R2
// collapses. Bilinear blend in f32 from bf16 corners, direct-to-fragment
// (lane quad*16+mrow = px mrow, channels quad*8+j / +32), 8 MFMAs per tap.
// Epilogue: per-wave LDS transpose scratch -> coalesced 64B stores.
// LDS total = 100,352 + 34,816 = 135,168 B -> 1 block/CU.
// ---------------------------------------------------------------------------
__global__ __launch_bounds__(512) void k_deform_mfma(
    const __hip_bfloat16* __restrict__ xTbP,
    const float* __restrict__ off3b, const float* __restrict__ off5b,
    const __hip_bfloat16* __restrict__ wBd,
    float* __restrict__ dsum)
{
  __shared__ __align__(16) short Fr[784 * 64];     // swizzled bf16 frame
  __shared__ __align__(16) float ct[8][64 * 17];   // per-wave C transpose
  const int tid = threadIdx.x;
  const int w = tid >> 6, lane = tid & 63;
  const int quad = lane >> 4, mrow = lane & 15;
  const int part = blockIdx.x, n = blockIdx.y;

  // stage swizzled frame from the padded bf16 image (row px: slot k holds
  // channel-chunk k ^ (px&7); XOR is self-inverse)
  {
    const short* xb = (const short*)xTbP + (size_t)n * PADPX * 64;
    for (int idx = tid; idx < 784 * 8; idx += 512) {
      int px = idx >> 3, k = idx & 7;
      int py = px / WD, pxc = px % WD;
      float4 v = ((const float4*)(xb + ((py + 2) * 32 + (pxc + 2)) * 64))[k];
      ((float4*)Fr)[px * 8 + (k ^ (px & 7))] = v;
    }
  }
  __syncthreads();

  const int cnt = (part == 0) ? 13 : 12;
  const int start = part * 12 + (part > 0 ? 1 : 0);
  const char* F = (const char*)Fr;

  for (int t = w; t < cnt; t += 8) {
    const int px0 = (start + t) * 16;
    const int pxg = px0 + mrow;
    const int y_g = pxg / WD, x_g = pxg % WD;
    const float* ob3 = off3b + (size_t)n * 18 * HW + pxg;
    const float* ob5 = off5b + (size_t)n * 50 * HW + pxg;

    f32x4 acc[4];
#pragma unroll
    for (int nt = 0; nt < 4; nt++) acc[nt] = (f32x4){0.f, 0.f, 0.f, 0.f};

#pragma unroll 2
    for (int tap = 0; tap < 34; tap++) {
      // B frags (L2-resident), issued early
      const short* bw = (const short*)wBd + (size_t)tap * 4096 + lane * 8;
      short8 bfrag[8];
#pragma unroll
      for (int q = 0; q < 8; q++) bfrag[q] = *(const short8*)(bw + q * 512);

      int kk, ty, tx, PADl; const float* obp;
      if (tap < 9) { kk = tap; ty = kk / 3; tx = kk % 3; PADl = 1; obp = ob3; }
      else { kk = tap - 9; ty = kk / 5; tx = kk % 5; PADl = 2; obp = ob5; }
      float offy = obp[(2 * kk) * HW];
      float offx = obp[(2 * kk + 1) * HW];
      float py = (float)(y_g + ty - PADl) + offy;
      float pxx = (float)(x_g + tx - PADl) + offx;
      float fy = floorf(py), fx = floorf(pxx);
      int y0 = (int)fy, x0 = (int)fx;
      float ly = py - fy, lx = pxx - fx;
      int y1 = y0 + 1, x1 = x0 + 1;
      float vy0 = (y0 >= 0 && y0 < WD) ? 1.f : 0.f;
      float vy1 = (y1 >= 0 && y1 < WD) ? 1.f : 0.f;
      float vx0 = (x0 >= 0 && x0 < WD) ? 1.f : 0.f;
      float vx1 = (x1 >= 0 && x1 < WD) ? 1.f : 0.f;
      float w00 = (1.f - ly) * (1.f - lx) * vy0 * vx0;
      float w01 = (1.f - ly) * lx * vy0 * vx1;
      float w10 = ly * (1.f - lx) * vy1 * vx0;
      float w11 = ly * lx * vy1 * vx1;
      int cy0 = min(max(y0, 0), WD - 1), cy1 = min(max(y1, 0), WD - 1);
      int cx0 = min(max(x0, 0), WD - 1), cx1 = min(max(x1, 0), WD - 1);
      int r00 = cy0 * WD + cx0, r01 = cy0 * WD + cx1;
      int r10 = cy1 * WD + cx0, r11 = cy1 * WD + cx1;
      // 8 swizzled LDS corner reads: chunk q of row r lives at slot q^(r&7)
      short8 c00 = *(const short8*)(F + r00 * 128 + ((quad ^ (r00 & 7)) << 4));
      short8 c01 = *(const short8*)(F + r01 * 128 + ((quad ^ (r01 & 7)) << 4));
      short8 c10 = *(const short8*)(F + r10 * 128 + ((quad ^ (r10 & 7)) << 4));
      short8 c11 = *(const short8*)(F + r11 * 128 + ((quad ^ (r11 & 7)) << 4));
      short8 d00 = *(const short8*)(F + r00 * 128 + (((quad + 4) ^ (r00 & 7)) << 4));
      short8 d01 = *(const short8*)(F + r01 * 128 + (((quad + 4) ^ (r01 & 7)) << 4));
      short8 d10 = *(const short8*)(F + r10 * 128 + (((quad + 4) ^ (r10 & 7)) << 4));
      short8 d11 = *(const short8*)(F + r11 * 128 + (((quad + 4) ^ (r11 & 7)) << 4));
      short8 a0, a1;
#pragma unroll
      for (int j = 0; j < 8; j++) {
        float g0 = b2f(c00[j]) * w00 + b2f(c01[j]) * w01 +
                   b2f(c10[j]) * w10 + b2f(c11[j]) * w11;
        float g1 = b2f(d00[j]) * w00 + b2f(d01[j]) * w01 +
                   b2f(d10[j]) * w10 + b2f(d11[j]) * w11;
        __hip_bfloat16 q0 = __float2bfloat16(g0);
        __hip_bfloat16 q1 = __float2bfloat16(g1);
        a0[j] = *(short*)&q0;
        a1[j] = *(short*)&q1;
      }
#pragma unroll
      for (int nt = 0; nt < 4; nt++)
        acc[nt] = __builtin_amdgcn_mfma_f32_16x16x32_bf16(a0, bfrag[nt], acc[nt], 0, 0, 0);
#pragma unroll
      for (int nt = 0; nt < 4; nt++)
        acc[nt] = __builtin_amdgcn_mfma_f32_16x16x32_bf16(a1, bfrag[4 + nt], acc[nt], 0, 0, 0);
    }

    // epilogue (wave-private scratch; in-wave LDS ordering suffices)
    // C/D frag: col(oc) = lane&15 (+nt*16), row(px) = quad*4 + reg
#pragma unroll
    for (int nt = 0; nt < 4; nt++) {
      int oc_l = nt * 16 + mrow;
#pragma unroll
      for (int reg = 0; reg < 4; reg++)
        ct[w][oc_l * 17 + quad * 4 + reg] = acc[nt][reg];
    }
    {
      const int oc = lane;
      float* dp = dsum + ((size_t)n * 64 + oc) * HW + px0;
#pragma unroll
      for (int q = 0; q < 4; q++) {
        float4 o4 = make_float4(ct[w][oc * 17 + q * 4 + 0],
                                ct[w][oc * 17 + q * 4 + 1],
                                ct[w][oc * 17 + q * 4 + 2],
                                ct[w][oc * 17 + q * 4 + 3]);
        *(float4*)(dp + q * 4) = o4;
      }
    }
  }
}

// ---------------------------------------------------------------------------
// maxpool 3x3 + 1x1 conv (BN folded) + diff epilogue (dsum holds d3+d5).
// ---------------------------------------------------------------------------
__global__ __launch_bounds__(256) void k_davg_diff(
    const float* __restrict__ frames, const float* __restrict__ c1T,
    const float* __restrict__ B3, float* __restrict__ dsum)
{
  __shared__ float wl[64 * 32];
  const int tid = threadIdx.x;
  const int o0 = blockIdx.y * 32;
  for (int i = tid; i < 512; i += 256) {
    int c = i >> 3, q = i & 7;
    ((float4*)wl)[i] = *(const float4*)(c1T + c * 64 + o0 + q * 4);
  }
  __syncthreads();
  const int gpx = blockIdx.x * 256 + tid;
  const bool act = gpx < NPX;
  const int gpe = act ? gpx : 0;
  const int n = gpe / HW, px = gpe % HW;
  const int b = n / 7, t = n % 7;
  const int fpost = b * 8 + t + 1, fpre = b * 8 + t;
  const int y = px / WD, x = px % WD;
  int lin[9]; bool okm[9];
#pragma unroll
  for (int t2 = 0; t2 < 9; t2++) {
    int iy = y + t2 / 3 - 1, ix = x + t2 % 3 - 1;
    okm[t2] = iy >= 0 && iy < WD && ix >= 0 && ix < WD;
    lin[t2] = min(max(iy, 0), WD - 1) * WD + min(max(ix, 0), WD - 1);
  }
  float acc[32];
#pragma unroll
  for (int j = 0; j < 32; j++) acc[j] = 0.f;
  const float* sb = frames + (size_t)fpost * 64 * HW;
  for (int c = 0; c < 64; c++) {
    const float* p = sb + c * HW;
    float m = -1e30f;
#pragma unroll
    for (int t2 = 0; t2 < 9; t2++) {
      float v = okm[t2] ? p[lin[t2]] : -1e30f;
      m = fmaxf(m, v);
    }
    const float* wr = &wl[c * 32];
#pragma unroll
    for (int j = 0; j < 32; j++) acc[j] += m * wr[j];
  }
  if (act) {
    const float* xpre = frames + (size_t)fpre * 64 * HW + px;
    float* dp = dsum + (size_t)n * 64 * HW + px;
#pragma unroll
    for (int j = 0; j < 32; j++) {
      int o = o0 + j;
      float d = dp[o * HW] + (acc[j] + B3[o]) - 3.f * xpre[o * HW];
      dp[o * HW] = fabsf(d);
    }
  }
}

// ---------------------------------------------------------------------------
// Spatial mean of cat = [diff frames | t_out] per (nt, c).
// ---------------------------------------------------------------------------
__global__ void k_gmean(const float* __restrict__ dsum,
                        const float* __restrict__ t_out,
                        float* __restrict__ gmean)
{
  const int nt = blockIdx.x, c = blockIdx.y;
  const int b = nt >> 3, tt = nt & 7;
  const float* p = (tt < 7) ? (dsum + (size_t)((b * 7 + tt) * 64 + c) * HW)
                            : (t_out + (size_t)(b * 64 + c) * HW);
  const int tid = threadIdx.x;
  float s = 0.f;
  for (int i = tid; i < HW; i += 64) s += p[i];
#pragma unroll
  for (int o = 32; o > 0; o >>= 1) s += __shfl_down(s, o, 64);
  if (tid == 0) gmean[nt * 64 + c] = s * (1.f / HW);
}

// ---------------------------------------------------------------------------
// Gate: 1x1 conv 64->256 + sigmoid; store mult.
// ---------------------------------------------------------------------------
__global__ __launch_bounds__(256) void k_gate(
    const float* __restrict__ gmean, const float* __restrict__ gwT,
    const float* __restrict__ Bg, float* __restrict__ mult)
{
  __shared__ float gm[64];
  const int nt = blockIdx.x, co = threadIdx.x;
  if (co < 64) gm[co] = gmean[nt * 64 + co];
  __syncthreads();
  float a = 0.f;
#pragma unroll 8
  for (int c = 0; c < 64; c++) a += gm[c] * gwT[c * 256 + co];
  float pre = a + Bg[co];
  mult[nt * 256 + co] = 0.5f + 1.f / (1.f + expf(-pre));
}

// ---------------------------------------------------------------------------
// out = x * mult[nt,co]
// ---------------------------------------------------------------------------
__global__ void k_apply(const float* __restrict__ x,
                        const float* __restrict__ mult,
                        float* __restrict__ outp)
{
  const int i = blockIdx.x * 256 + threadIdx.x;
  const int plane = i / 196;
  const float m = mult[plane];
  float4 v = ((const float4*)x)[i];
  v.x *= m; v.y *= m; v.z *= m; v.w *= m;
  ((float4*)outp)[i] = v;
}

// ---------------------------------------------------------------------------
extern "C" void kernel_launch(void* const* d_in, const int* in_sizes, int n_in,
                              void* d_out, int out_size, void* d_ws, size_t ws_size,
                              hipStream_t stream)
{
  const float* x       = (const float*)d_in[0];
  const float* w_down  = (const float*)d_in[1];
  const float* b_down  = (const float*)d_in[2];
  const float* bn1_g   = (const float*)d_in[3];
  const float* bn1_b   = (const float*)d_in[4];
  const float* bn1_m   = (const float*)d_in[5];
  const float* bn1_v   = (const float*)d_in[6];
  const float* tconv_w = (const float*)d_in[7];
  const float* tconv_b = (const float*)d_in[8];
  const float* bnt_g   = (const float*)d_in[9];
  const float* bnt_b   = (const float*)d_in[10];
  const float* bnt_m   = (const float*)d_in[11];
  const float* bnt_v   = (const float*)d_in[12];
  const float* off3_w  = (const float*)d_in[13];
  const float* off3_b  = (const float*)d_in[14];
  const float* def3_w  = (const float*)d_in[15];
  const float* off5_w  = (const float*)d_in[16];
  const float* off5_b  = (const float*)d_in[17];
  const float* def5_w  = (const float*)d_in[18];
  const float* conv1_w = (const float*)d_in[19];
  const float* conv1_b = (const float*)d_in[20];
  const float* bn3_g   = (const float*)d_in[21];
  const float* bn3_b   = (const float*)d_in[22];
  const float* bn3_m   = (const float*)d_in[23];
  const float* bn3_v   = (const float*)d_in[24];
  const float* conv_w  = (const float*)d_in[25];
  const float* conv_b  = (const float*)d_in[26];
  const float* bn2_g   = (const float*)d_in[27];
  const float* bn2_b   = (const float*)d_in[28];
  const float* bn2_m   = (const float*)d_in[29];
  const float* bn2_v   = (const float*)d_in[30];

  float* ws = (float*)d_ws;
  float* out_b  = ws; ws += 64 * 64 * HW;
  float* U      = ws; ws += 8 * 192 * HW;
  float* t_out  = ws; ws += 8 * 64 * HW;
  float* off3b  = ws; ws += 56 * 18 * HW;
  float* off5b  = ws; ws += 56 * 50 * HW;
  float* dsum   = ws; ws += 56 * 64 * HW;
  float* gmean  = ws; ws += 64 * 64;
  float* multb  = ws; ws += 64 * 256;
  float* wdownT = ws; ws += 256 * 64;
  float* bias1  = ws; ws += 64;
  float* wtT    = ws; ws += 192 * 9 * 64;
  float* AtBt   = ws; ws += 128;
  float* c1T    = ws; ws += 64 * 64;
  float* B3     = ws; ws += 64;
  float* gwT    = ws; ws += 64 * 256;
  float* Bg     = ws; ws += 256;
  __hip_bfloat16* wBs3 = (__hip_bfloat16*)ws; ws += 9216;    // 18432 bf16
  __hip_bfloat16* wBs5 = (__hip_bfloat16*)ws; ws += 51200;   // 102400 bf16
  __hip_bfloat16* wBd  = (__hip_bfloat16*)ws; ws += 69632;   // 139264 bf16
  __hip_bfloat16* xTbP = (__hip_bfloat16*)ws; ws += 56 * PADPX * 64 / 2;

  k_prep<<<256, 256, 0, stream>>>(
      w_down, b_down, bn1_g, bn1_b, bn1_m, bn1_v,
      tconv_w, tconv_b, bnt_g, bnt_b, bnt_m, bnt_v,
      off3_w, def3_w, off5_w, def5_w,
      conv1_w, conv1_b, bn3_g, bn3_b, bn3_m, bn3_v,
      conv_w, conv_b, bn2_g, bn2_b, bn2_m, bn2_v,
      wdownT, bias1, wtT, AtBt, wBs3, wBs5, wBd,
      c1T, B3, gwT, Bg);
  k_zerob<<<1792, 256, 0, stream>>>((float4*)xTbP);

  k_down<<<dim3(196, 2), 256, 0, stream>>>(x, wdownT, bias1, out_b);
  k_xpose<<<dim3(56, 13), 256, 0, stream>>>(out_b, xTbP);
  k_makeU<<<1568, 256, 0, stream>>>(out_b, U);
  k_tconv<<<dim3(8, 4, 16), 256, 0, stream>>>(U, wtT, AtBt, t_out);
  // 686 blocks of 64 px each (43904 = 686*64 exact)
  k_offconv_mfma<3, 1, 18, 2, 9><<<686, 256, 0, stream>>>(xTbP, wBs3, off3_b, off3b);
  k_offconv_mfma<5, 2, 50, 4, 5><<<686, 256, 0, stream>>>(xTbP, wBs5, off5_b, off5b);
  // 4 parts x 56 frames, 8 waves/block, frame resident in LDS
  k_deform_mfma<<<dim3(4, 56), 512, 0, stream>>>(xTbP, off3b, off5b, wBd, dsum);
  k_davg_diff<<<dim3(PXBLK, 2), 256, 0, stream>>>(out_b, c1T, B3, dsum);
  k_gmean<<<dim3(64, 64), 64, 0, stream>>>(dsum, t_out, gmean);
  k_gate<<<64, 256, 0, stream>>>(gmean, gwT, Bg, multb);
  k_apply<<<12544, 256, 0, stream>>>(x, multb, (float*)d_out);
}

// Round 5
// 481.611 us; speedup vs baseline: 1.2299x; 1.0286x over previous
//
#include <hip/hip_runtime.h>
#include <hip/hip_bf16.h>

#define HW 784
#define WD 28
#define NPX (56 * 784)         // 43904 deform/offconv pixels
#define PXBLK 172              // ceil(43904/256)
#define PLANE (56 * 64 * 784)  // 2,809,856 floats: one full plane
#define PADPX 1024             // 32x32 padded spatial (halo 2)

using short8 = __attribute__((ext_vector_type(8))) short;
using f32x4  = __attribute__((ext_vector_type(4))) float;

__device__ __forceinline__ float b2f(short s)
{
  return __uint_as_float(((unsigned)(unsigned short)s) << 16);
}

// ---------------------------------------------------------------------------
// Prep: fold BN into transposed weight layouts + MFMA-fragment-order bf16
// weights for the offset convs and the fused deform GEMM.
// wBs[tap][chunk][ntile][lane][j] (bf16): B[k=chunk*32+(lane>>4)*8+j][oc=ntile*16+(lane&15)]
// wBd: same frag layout, 34 taps (9 from def3_w, 25 from def5_w), NT=4.
// ---------------------------------------------------------------------------
__global__ void k_prep(
    const float* __restrict__ w_down, const float* __restrict__ b_down,
    const float* __restrict__ bn1_g, const float* __restrict__ bn1_b,
    const float* __restrict__ bn1_m, const float* __restrict__ bn1_v,
    const float* __restrict__ tconv_w, const float* __restrict__ tconv_b,
    const float* __restrict__ bnt_g, const float* __restrict__ bnt_b,
    const float* __restrict__ bnt_m, const float* __restrict__ bnt_v,
    const float* __restrict__ off3_w, const float* __restrict__ def3_w,
    const float* __restrict__ off5_w, const float* __restrict__ def5_w,
    const float* __restrict__ conv1_w, const float* __restrict__ conv1_b,
    const float* __restrict__ bn3_g, const float* __restrict__ bn3_b,
    const float* __restrict__ bn3_m, const float* __restrict__ bn3_v,
    const float* __restrict__ conv_w, const float* __restrict__ conv_b,
    const float* __restrict__ bn2_g, const float* __restrict__ bn2_b,
    const float* __restrict__ bn2_m, const float* __restrict__ bn2_v,
    float* __restrict__ wdownT, float* __restrict__ bias1,
    float* __restrict__ wtT, float* __restrict__ AtBt,
    __hip_bfloat16* __restrict__ wBs3, __hip_bfloat16* __restrict__ wBs5,
    __hip_bfloat16* __restrict__ wBd,
    float* __restrict__ c1T, float* __restrict__ B3,
    float* __restrict__ gwT, float* __restrict__ Bg)
{
  const int tid = blockIdx.x * blockDim.x + threadIdx.x;
  const int nth = gridDim.x * blockDim.x;
  for (int i = tid; i < 256 * 64; i += nth) {
    int c = i >> 6, cr = i & 63;
    float s = bn1_g[cr] / sqrtf(bn1_v[cr] + 1e-5f);
    wdownT[i] = w_down[cr * 256 + c] * s;
  }
  for (int i = tid; i < 64; i += nth) {
    float s = bn1_g[i] / sqrtf(bn1_v[i] + 1e-5f);
    bias1[i] = (b_down[i] - bn1_m[i]) * s + bn1_b[i];
  }
  for (int i = tid; i < 192 * 9 * 64; i += nth) {
    int cc = i / (9 * 64); int tap = (i / 64) % 9; int o = i & 63;
    int dt = cc >> 6, c = cc & 63;
    wtT[i] = tconv_w[o * 1728 + c * 27 + dt * 9 + tap];
  }
  for (int i = tid; i < 64; i += nth) {
    float s = bnt_g[i] / sqrtf(bnt_v[i] + 1e-5f);
    AtBt[i] = s * 0.125f;
    AtBt[64 + i] = (tconv_b[i] - bnt_m[i]) * s + bnt_b[i];
  }
  // off3 MFMA B-frags: K2=9, NT=2 (ocpad 32). total 9*2*2*512 = 18432
  for (int i = tid; i < 9 * 2 * 2 * 512; i += nth) {
    int j = i & 7; int lane = (i >> 3) & 63;
    int rest = i >> 9; int nt = rest % 2; rest /= 2;
    int chunk = rest & 1; int tap = rest >> 1;
    int c = chunk * 32 + ((lane >> 4) << 3) + j;
    int oc = nt * 16 + (lane & 15);
    float v = (oc < 18) ? off3_w[oc * 576 + c * 9 + tap] : 0.f;
    wBs3[i] = __float2bfloat16(v);
  }
  // off5 MFMA B-frags: K2=25, NT=4 (ocpad 64). total 25*2*4*512 = 102400
  for (int i = tid; i < 25 * 2 * 4 * 512; i += nth) {
    int j = i & 7; int lane = (i >> 3) & 63;
    int rest = i >> 9; int nt = rest % 4; rest /= 4;
    int chunk = rest & 1; int tap = rest >> 1;
    int c = chunk * 32 + ((lane >> 4) << 3) + j;
    int oc = nt * 16 + (lane & 15);
    float v = (oc < 50) ? off5_w[oc * 1600 + c * 25 + tap] : 0.f;
    wBs5[i] = __float2bfloat16(v);
  }
  // fused deform B-frags: 34 taps (0..8 = def3, 9..33 = def5), NT=4 (oc=64)
  for (int i = tid; i < 34 * 2 * 4 * 512; i += nth) {
    int j = i & 7; int lane = (i >> 3) & 63;
    int rest = i >> 9; int nt = rest & 3; rest >>= 2;
    int chunk = rest & 1; int tap = rest >> 1;
    int c = chunk * 32 + ((lane >> 4) << 3) + j;
    int oc = nt * 16 + (lane & 15);
    float v = (tap < 9) ? def3_w[oc * 576 + c * 9 + tap]
                        : def5_w[oc * 1600 + c * 25 + (tap - 9)];
    wBd[i] = __float2bfloat16(v);
  }
  for (int i = tid; i < 64 * 64; i += nth) {
    int c = i >> 6, o = i & 63;
    float s = bn3_g[o] / sqrtf(bn3_v[o] + 1e-5f);
    c1T[i] = conv1_w[o * 64 + c] * s;
  }
  for (int i = tid; i < 64; i += nth) {
    float s = bn3_g[i] / sqrtf(bn3_v[i] + 1e-5f);
    B3[i] = (conv1_b[i] - bn3_m[i]) * s + bn3_b[i];
  }
  for (int i = tid; i < 64 * 256; i += nth) {
    int c = i >> 8, co = i & 255;
    float s = bn2_g[co] / sqrtf(bn2_v[co] + 1e-5f);
    gwT[i] = conv_w[co * 64 + c] * s;
  }
  for (int i = tid; i < 256; i += nth) {
    float s = bn2_g[i] / sqrtf(bn2_v[i] + 1e-5f);
    Bg[i] = (conv_b[i] - bn2_m[i]) * s + bn2_b[i];
  }
}

// ---------------------------------------------------------------------------
// Zero the padded bf16 image (halo must be 0 every call; ws is re-poisoned).
// 56*1024*64 bf16 = 458752 float4.
// ---------------------------------------------------------------------------
__global__ void k_zerob(float4* __restrict__ p)
{
  p[blockIdx.x * 256 + threadIdx.x] = make_float4(0.f, 0.f, 0.f, 0.f);
}

// ---------------------------------------------------------------------------
// 1x1 down conv (256->64) + BN fold. px-flat grid (196, o-split 2).
// Epilogue ALSO writes the padded px-major bf16 image (its 32-oc half-row)
// for post frames, eliminating the separate transpose kernel.
// ---------------------------------------------------------------------------
__global__ __launch_bounds__(256) void k_down(
    const float* __restrict__ x, const float* __restrict__ wdownT,
    const float* __restrict__ bias1, float* __restrict__ out,
    __hip_bfloat16* __restrict__ xTbP)
{
  __shared__ float wl[256 * 32];            // 32 KB
  const int tid = threadIdx.x;
  const int o0 = blockIdx.y * 32;
  for (int i = tid; i < 2048; i += 256) {
    int c = i >> 3, q = i & 7;
    ((float4*)wl)[i] = *(const float4*)(wdownT + c * 64 + o0 + q * 4);
  }
  __syncthreads();
  const int gpx = blockIdx.x * 256 + tid;   // < 50176 exact
  const int f = gpx / HW, px = gpx % HW;
  const float* xp = x + (size_t)f * 256 * HW + px;
  float acc[32];
#pragma unroll
  for (int j = 0; j < 32; j++) acc[j] = 0.f;
#pragma unroll 4
  for (int c = 0; c < 256; c++) {
    float xv = xp[c * HW];
    const float* wr = &wl[c * 32];
#pragma unroll
    for (int j = 0; j < 32; j++) acc[j] += xv * wr[j];
  }
  float* op = out + (size_t)f * 64 * HW + px;
  short8 hv[4];
#pragma unroll
  for (int j = 0; j < 32; j++) {
    float vv = acc[j] + bias1[o0 + j];
    op[(o0 + j) * HW] = vv;
    __hip_bfloat16 q = __float2bfloat16(vv);
    hv[j >> 3][j & 7] = *(short*)&q;
  }
  if (f % 8) {                      // post frame -> padded bf16 image
    int n = (f >> 3) * 7 + (f & 7) - 1;
    int py = px / WD, pxc = px % WD;
    short8* xp2 = (short8*)((short*)xTbP +
        ((size_t)n * PADPX + (py + 2) * 32 + (pxc + 2)) * 64 + o0);
#pragma unroll
    for (int q4 = 0; q4 < 4; q4++) xp2[q4] = hv[q4];
  }
}

// ---------------------------------------------------------------------------
// U planes for collapsed temporal conv.
// ---------------------------------------------------------------------------
__global__ void k_makeU(const float* __restrict__ out, float* __restrict__ U)
{
  const int idx = blockIdx.x * 256 + threadIdx.x;
  const int b = idx / (64 * HW);
  const int r = idx % (64 * HW);
  const float* p = out + (size_t)b * 8 * 64 * HW + r;
  float v0 = p[0];
  float s = v0, v = v0;
#pragma unroll
  for (int t = 1; t < 8; t++) { v = p[t * 64 * HW]; s += v; }
  float* u = U + (size_t)b * 192 * HW + r;
  u[0] = s - v;
  u[64 * HW] = s;
  u[128 * HW] = s - v0;
}

// ---------------------------------------------------------------------------
// Collapsed temporal conv: 3x3, 192->64. o-groups of 4 (16 z-blocks).
// ---------------------------------------------------------------------------
__global__ __launch_bounds__(256) void k_tconv(
    const float* __restrict__ U, const float* __restrict__ wtT,
    const float* __restrict__ AtBt, float* __restrict__ t_out)
{
  __shared__ float wl[16 * 9 * 4];
  const int tid = threadIdx.x;
  const int b = blockIdx.x;
  const int px = blockIdx.y * 256 + tid;
  const int o0 = blockIdx.z * 4;
  const bool act = px < HW;
  const int pxe = act ? px : 0;
  const int y = pxe / WD, x = pxe % WD;
  int lin[9]; float msk[9];
#pragma unroll
  for (int t = 0; t < 9; t++) {
    int iy = y + t / 3 - 1, ix = x + t % 3 - 1;
    bool ok = iy >= 0 && iy < WD && ix >= 0 && ix < WD;
    lin[t] = min(max(iy, 0), WD - 1) * WD + min(max(ix, 0), WD - 1);
    msk[t] = ok ? 1.f : 0.f;
  }
  float acc[4];
#pragma unroll
  for (int j = 0; j < 4; j++) acc[j] = 0.f;
  const float* ub = U + (size_t)b * 192 * HW;
  for (int ccb = 0; ccb < 12; ccb++) {
    __syncthreads();
    for (int i = tid; i < 576; i += 256) {
      int ccL = i / 36; int rr = i % 36; int tap = rr >> 2; int j = rr & 3;
      wl[i] = wtT[((ccb * 16 + ccL) * 9 + tap) * 64 + o0 + j];
    }
    __syncthreads();
    for (int ccL = 0; ccL < 16; ccL++) {
      const float* p = ub + (ccb * 16 + ccL) * HW;
      float v[9];
#pragma unroll
      for (int t = 0; t < 9; t++) v[t] = p[lin[t]] * msk[t];
      const float* wr = &wl[ccL * 36];
#pragma unroll
      for (int t = 0; t < 9; t++)
#pragma unroll
        for (int j = 0; j < 4; j++) acc[j] += v[t] * wr[t * 4 + j];
    }
  }
  if (act) {
#pragma unroll
    for (int j = 0; j < 4; j++) {
      int o = o0 + j;
      t_out[(size_t)(b * 64 + o) * HW + px] = acc[j] * AtBt[o] + AtBt[64 + o];
    }
  }
}

// ---------------------------------------------------------------------------
// Offset convs as implicit-GEMM bf16 MFMA (16x16x32).
// ---------------------------------------------------------------------------
template <int KS, int PAD, int OC, int NT, int TAPBLK>
__global__ __launch_bounds__(256) void k_offconv_mfma(
    const __hip_bfloat16* __restrict__ xTbP,
    const __hip_bfloat16* __restrict__ wBs,
    const float* __restrict__ bias, float* __restrict__ dst)
{
  constexpr int K2 = KS * KS;
  __shared__ short bs[TAPBLK * NT * 1024];   // B frags, 2*NT KB per tap
  __shared__ float ct[NT * 16 * 65];         // C tile [ocpad][px(64)+pad]
  const int tid = threadIdx.x;
  const int w = tid >> 6, lane = tid & 63;
  const int quad = lane >> 4, mrow = lane & 15;
  const int gpx = blockIdx.x * 64 + w * 16 + mrow;   // A-row pixel
  const int n = gpx / HW, px = gpx % HW;
  const int y = px / WD, x = px % WD;
  const short* xb = (const short*)xTbP + ((size_t)n * PADPX) * 64;
  f32x4 acc[NT];
#pragma unroll
  for (int nt = 0; nt < NT; nt++) acc[nt] = (f32x4){0.f, 0.f, 0.f, 0.f};

  for (int tb = 0; tb < K2; tb += TAPBLK) {
    __syncthreads();
    for (int i = tid; i < TAPBLK * NT * 128; i += 256)
      ((float4*)bs)[i] = ((const float4*)(wBs + (size_t)tb * NT * 1024))[i];
    __syncthreads();
#pragma unroll
    for (int t2 = 0; t2 < TAPBLK; t2++) {
      int tap = tb + t2;
      if (K2 % TAPBLK != 0 && tap >= K2) break;
      int ty = tap / KS, tx = tap % KS;
      int sp = (y + ty + (2 - PAD)) * 32 + (x + tx + (2 - PAD));
      const short* ap = xb + sp * 64 + quad * 8;
      short8 a0 = *(const short8*)(ap);
      short8 a1 = *(const short8*)(ap + 32);
      const short* bp = bs + t2 * NT * 1024;
#pragma unroll
      for (int nt = 0; nt < NT; nt++) {
        short8 b0 = *(const short8*)(bp + nt * 512 + lane * 8);
        acc[nt] = __builtin_amdgcn_mfma_f32_16x16x32_bf16(a0, b0, acc[nt], 0, 0, 0);
      }
#pragma unroll
      for (int nt = 0; nt < NT; nt++) {
        short8 b1 = *(const short8*)(bp + (NT + nt) * 512 + lane * 8);
        acc[nt] = __builtin_amdgcn_mfma_f32_16x16x32_bf16(a1, b1, acc[nt], 0, 0, 0);
      }
    }
  }
  // C/D frag: col(oc) = lane&15, row(px) = quad*4 + reg
  __syncthreads();
#pragma unroll
  for (int nt = 0; nt < NT; nt++) {
    int oc_l = nt * 16 + mrow;
#pragma unroll
    for (int reg = 0; reg < 4; reg++) {
      int pxr = w * 16 + quad * 4 + reg;
      ct[oc_l * 65 + pxr] = acc[nt][reg];
    }
  }
  __syncthreads();
  for (int i = tid; i < OC * 64; i += 256) {
    int oc = i >> 6, p2 = i & 63;
    int g2 = blockIdx.x * 64 + p2;
    int n2 = g2 / HW, px2 = g2 % HW;
    dst[((size_t)n2 * OC + oc) * HW + px2] = ct[oc * 65 + p2] + bias[oc];
  }
}

// ---------------------------------------------------------------------------
// FUSED deformable conv (def3 + def5): LDS half-frame gather + bf16 MFMA,
// C-SPLIT x2 for occupancy.
// Grid = (7 parts, 56 frames, 2 c-halves) x 448 threads (7 waves). Each block
// stages a 32-channel half-frame (28x28x32 bf16 = 49,152 B, 4-slot XOR
// swizzle slot = s ^ (px&3)) -> 3 blocks/CU, ~5 waves/SIMD (vs 2 in R3).
// Each wave owns ONE 16px x 64oc tile (49 tiles = 7 parts x 7 waves); per tap
// (34 total): 4 swizzled LDS corner reads (8ch each), f32 bilinear blend,
// direct-to-fragment bf16, 4 MFMAs (K=32 = this c-half). Zero barriers after
// staging. C-frag regs are px-contiguous per lane -> direct float4 stores,
// no LDS transpose scratch. csel 0 -> dsum, csel 1 -> pext (summed in davg).
// ---------------------------------------------------------------------------
__global__ __launch_bounds__(448, 6) void k_deform_mfma(
    const __hip_bfloat16* __restrict__ xTbP,
    const float* __restrict__ off3b, const float* __restrict__ off5b,
    const __hip_bfloat16* __restrict__ wBd,
    float* __restrict__ dsum, float* __restrict__ pext)
{
  __shared__ __align__(16) short Fr[784 * 32];   // swizzled bf16 half-frame
  const int tid = threadIdx.x;
  const int w = tid >> 6, lane = tid & 63;
  const int quad = lane >> 4, mrow = lane & 15;
  const int part = blockIdx.x, n = blockIdx.y, csel = blockIdx.z;

  // stage half-frame (channels csel*32..+32): row px -> 4 float4 slots,
  // slot s of row px stored at s ^ (px&3) (XOR self-inverse)
  {
    const short* xb = (const short*)xTbP + (size_t)n * PADPX * 64;
    for (int idx = tid; idx < 784 * 4; idx += 448) {
      int px = idx >> 2, s = idx & 3;
      int py = px / WD, pxc = px % WD;
      float4 v = ((const float4*)(xb + ((py + 2) * 32 + (pxc + 2)) * 64))[csel * 4 + s];
      ((float4*)Fr)[px * 4 + (s ^ (px & 3))] = v;
    }
  }
  __syncthreads();

  const char* F = (const char*)Fr;
  const int px0 = (part * 7 + w) * 16;
  const int pxg = px0 + mrow;
  const int y_g = pxg / WD, x_g = pxg % WD;
  const float* ob3 = off3b + (size_t)n * 18 * HW + pxg;
  const float* ob5 = off5b + (size_t)n * 50 * HW + pxg;

  f32x4 acc[4];
#pragma unroll
  for (int nt = 0; nt < 4; nt++) acc[nt] = (f32x4){0.f, 0.f, 0.f, 0.f};

#pragma unroll 2
  for (int tap = 0; tap < 34; tap++) {
    // B frags for this tap & c-half (L2-resident)
    const short* bw = (const short*)wBd +
        ((size_t)(tap * 2 + csel) * 4) * 512 + lane * 8;
    short8 bfrag[4];
#pragma unroll
    for (int nt = 0; nt < 4; nt++) bfrag[nt] = *(const short8*)(bw + nt * 512);

    int kk, ty, tx, PADl; const float* obp;
    if (tap < 9) { kk = tap; ty = kk / 3; tx = kk % 3; PADl = 1; obp = ob3; }
    else { kk = tap - 9; ty = kk / 5; tx = kk % 5; PADl = 2; obp = ob5; }
    float offy = obp[(2 * kk) * HW];
    float offx = obp[(2 * kk + 1) * HW];
    float py = (float)(y_g + ty - PADl) + offy;
    float pxx = (float)(x_g + tx - PADl) + offx;
    float fy = floorf(py), fx = floorf(pxx);
    int y0 = (int)fy, x0 = (int)fx;
    float ly = py - fy, lx = pxx - fx;
    int y1 = y0 + 1, x1 = x0 + 1;
    float vy0 = (y0 >= 0 && y0 < WD) ? 1.f : 0.f;
    float vy1 = (y1 >= 0 && y1 < WD) ? 1.f : 0.f;
    float vx0 = (x0 >= 0 && x0 < WD) ? 1.f : 0.f;
    float vx1 = (x1 >= 0 && x1 < WD) ? 1.f : 0.f;
    float w00 = (1.f - ly) * (1.f - lx) * vy0 * vx0;
    float w01 = (1.f - ly) * lx * vy0 * vx1;
    float w10 = ly * (1.f - lx) * vy1 * vx0;
    float w11 = ly * lx * vy1 * vx1;
    int cy0 = min(max(y0, 0), WD - 1), cy1 = min(max(y1, 0), WD - 1);
    int cx0 = min(max(x0, 0), WD - 1), cx1 = min(max(x1, 0), WD - 1);
    int r00 = cy0 * WD + cx0, r01 = cy0 * WD + cx1;
    int r10 = cy1 * WD + cx0, r11 = cy1 * WD + cx1;
    // 4 swizzled LDS corner reads: chunk quad of row r at slot quad^(r&3)
    short8 c00 = *(const short8*)(F + r00 * 64 + ((quad ^ (r00 & 3)) << 4));
    short8 c01 = *(const short8*)(F + r01 * 64 + ((quad ^ (r01 & 3)) << 4));
    short8 c10 = *(const short8*)(F + r10 * 64 + ((quad ^ (r10 & 3)) << 4));
    short8 c11 = *(const short8*)(F + r11 * 64 + ((quad ^ (r11 & 3)) << 4));
    short8 a0;
#pragma unroll
    for (int j = 0; j < 8; j++) {
      float g0 = b2f(c00[j]) * w00 + b2f(c01[j]) * w01 +
                 b2f(c10[j]) * w10 + b2f(c11[j]) * w11;
      __hip_bfloat16 q0 = __float2bfloat16(g0);
      a0[j] = *(short*)&q0;
    }
#pragma unroll
    for (int nt = 0; nt < 4; nt++)
      acc[nt] = __builtin_amdgcn_mfma_f32_16x16x32_bf16(a0, bfrag[nt], acc[nt], 0, 0, 0);
  }

  // C/D frag: col(oc) = lane&15 (+nt*16), row(px) = quad*4 + reg.
  // acc[nt] regs 0..3 are px quad*4+0..3 of the SAME lane -> direct float4.
  float* P = csel ? pext : dsum;
#pragma unroll
  for (int nt = 0; nt < 4; nt++)
    *(f32x4*)(P + ((size_t)n * 64 + nt * 16 + mrow) * HW + px0 + quad * 4) =
        acc[nt];
}

// ---------------------------------------------------------------------------
// maxpool 3x3 + 1x1 conv (BN folded) + partial-sum + diff epilogue
// (dsum + pext hold the two c-halves of d3+d5).
// ---------------------------------------------------------------------------
__global__ __launch_bounds__(256) void k_davg_diff(
    const float* __restrict__ frames, const float* __restrict__ c1T,
    const float* __restrict__ B3, float* __restrict__ dsum,
    const float* __restrict__ pext)
{
  __shared__ float wl[64 * 32];
  const int tid = threadIdx.x;
  const int o0 = blockIdx.y * 32;
  for (int i = tid; i < 512; i += 256) {
    int c = i >> 3, q = i & 7;
    ((float4*)wl)[i] = *(const float4*)(c1T + c * 64 + o0 + q * 4);
  }
  __syncthreads();
  const int gpx = blockIdx.x * 256 + tid;
  const bool act = gpx < NPX;
  const int gpe = act ? gpx : 0;
  const int n = gpe / HW, px = gpe % HW;
  const int b = n / 7, t = n % 7;
  const int fpost = b * 8 + t + 1, fpre = b * 8 + t;
  const int y = px / WD, x = px % WD;
  int lin[9]; bool okm[9];
#pragma unroll
  for (int t2 = 0; t2 < 9; t2++) {
    int iy = y + t2 / 3 - 1, ix = x + t2 % 3 - 1;
    okm[t2] = iy >= 0 && iy < WD && ix >= 0 && ix < WD;
    lin[t2] = min(max(iy, 0), WD - 1) * WD + min(max(ix, 0), WD - 1);
  }
  float acc[32];
#pragma unroll
  for (int j = 0; j < 32; j++) acc[j] = 0.f;
  const float* sb = frames + (size_t)fpost * 64 * HW;
  for (int c = 0; c < 64; c++) {
    const float* p = sb + c * HW;
    float m = -1e30f;
#pragma unroll
    for (int t2 = 0; t2 < 9; t2++) {
      float v = okm[t2] ? p[lin[t2]] : -1e30f;
      m = fmaxf(m, v);
    }
    const float* wr = &wl[c * 32];
#pragma unroll
    for (int j = 0; j < 32; j++) acc[j] += m * wr[j];
  }
  if (act) {
    const float* xpre = frames + (size_t)fpre * 64 * HW + px;
    float* dp = dsum + (size_t)n * 64 * HW + px;
    const float* pp = pext + (size_t)n * 64 * HW + px;
#pragma unroll
    for (int j = 0; j < 32; j++) {
      int o = o0 + j;
      float d = dp[o * HW] + pp[o * HW] + (acc[j] + B3[o]) - 3.f * xpre[o * HW];
      dp[o * HW] = fabsf(d);
    }
  }
}

// ---------------------------------------------------------------------------
// Spatial mean of cat = [diff frames | t_out] per (nt, c).
// ---------------------------------------------------------------------------
__global__ void k_gmean(const float* __restrict__ dsum,
                        const float* __restrict__ t_out,
                        float* __restrict__ gmean)
{
  const int nt = blockIdx.x, c = blockIdx.y;
  const int b = nt >> 3, tt = nt & 7;
  const float* p = (tt < 7) ? (dsum + (size_t)((b * 7 + tt) * 64 + c) * HW)
                            : (t_out + (size_t)(b * 64 + c) * HW);
  const int tid = threadIdx.x;
  float s = 0.f;
  for (int i = tid; i < HW; i += 64) s += p[i];
#pragma unroll
  for (int o = 32; o > 0; o >>= 1) s += __shfl_down(s, o, 64);
  if (tid == 0) gmean[nt * 64 + c] = s * (1.f / HW);
}

// ---------------------------------------------------------------------------
// Gate: 1x1 conv 64->256 + sigmoid; store mult.
// ---------------------------------------------------------------------------
__global__ __launch_bounds__(256) void k_gate(
    const float* __restrict__ gmean, const float* __restrict__ gwT,
    const float* __restrict__ Bg, float* __restrict__ mult)
{
  __shared__ float gm[64];
  const int nt = blockIdx.x, co = threadIdx.x;
  if (co < 64) gm[co] = gmean[nt * 64 + co];
  __syncthreads();
  float a = 0.f;
#pragma unroll 8
  for (int c = 0; c < 64; c++) a += gm[c] * gwT[c * 256 + co];
  float pre = a + Bg[co];
  mult[nt * 256 + co] = 0.5f + 1.f / (1.f + expf(-pre));
}

// ---------------------------------------------------------------------------
// out = x * mult[nt,co]
// ---------------------------------------------------------------------------
__global__ void k_apply(const float* __restrict__ x,
                        const float* __restrict__ mult,
                        float* __restrict__ outp)
{
  const int i = blockIdx.x * 256 + threadIdx.x;
  const int plane = i / 196;
  const float m = mult[plane];
  float4 v = ((const float4*)x)[i];
  v.x *= m; v.y *= m; v.z *= m; v.w *= m;
  ((float4*)outp)[i] = v;
}

// ---------------------------------------------------------------------------
extern "C" void kernel_launch(void* const* d_in, const int* in_sizes, int n_in,
                              void* d_out, int out_size, void* d_ws, size_t ws_size,
                              hipStream_t stream)
{
  const float* x       = (const float*)d_in[0];
  const float* w_down  = (const float*)d_in[1];
  const float* b_down  = (const float*)d_in[2];
  const float* bn1_g   = (const float*)d_in[3];
  const float* bn1_b   = (const float*)d_in[4];
  const float* bn1_m   = (const float*)d_in[5];
  const float* bn1_v   = (const float*)d_in[6];
  const float* tconv_w = (const float*)d_in[7];
  const float* tconv_b = (const float*)d_in[8];
  const float* bnt_g   = (const float*)d_in[9];
  const float* bnt_b   = (const float*)d_in[10];
  const float* bnt_m   = (const float*)d_in[11];
  const float* bnt_v   = (const float*)d_in[12];
  const float* off3_w  = (const float*)d_in[13];
  const float* off3_b  = (const float*)d_in[14];
  const float* def3_w  = (const float*)d_in[15];
  const float* off5_w  = (const float*)d_in[16];
  const float* off5_b  = (const float*)d_in[17];
  const float* def5_w  = (const float*)d_in[18];
  const float* conv1_w = (const float*)d_in[19];
  const float* conv1_b = (const float*)d_in[20];
  const float* bn3_g   = (const float*)d_in[21];
  const float* bn3_b   = (const float*)d_in[22];
  const float* bn3_m   = (const float*)d_in[23];
  const float* bn3_v   = (const float*)d_in[24];
  const float* conv_w  = (const float*)d_in[25];
  const float* conv_b  = (const float*)d_in[26];
  const float* bn2_g   = (const float*)d_in[27];
  const float* bn2_b   = (const float*)d_in[28];
  const float* bn2_m   = (const float*)d_in[29];
  const float* bn2_v   = (const float*)d_in[30];

  float* ws = (float*)d_ws;
  float* out_b  = ws; ws += 64 * 64 * HW;
  float* U      = ws; ws += 8 * 192 * HW;
  float* t_out  = ws; ws += 8 * 64 * HW;
  float* off3b  = ws; ws += 56 * 18 * HW;
  float* off5b  = ws; ws += 56 * 50 * HW;
  float* dsum   = ws; ws += PLANE;
  float* pext   = ws; ws += PLANE;
  float* gmean  = ws; ws += 64 * 64;
  float* multb  = ws; ws += 64 * 256;
  float* wdownT = ws; ws += 256 * 64;
  float* bias1  = ws; ws += 64;
  float* wtT    = ws; ws += 192 * 9 * 64;
  float* AtBt   = ws; ws += 128;
  float* c1T    = ws; ws += 64 * 64;
  float* B3     = ws; ws += 64;
  float* gwT    = ws; ws += 64 * 256;
  float* Bg     = ws; ws += 256;
  __hip_bfloat16* wBs3 = (__hip_bfloat16*)ws; ws += 9216;    // 18432 bf16
  __hip_bfloat16* wBs5 = (__hip_bfloat16*)ws; ws += 51200;   // 102400 bf16
  __hip_bfloat16* wBd  = (__hip_bfloat16*)ws; ws += 69632;   // 139264 bf16
  __hip_bfloat16* xTbP = (__hip_bfloat16*)ws; ws += 56 * PADPX * 64 / 2;

  k_prep<<<256, 256, 0, stream>>>(
      w_down, b_down, bn1_g, bn1_b, bn1_m, bn1_v,
      tconv_w, tconv_b, bnt_g, bnt_b, bnt_m, bnt_v,
      off3_w, def3_w, off5_w, def5_w,
      conv1_w, conv1_b, bn3_g, bn3_b, bn3_m, bn3_v,
      conv_w, conv_b, bn2_g, bn2_b, bn2_m, bn2_v,
      wdownT, bias1, wtT, AtBt, wBs3, wBs5, wBd,
      c1T, B3, gwT, Bg);
  k_zerob<<<1792, 256, 0, stream>>>((float4*)xTbP);

  k_down<<<dim3(196, 2), 256, 0, stream>>>(x, wdownT, bias1, out_b, xTbP);
  k_makeU<<<1568, 256, 0, stream>>>(out_b, U);
  k_tconv<<<dim3(8, 4, 16), 256, 0, stream>>>(U, wtT, AtBt, t_out);
  // 686 blocks of 64 px each (43904 = 686*64 exact)
  k_offconv_mfma<3, 1, 18, 2, 9><<<686, 256, 0, stream>>>(xTbP, wBs3, off3_b, off3b);
  k_offconv_mfma<5, 2, 50, 4, 5><<<686, 256, 0, stream>>>(xTbP, wBs5, off5_b, off5b);
  // 7 parts x 56 frames x 2 c-halves, 7 waves/block, half-frame in LDS
  k_deform_mfma<<<dim3(7, 56, 2), 448, 0, stream>>>(xTbP, off3b, off5b, wBd,
                                                    dsum, pext);
  k_davg_diff<<<dim3(PXBLK, 2), 256, 0, stream>>>(out_b, c1T, B3, dsum, pext);
  k_gmean<<<dim3(64, 64), 64, 0, stream>>>(dsum, t_out, gmean);
  k_gate<<<64, 256, 0, stream>>>(gmean, gwT, Bg, multb);
  k_apply<<<12544, 256, 0, stream>>>(x, multb, (float*)d_out);
}

// Round 6
// 403.520 us; speedup vs baseline: 1.4679x; 1.1935x over previous
//
#include <hip/hip_runtime.h>
#include <hip/hip_bf16.h>

#define HW 784
#define WD 28
#define NPX (56 * 784)         // 43904 deform/offconv pixels
#define PLANE (56 * 64 * 784)  // 2,809,856 floats: one full plane
#define PADPX 1024             // 32x32 padded spatial (halo 2)

using short8 = __attribute__((ext_vector_type(8))) short;
using f32x4  = __attribute__((ext_vector_type(4))) float;

__device__ __forceinline__ float b2f(short s)
{
  return __uint_as_float(((unsigned)(unsigned short)s) << 16);
}

// ---------------------------------------------------------------------------
// Prep: fold BN into weight layouts; MFMA-fragment-order bf16 weights for
// offset convs (wBs), fused deform (wBd), down conv (wdB, hi/lo split) and
// davg 1x1 conv (c1B).
// Frag layout: B[k=chunk*32+(lane>>4)*8+j][oc=nt*16+(lane&15)].
// ---------------------------------------------------------------------------
__global__ void k_prep(
    const float* __restrict__ w_down, const float* __restrict__ b_down,
    const float* __restrict__ bn1_g, const float* __restrict__ bn1_b,
    const float* __restrict__ bn1_m, const float* __restrict__ bn1_v,
    const float* __restrict__ tconv_w, const float* __restrict__ tconv_b,
    const float* __restrict__ bnt_g, const float* __restrict__ bnt_b,
    const float* __restrict__ bnt_m, const float* __restrict__ bnt_v,
    const float* __restrict__ off3_w, const float* __restrict__ def3_w,
    const float* __restrict__ off5_w, const float* __restrict__ def5_w,
    const float* __restrict__ conv1_w, const float* __restrict__ conv1_b,
    const float* __restrict__ bn3_g, const float* __restrict__ bn3_b,
    const float* __restrict__ bn3_m, const float* __restrict__ bn3_v,
    const float* __restrict__ conv_w, const float* __restrict__ conv_b,
    const float* __restrict__ bn2_g, const float* __restrict__ bn2_b,
    const float* __restrict__ bn2_m, const float* __restrict__ bn2_v,
    __hip_bfloat16* __restrict__ wdB, float* __restrict__ bias1,
    float* __restrict__ wtT, float* __restrict__ AtBt,
    __hip_bfloat16* __restrict__ wBs3, __hip_bfloat16* __restrict__ wBs5,
    __hip_bfloat16* __restrict__ wBd, __hip_bfloat16* __restrict__ c1B,
    float* __restrict__ B3,
    float* __restrict__ gwT, float* __restrict__ Bg)
{
  const int tid = blockIdx.x * blockDim.x + threadIdx.x;
  const int nth = gridDim.x * blockDim.x;
  // down-conv MFMA B-frags, hi/lo split: chunks 0-7 = hi(w), 8-15 = lo(w)
  for (int i = tid; i < 16 * 4 * 512; i += nth) {
    int j = i & 7; int lane = (i >> 3) & 63;
    int rest = i >> 9; int nt = rest & 3; int ch = rest >> 2;
    int c = (ch & 7) * 32 + ((lane >> 4) << 3) + j;
    int oc = nt * 16 + (lane & 15);
    float s = bn1_g[oc] / sqrtf(bn1_v[oc] + 1e-5f);
    float wv = w_down[oc * 256 + c] * s;
    __hip_bfloat16 h = __float2bfloat16(wv);
    float hi = b2f(*(short*)&h);
    wdB[i] = (ch < 8) ? h : __float2bfloat16(wv - hi);
  }
  for (int i = tid; i < 64; i += nth) {
    float s = bn1_g[i] / sqrtf(bn1_v[i] + 1e-5f);
    bias1[i] = (b_down[i] - bn1_m[i]) * s + bn1_b[i];
  }
  for (int i = tid; i < 192 * 9 * 64; i += nth) {
    int cc = i / (9 * 64); int tap = (i / 64) % 9; int o = i & 63;
    int dt = cc >> 6, c = cc & 63;
    wtT[i] = tconv_w[o * 1728 + c * 27 + dt * 9 + tap];
  }
  for (int i = tid; i < 64; i += nth) {
    float s = bnt_g[i] / sqrtf(bnt_v[i] + 1e-5f);
    AtBt[i] = s * 0.125f;
    AtBt[64 + i] = (tconv_b[i] - bnt_m[i]) * s + bnt_b[i];
  }
  // off3 MFMA B-frags: K2=9, NT=2 (ocpad 32)
  for (int i = tid; i < 9 * 2 * 2 * 512; i += nth) {
    int j = i & 7; int lane = (i >> 3) & 63;
    int rest = i >> 9; int nt = rest % 2; rest /= 2;
    int chunk = rest & 1; int tap = rest >> 1;
    int c = chunk * 32 + ((lane >> 4) << 3) + j;
    int oc = nt * 16 + (lane & 15);
    float v = (oc < 18) ? off3_w[oc * 576 + c * 9 + tap] : 0.f;
    wBs3[i] = __float2bfloat16(v);
  }
  // off5 MFMA B-frags: K2=25, NT=4 (ocpad 64)
  for (int i = tid; i < 25 * 2 * 4 * 512; i += nth) {
    int j = i & 7; int lane = (i >> 3) & 63;
    int rest = i >> 9; int nt = rest % 4; rest /= 4;
    int chunk = rest & 1; int tap = rest >> 1;
    int c = chunk * 32 + ((lane >> 4) << 3) + j;
    int oc = nt * 16 + (lane & 15);
    float v = (oc < 50) ? off5_w[oc * 1600 + c * 25 + tap] : 0.f;
    wBs5[i] = __float2bfloat16(v);
  }
  // fused deform B-frags: 34 taps (0..8 def3, 9..33 def5), NT=4
  for (int i = tid; i < 34 * 2 * 4 * 512; i += nth) {
    int j = i & 7; int lane = (i >> 3) & 63;
    int rest = i >> 9; int nt = rest & 3; rest >>= 2;
    int chunk = rest & 1; int tap = rest >> 1;
    int c = chunk * 32 + ((lane >> 4) << 3) + j;
    int oc = nt * 16 + (lane & 15);
    float v = (tap < 9) ? def3_w[oc * 576 + c * 9 + tap]
                        : def5_w[oc * 1600 + c * 25 + (tap - 9)];
    wBd[i] = __float2bfloat16(v);
  }
  // davg 1x1 conv MFMA B-frags: K=64 (2 chunks), NT=4, BN folded
  for (int i = tid; i < 2 * 4 * 512; i += nth) {
    int j = i & 7; int lane = (i >> 3) & 63;
    int rest = i >> 9; int nt = rest & 3; int chunk = rest >> 2;
    int c = chunk * 32 + ((lane >> 4) << 3) + j;
    int oc = nt * 16 + (lane & 15);
    float s = bn3_g[oc] / sqrtf(bn3_v[oc] + 1e-5f);
    c1B[i] = __float2bfloat16(conv1_w[oc * 64 + c] * s);
  }
  for (int i = tid; i < 64; i += nth) {
    float s = bn3_g[i] / sqrtf(bn3_v[i] + 1e-5f);
    B3[i] = (conv1_b[i] - bn3_m[i]) * s + bn3_b[i];
  }
  for (int i = tid; i < 64 * 256; i += nth) {
    int c = i >> 8, co = i & 255;
    float s = bn2_g[co] / sqrtf(bn2_v[co] + 1e-5f);
    gwT[i] = conv_w[co * 64 + c] * s;
  }
  for (int i = tid; i < 256; i += nth) {
    float s = bn2_g[i] / sqrtf(bn2_v[i] + 1e-5f);
    Bg[i] = (conv_b[i] - bn2_m[i]) * s + bn2_b[i];
  }
}

// ---------------------------------------------------------------------------
// Zero ONLY the halo of the padded bf16 image (interior is fully overwritten
// by k_down's epilogue every call). 56 frames x 240 halo slots x 128 B.
// 240 slots = rows {0,1,30,31} full (128) + rows 2..29 cols {0,1,30,31} (112).
// ---------------------------------------------------------------------------
__global__ void k_zerohalo(float4* __restrict__ p)
{
  const int i = blockIdx.x * 256 + threadIdx.x;   // < 107520 = 56*240*8
  const int n = i / 1920, rem = i % 1920;
  const int sl = rem >> 3, q = rem & 7;
  int row, col;
  if (sl < 128) {
    int r = sl >> 5;
    row = (r & 1) + ((r >> 1) * 30);
    col = sl & 31;
  } else {
    int t2 = sl - 128;
    row = 2 + (t2 >> 2);
    int qq = t2 & 3;
    col = (qq & 1) + ((qq >> 1) * 30);
  }
  p[((size_t)n * 1024 + row * 32 + col) * 8 + q] =
      make_float4(0.f, 0.f, 0.f, 0.f);
}

// ---------------------------------------------------------------------------
// 1x1 down conv 256->64 as bf16 MFMA implicit GEMM with hi/lo split
// precision (out = xhi*whi + xlo*whi + xhi*wlo ~= f32 accuracy).
// Grid 784 blocks x 256 thr (4 waves); wave = 16px x 64oc tile; K=256 in
// 8 chunks. Reads x ONCE (vs 2x in the o-split version) and runs the MACs
// on the matrix pipe instead of VALU+LDS. Epilogue: ct transpose -> f32
// out_b (coalesced) + padded bf16 xTbP rows for post frames (fused xpose).
// ---------------------------------------------------------------------------
__global__ __launch_bounds__(256) void k_down(
    const float* __restrict__ x, const __hip_bfloat16* __restrict__ wdB,
    const float* __restrict__ bias1, float* __restrict__ out,
    __hip_bfloat16* __restrict__ xTbP)
{
  __shared__ float ct[64 * 65];
  const int tid = threadIdx.x;
  const int w = tid >> 6, lane = tid & 63;
  const int quad = lane >> 4, mrow = lane & 15;
  const int gpx = blockIdx.x * 64 + w * 16 + mrow;  // tiles never cross frames
  const int f = gpx / HW, px = gpx % HW;
  const float* xp = x + (size_t)f * 256 * HW + px;
  f32x4 acc[4];
#pragma unroll
  for (int nt = 0; nt < 4; nt++) acc[nt] = (f32x4){0.f, 0.f, 0.f, 0.f};

#pragma unroll
  for (int ch = 0; ch < 8; ch++) {
    short8 aH, aL;
#pragma unroll
    for (int j = 0; j < 8; j++) {
      float xv = xp[(ch * 32 + quad * 8 + j) * HW];
      __hip_bfloat16 h = __float2bfloat16(xv);
      aH[j] = *(short*)&h;
      __hip_bfloat16 l = __float2bfloat16(xv - b2f(aH[j]));
      aL[j] = *(short*)&l;
    }
    const short* bwH = (const short*)wdB + (size_t)(ch * 4) * 512 + lane * 8;
    const short* bwL = bwH + 16384;          // chunks 8..15 = lo(w)
#pragma unroll
    for (int nt = 0; nt < 4; nt++) {
      short8 bH = *(const short8*)(bwH + nt * 512);
      short8 bL = *(const short8*)(bwL + nt * 512);
      acc[nt] = __builtin_amdgcn_mfma_f32_16x16x32_bf16(aH, bH, acc[nt], 0, 0, 0);
      acc[nt] = __builtin_amdgcn_mfma_f32_16x16x32_bf16(aL, bH, acc[nt], 0, 0, 0);
      acc[nt] = __builtin_amdgcn_mfma_f32_16x16x32_bf16(aH, bL, acc[nt], 0, 0, 0);
    }
  }
  // C/D frag: col(oc) = lane&15, row(px) = quad*4 + reg
#pragma unroll
  for (int nt = 0; nt < 4; nt++) {
    int oc_l = nt * 16 + mrow;
#pragma unroll
    for (int reg = 0; reg < 4; reg++)
      ct[oc_l * 65 + w * 16 + quad * 4 + reg] = acc[nt][reg];
  }
  __syncthreads();
  for (int i = tid; i < 4096; i += 256) {        // out_b: [f][oc][px]
    int oc = i >> 6, p2 = i & 63;
    int g2 = blockIdx.x * 64 + p2;
    int f2 = g2 / HW, px2 = g2 % HW;
    out[((size_t)f2 * 64 + oc) * HW + px2] = ct[oc * 65 + p2] + bias1[oc];
  }
  for (int i = tid; i < 4096; i += 256) {        // xTbP: post frames only
    int p2 = i >> 6, oc = i & 63;
    int g2 = blockIdx.x * 64 + p2;
    int f2 = g2 / HW, px2 = g2 % HW;
    if (f2 & 7) {
      int n = (f2 >> 3) * 7 + (f2 & 7) - 1;
      int py = px2 / WD, pxc = px2 % WD;
      __hip_bfloat16 q = __float2bfloat16(ct[oc * 65 + p2] + bias1[oc]);
      ((short*)xTbP)[((size_t)n * PADPX + (py + 2) * 32 + (pxc + 2)) * 64 + oc] =
          *(short*)&q;
    }
  }
}

// ---------------------------------------------------------------------------
// U planes for collapsed temporal conv.
// ---------------------------------------------------------------------------
__global__ void k_makeU(const float* __restrict__ out, float* __restrict__ U)
{
  const int idx = blockIdx.x * 256 + threadIdx.x;
  const int b = idx / (64 * HW);
  const int r = idx % (64 * HW);
  const float* p = out + (size_t)b * 8 * 64 * HW + r;
  float v0 = p[0];
  float s = v0, v = v0;
#pragma unroll
  for (int t = 1; t < 8; t++) { v = p[t * 64 * HW]; s += v; }
  float* u = U + (size_t)b * 192 * HW + r;
  u[0] = s - v;
  u[64 * HW] = s;
  u[128 * HW] = s - v0;
}

// ---------------------------------------------------------------------------
// Collapsed temporal conv: 3x3, 192->64. o-groups of 4 (16 z-blocks).
// ---------------------------------------------------------------------------
__global__ __launch_bounds__(256) void k_tconv(
    const float* __restrict__ U, const float* __restrict__ wtT,
    const float* __restrict__ AtBt, float* __restrict__ t_out)
{
  __shared__ float wl[16 * 9 * 4];
  const int tid = threadIdx.x;
  const int b = blockIdx.x;
  const int px = blockIdx.y * 256 + tid;
  const int o0 = blockIdx.z * 4;
  const bool act = px < HW;
  const int pxe = act ? px : 0;
  const int y = pxe / WD, x = pxe % WD;
  int lin[9]; float msk[9];
#pragma unroll
  for (int t = 0; t < 9; t++) {
    int iy = y + t / 3 - 1, ix = x + t % 3 - 1;
    bool ok = iy >= 0 && iy < WD && ix >= 0 && ix < WD;
    lin[t] = min(max(iy, 0), WD - 1) * WD + min(max(ix, 0), WD - 1);
    msk[t] = ok ? 1.f : 0.f;
  }
  float acc[4];
#pragma unroll
  for (int j = 0; j < 4; j++) acc[j] = 0.f;
  const float* ub = U + (size_t)b * 192 * HW;
  for (int ccb = 0; ccb < 12; ccb++) {
    __syncthreads();
    for (int i = tid; i < 576; i += 256) {
      int ccL = i / 36; int rr = i % 36; int tap = rr >> 2; int j = rr & 3;
      wl[i] = wtT[((ccb * 16 + ccL) * 9 + tap) * 64 + o0 + j];
    }
    __syncthreads();
    for (int ccL = 0; ccL < 16; ccL++) {
      const float* p = ub + (ccb * 16 + ccL) * HW;
      float v[9];
#pragma unroll
      for (int t = 0; t < 9; t++) v[t] = p[lin[t]] * msk[t];
      const float* wr = &wl[ccL * 36];
#pragma unroll
      for (int t = 0; t < 9; t++)
#pragma unroll
        for (int j = 0; j < 4; j++) acc[j] += v[t] * wr[t * 4 + j];
    }
  }
  if (act) {
#pragma unroll
    for (int j = 0; j < 4; j++) {
      int o = o0 + j;
      t_out[(size_t)(b * 64 + o) * HW + px] = acc[j] * AtBt[o] + AtBt[64 + o];
    }
  }
}

// ---------------------------------------------------------------------------
// Offset convs as implicit-GEMM bf16 MFMA (16x16x32). B-frags loaded
// DIRECTLY from global (L2-hot, <=200KB total) — no LDS staging, no
// mid-kernel barriers (the 10 staging barriers in the old version gated
// all 4 waves on each other).
// ---------------------------------------------------------------------------
template <int KS, int PAD, int OC, int NT>
__global__ __launch_bounds__(256) void k_offconv_mfma(
    const __hip_bfloat16* __restrict__ xTbP,
    const __hip_bfloat16* __restrict__ wBs,
    const float* __restrict__ bias, float* __restrict__ dst)
{
  constexpr int K2 = KS * KS;
  __shared__ float ct[NT * 16 * 65];         // C tile [ocpad][px(64)+pad]
  const int tid = threadIdx.x;
  const int w = tid >> 6, lane = tid & 63;
  const int quad = lane >> 4, mrow = lane & 15;
  const int gpx = blockIdx.x * 64 + w * 16 + mrow;   // A-row pixel
  const int n = gpx / HW, px = gpx % HW;
  const int y = px / WD, x = px % WD;
  const short* xb = (const short*)xTbP + ((size_t)n * PADPX) * 64;
  f32x4 acc[NT];
#pragma unroll
  for (int nt = 0; nt < NT; nt++) acc[nt] = (f32x4){0.f, 0.f, 0.f, 0.f};

  for (int tap = 0; tap < K2; tap++) {
    const short* bw = (const short*)wBs + (size_t)tap * NT * 1024 + lane * 8;
    short8 bf[2 * NT];
#pragma unroll
    for (int q = 0; q < 2 * NT; q++) bf[q] = *(const short8*)(bw + q * 512);
    int ty = tap / KS, tx = tap % KS;
    int sp = (y + ty + (2 - PAD)) * 32 + (x + tx + (2 - PAD));
    const short* ap = xb + sp * 64 + quad * 8;
    short8 a0 = *(const short8*)(ap);
    short8 a1 = *(const short8*)(ap + 32);
#pragma unroll
    for (int nt = 0; nt < NT; nt++)
      acc[nt] = __builtin_amdgcn_mfma_f32_16x16x32_bf16(a0, bf[nt], acc[nt], 0, 0, 0);
#pragma unroll
    for (int nt = 0; nt < NT; nt++)
      acc[nt] = __builtin_amdgcn_mfma_f32_16x16x32_bf16(a1, bf[NT + nt], acc[nt], 0, 0, 0);
  }
  // C/D frag: col(oc) = lane&15, row(px) = quad*4 + reg
#pragma unroll
  for (int nt = 0; nt < NT; nt++) {
    int oc_l = nt * 16 + mrow;
#pragma unroll
    for (int reg = 0; reg < 4; reg++) {
      int pxr = w * 16 + quad * 4 + reg;
      ct[oc_l * 65 + pxr] = acc[nt][reg];
    }
  }
  __syncthreads();
  for (int i = tid; i < OC * 64; i += 256) {
    int oc = i >> 6, p2 = i & 63;
    int g2 = blockIdx.x * 64 + p2;
    int n2 = g2 / HW, px2 = g2 % HW;
    dst[((size_t)n2 * OC + oc) * HW + px2] = ct[oc * 65 + p2] + bias[oc];
  }
}

// ---------------------------------------------------------------------------
// FUSED deformable conv (def3 + def5): LDS half-frame gather + bf16 MFMA,
// c-split x2. PARITY-INTERLEAVED LDS layout: 16B slot s of row r lives at
// byte (r&~1)*64 + ((s^((r>>1)&3))<<5) + ((r&1)<<4). Even rows occupy banks
// {0-3,8-11,16-19,24-27}, odd rows the complement -> gather reads with mixed
// row parity spread over ALL 32 banks (the old 64B-stride layout confined
// each parity class to a 16-bank half: 6.0M conflict cycles). Zero extra LDS.
// ---------------------------------------------------------------------------
__global__ __launch_bounds__(448, 6) void k_deform_mfma(
    const __hip_bfloat16* __restrict__ xTbP,
    const float* __restrict__ off3b, const float* __restrict__ off5b,
    const __hip_bfloat16* __restrict__ wBd,
    float* __restrict__ dsum, float* __restrict__ pext)
{
  __shared__ __align__(128) short Fr[784 * 32];  // interleaved bf16 half-frame
  const int tid = threadIdx.x;
  const int w = tid >> 6, lane = tid & 63;
  const int quad = lane >> 4, mrow = lane & 15;
  const int part = blockIdx.x, n = blockIdx.y, csel = blockIdx.z;

  // stage half-frame (channels csel*32..+32) in interleaved layout
  {
    const short* xb = (const short*)xTbP + (size_t)n * PADPX * 64;
    for (int idx = tid; idx < 784 * 4; idx += 448) {
      int px = idx >> 2, s = idx & 3;
      int py = px / WD, pxc = px % WD;
      float4 v = ((const float4*)(xb + ((py + 2) * 32 + (pxc + 2)) * 64))[csel * 4 + s];
      int slot = (px & ~1) * 4 + ((s ^ ((px >> 1) & 3)) << 1) + (px & 1);
      ((float4*)Fr)[slot] = v;
    }
  }
  __syncthreads();

  const char* F = (const char*)Fr;
  const int px0 = (part * 7 + w) * 16;
  const int pxg = px0 + mrow;
  const int y_g = pxg / WD, x_g = pxg % WD;
  const float* ob3 = off3b + (size_t)n * 18 * HW + pxg;
  const float* ob5 = off5b + (size_t)n * 50 * HW + pxg;

  f32x4 acc[4];
#pragma unroll
  for (int nt = 0; nt < 4; nt++) acc[nt] = (f32x4){0.f, 0.f, 0.f, 0.f};

#pragma unroll 2
  for (int tap = 0; tap < 34; tap++) {
    // B frags for this tap & c-half (L2-resident)
    const short* bw = (const short*)wBd +
        ((size_t)(tap * 2 + csel) * 4) * 512 + lane * 8;
    short8 bfrag[4];
#pragma unroll
    for (int nt = 0; nt < 4; nt++) bfrag[nt] = *(const short8*)(bw + nt * 512);

    int kk, ty, tx, PADl; const float* obp;
    if (tap < 9) { kk = tap; ty = kk / 3; tx = kk % 3; PADl = 1; obp = ob3; }
    else { kk = tap - 9; ty = kk / 5; tx = kk % 5; PADl = 2; obp = ob5; }
    float offy = obp[(2 * kk) * HW];
    float offx = obp[(2 * kk + 1) * HW];
    float py = (float)(y_g + ty - PADl) + offy;
    float pxx = (float)(x_g + tx - PADl) + offx;
    float fy = floorf(py), fx = floorf(pxx);
    int y0 = (int)fy, x0 = (int)fx;
    float ly = py - fy, lx = pxx - fx;
    int y1 = y0 + 1, x1 = x0 + 1;
    float vy0 = (y0 >= 0 && y0 < WD) ? 1.f : 0.f;
    float vy1 = (y1 >= 0 && y1 < WD) ? 1.f : 0.f;
    float vx0 = (x0 >= 0 && x0 < WD) ? 1.f : 0.f;
    float vx1 = (x1 >= 0 && x1 < WD) ? 1.f : 0.f;
    float w00 = (1.f - ly) * (1.f - lx) * vy0 * vx0;
    float w01 = (1.f - ly) * lx * vy0 * vx1;
    float w10 = ly * (1.f - lx) * vy1 * vx0;
    float w11 = ly * lx * vy1 * vx1;
    int cy0 = min(max(y0, 0), WD - 1), cy1 = min(max(y1, 0), WD - 1);
    int cx0 = min(max(x0, 0), WD - 1), cx1 = min(max(x1, 0), WD - 1);
    int r00 = cy0 * WD + cx0, r01 = cy0 * WD + cx1;
    int r10 = cy1 * WD + cx0, r11 = cy1 * WD + cx1;
    // interleaved corner reads (quad = 16B slot index)
#define LADDR(r) ((r & ~1) * 64 + (((quad ^ ((r >> 1) & 3))) << 5) + ((r & 1) << 4))
    short8 c00 = *(const short8*)(F + LADDR(r00));
    short8 c01 = *(const short8*)(F + LADDR(r01));
    short8 c10 = *(const short8*)(F + LADDR(r10));
    short8 c11 = *(const short8*)(F + LADDR(r11));
#undef LADDR
    short8 a0;
#pragma unroll
    for (int j = 0; j < 8; j++) {
      float g0 = b2f(c00[j]) * w00 + b2f(c01[j]) * w01 +
                 b2f(c10[j]) * w10 + b2f(c11[j]) * w11;
      __hip_bfloat16 q0 = __float2bfloat16(g0);
      a0[j] = *(short*)&q0;
    }
#pragma unroll
    for (int nt = 0; nt < 4; nt++)
      acc[nt] = __builtin_amdgcn_mfma_f32_16x16x32_bf16(a0, bfrag[nt], acc[nt], 0, 0, 0);
  }

  // C/D frag: col(oc) = lane&15 (+nt*16), row(px) = quad*4 + reg
  float* P = csel ? pext : dsum;
#pragma unroll
  for (int nt = 0; nt < 4; nt++)
    *(f32x4*)(P + ((size_t)n * 64 + nt * 16 + mrow) * HW + px0 + quad * 4) =
        acc[nt];
}

// ---------------------------------------------------------------------------
// maxpool 3x3 + 1x1 conv (64->64, BN folded) as bf16 MFMA + partial-sum +
// diff epilogue. Grid 686 x 256 (4 waves); wave = 16px x 64oc tile.
// Per lane: maxpool for its 16 fragment channels (2 chunks x 8), bf16,
// 8 MFMAs; epilogue reads dsum/pext/xpre as f32x4 (D-frag is px-contiguous)
// and writes |d3+d5+d_avg-3*xpre| back to dsum. No LDS, no barriers.
// ---------------------------------------------------------------------------
__global__ __launch_bounds__(256) void k_davg_diff(
    const float* __restrict__ frames, const __hip_bfloat16* __restrict__ c1B,
    const float* __restrict__ B3, float* __restrict__ dsum,
    const float* __restrict__ pext)
{
  const int tid = threadIdx.x;
  const int w = tid >> 6, lane = tid & 63;
  const int quad = lane >> 4, mrow = lane & 15;
  const int gpx = blockIdx.x * 64 + w * 16 + mrow;  // wave tiles don't cross n
  const int n = gpx / HW, px = gpx % HW;
  const int fpost = (n / 7) * 8 + (n % 7) + 1;
  const int fpre = fpost - 1;
  const int y = px / WD, x = px % WD;
  int lin[9]; bool okm[9];
#pragma unroll
  for (int t2 = 0; t2 < 9; t2++) {
    int iy = y + t2 / 3 - 1, ix = x + t2 % 3 - 1;
    okm[t2] = iy >= 0 && iy < WD && ix >= 0 && ix < WD;
    lin[t2] = min(max(iy, 0), WD - 1) * WD + min(max(ix, 0), WD - 1);
  }
  const float* sb = frames + (size_t)fpost * 64 * HW;
  f32x4 acc[4];
#pragma unroll
  for (int nt = 0; nt < 4; nt++) acc[nt] = (f32x4){0.f, 0.f, 0.f, 0.f};

#pragma unroll
  for (int chunk = 0; chunk < 2; chunk++) {
    short8 aM;
#pragma unroll
    for (int j = 0; j < 8; j++) {
      const float* p = sb + (chunk * 32 + quad * 8 + j) * HW;
      float m = -1e30f;
#pragma unroll
      for (int t2 = 0; t2 < 9; t2++) {
        float v = okm[t2] ? p[lin[t2]] : -1e30f;
        m = fmaxf(m, v);
      }
      __hip_bfloat16 h = __float2bfloat16(m);
      aM[j] = *(short*)&h;
    }
    const short* bw = (const short*)c1B + (size_t)(chunk * 4) * 512 + lane * 8;
#pragma unroll
    for (int nt = 0; nt < 4; nt++) {
      short8 bf = *(const short8*)(bw + nt * 512);
      acc[nt] = __builtin_amdgcn_mfma_f32_16x16x32_bf16(aM, bf, acc[nt], 0, 0, 0);
    }
  }
  // epilogue: D-frag row(px) = quad*4+reg, col(oc) = nt*16+mrow
  const int pxb = (px - mrow) + quad * 4;
#pragma unroll
  for (int nt = 0; nt < 4; nt++) {
    int oc = nt * 16 + mrow;
    size_t base = ((size_t)n * 64 + oc) * HW + pxb;
    f32x4 ds = *(const f32x4*)(dsum + base);
    f32x4 pe = *(const f32x4*)(pext + base);
    f32x4 xp4 = *(const f32x4*)(frames + ((size_t)fpre * 64 + oc) * HW + pxb);
    float b3 = B3[oc];
    f32x4 o;
#pragma unroll
    for (int r = 0; r < 4; r++)
      o[r] = fabsf(ds[r] + pe[r] + acc[nt][r] + b3 - 3.f * xp4[r]);
    *(f32x4*)(dsum + base) = o;
  }
}

// ---------------------------------------------------------------------------
// Spatial mean of cat = [diff frames | t_out] per (nt, c). 4 c per block.
// ---------------------------------------------------------------------------
__global__ __launch_bounds__(256) void k_gmean(
    const float* __restrict__ dsum, const float* __restrict__ t_out,
    float* __restrict__ gmean)
{
  const int nt = blockIdx.x, cg = blockIdx.y;
  const int c = cg * 4 + (threadIdx.x >> 6), lane = threadIdx.x & 63;
  const int b = nt >> 3, tt = nt & 7;
  const float* p = (tt < 7) ? (dsum + (size_t)((b * 7 + tt) * 64 + c) * HW)
                            : (t_out + (size_t)(b * 64 + c) * HW);
  float s = 0.f;
  for (int i = lane; i < HW; i += 64) s += p[i];
#pragma unroll
  for (int o = 32; o > 0; o >>= 1) s += __shfl_down(s, o, 64);
  if (lane == 0) gmean[nt * 64 + c] = s * (1.f / HW);
}

// ---------------------------------------------------------------------------
// Gate: 1x1 conv 64->256 + sigmoid; store mult.
// ---------------------------------------------------------------------------
__global__ __launch_bounds__(256) void k_gate(
    const float* __restrict__ gmean, const float* __restrict__ gwT,
    const float* __restrict__ Bg, float* __restrict__ mult)
{
  __shared__ float gm[64];
  const int nt = blockIdx.x, co = threadIdx.x;
  if (co < 64) gm[co] = gmean[nt * 64 + co];
  __syncthreads();
  float a = 0.f;
#pragma unroll 8
  for (int c = 0; c < 64; c++) a += gm[c] * gwT[c * 256 + co];
  float pre = a + Bg[co];
  mult[nt * 256 + co] = 0.5f + 1.f / (1.f + expf(-pre));
}

// ---------------------------------------------------------------------------
// out = x * mult[nt,co]
// ---------------------------------------------------------------------------
__global__ void k_apply(const float* __restrict__ x,
                        const float* __restrict__ mult,
                        float* __restrict__ outp)
{
  const int i = blockIdx.x * 256 + threadIdx.x;
  const int plane = i / 196;
  const float m = mult[plane];
  float4 v = ((const float4*)x)[i];
  v.x *= m; v.y *= m; v.z *= m; v.w *= m;
  ((float4*)outp)[i] = v;
}

// ---------------------------------------------------------------------------
extern "C" void kernel_launch(void* const* d_in, const int* in_sizes, int n_in,
                              void* d_out, int out_size, void* d_ws, size_t ws_size,
                              hipStream_t stream)
{
  const float* x       = (const float*)d_in[0];
  const float* w_down  = (const float*)d_in[1];
  const float* b_down  = (const float*)d_in[2];
  const float* bn1_g   = (const float*)d_in[3];
  const float* bn1_b   = (const float*)d_in[4];
  const float* bn1_m   = (const float*)d_in[5];
  const float* bn1_v   = (const float*)d_in[6];
  const float* tconv_w = (const float*)d_in[7];
  const float* tconv_b = (const float*)d_in[8];
  const float* bnt_g   = (const float*)d_in[9];
  const float* bnt_b   = (const float*)d_in[10];
  const float* bnt_m   = (const float*)d_in[11];
  const float* bnt_v   = (const float*)d_in[12];
  const float* off3_w  = (const float*)d_in[13];
  const float* off3_b  = (const float*)d_in[14];
  const float* def3_w  = (const float*)d_in[15];
  const float* off5_w  = (const float*)d_in[16];
  const float* off5_b  = (const float*)d_in[17];
  const float* def5_w  = (const float*)d_in[18];
  const float* conv1_w = (const float*)d_in[19];
  const float* conv1_b = (const float*)d_in[20];
  const float* bn3_g   = (const float*)d_in[21];
  const float* bn3_b   = (const float*)d_in[22];
  const float* bn3_m   = (const float*)d_in[23];
  const float* bn3_v   = (const float*)d_in[24];
  const float* conv_w  = (const float*)d_in[25];
  const float* conv_b  = (const float*)d_in[26];
  const float* bn2_g   = (const float*)d_in[27];
  const float* bn2_b   = (const float*)d_in[28];
  const float* bn2_m   = (const float*)d_in[29];
  const float* bn2_v   = (const float*)d_in[30];

  float* ws = (float*)d_ws;
  float* out_b  = ws; ws += 64 * 64 * HW;
  float* U      = ws; ws += 8 * 192 * HW;
  float* t_out  = ws; ws += 8 * 64 * HW;
  float* off3b  = ws; ws += 56 * 18 * HW;
  float* off5b  = ws; ws += 56 * 50 * HW;
  float* dsum   = ws; ws += PLANE;
  float* pext   = ws; ws += PLANE;
  float* gmean  = ws; ws += 64 * 64;
  float* multb  = ws; ws += 64 * 256;
  float* bias1  = ws; ws += 64;
  float* wtT    = ws; ws += 192 * 9 * 64;
  float* AtBt   = ws; ws += 128;
  float* B3     = ws; ws += 64;
  float* gwT    = ws; ws += 64 * 256;
  float* Bg     = ws; ws += 256;
  __hip_bfloat16* wdB  = (__hip_bfloat16*)ws; ws += 16384;   // 32768 bf16
  __hip_bfloat16* wBs3 = (__hip_bfloat16*)ws; ws += 9216;    // 18432 bf16
  __hip_bfloat16* wBs5 = (__hip_bfloat16*)ws; ws += 51200;   // 102400 bf16
  __hip_bfloat16* wBd  = (__hip_bfloat16*)ws; ws += 69632;   // 139264 bf16
  __hip_bfloat16* c1B  = (__hip_bfloat16*)ws; ws += 2048;    // 4096 bf16
  __hip_bfloat16* xTbP = (__hip_bfloat16*)ws; ws += 56 * PADPX * 64 / 2;

  k_prep<<<256, 256, 0, stream>>>(
      w_down, b_down, bn1_g, bn1_b, bn1_m, bn1_v,
      tconv_w, tconv_b, bnt_g, bnt_b, bnt_m, bnt_v,
      off3_w, def3_w, off5_w, def5_w,
      conv1_w, conv1_b, bn3_g, bn3_b, bn3_m, bn3_v,
      conv_w, conv_b, bn2_g, bn2_b, bn2_m, bn2_v,
      wdB, bias1, wtT, AtBt, wBs3, wBs5, wBd, c1B,
      B3, gwT, Bg);
  k_zerohalo<<<420, 256, 0, stream>>>((float4*)xTbP);

  k_down<<<784, 256, 0, stream>>>(x, wdB, bias1, out_b, xTbP);
  k_makeU<<<1568, 256, 0, stream>>>(out_b, U);
  k_tconv<<<dim3(8, 4, 16), 256, 0, stream>>>(U, wtT, AtBt, t_out);
  // 686 blocks of 64 px each (43904 = 686*64 exact)
  k_offconv_mfma<3, 1, 18, 2><<<686, 256, 0, stream>>>(xTbP, wBs3, off3_b, off3b);
  k_offconv_mfma<5, 2, 50, 4><<<686, 256, 0, stream>>>(xTbP, wBs5, off5_b, off5b);
  // 7 parts x 56 frames x 2 c-halves, 7 waves/block, half-frame in LDS
  k_deform_mfma<<<dim3(7, 56, 2), 448, 0, stream>>>(xTbP, off3b, off5b, wBd,
                                                    dsum, pext);
  k_davg_diff<<<686, 256, 0, stream>>>(out_b, c1B, B3, dsum, pext);
  k_gmean<<<dim3(64, 16), 256, 0, stream>>>(dsum, t_out, gmean);
  k_gate<<<64, 256, 0, stream>>>(gmean, gwT, Bg, multb);
  k_apply<<<12544, 256, 0, stream>>>(x, multb, (float*)d_out);
}

// Round 7
// 346.576 us; speedup vs baseline: 1.7090x; 1.1643x over previous
//
#include <hip/hip_runtime.h>
#include <hip/hip_bf16.h>

#define HW 784
#define WD 28
#define NPX (56 * 784)         // 43904 deform/offconv pixels
#define PLANE (56 * 64 * 784)  // 2,809,856 floats: one full plane
#define PADPX 1024             // 32x32 padded spatial (halo 2)

using short8 = __attribute__((ext_vector_type(8))) short;
using f32x4  = __attribute__((ext_vector_type(4))) float;

__device__ __forceinline__ float b2f(short s)
{
  return __uint_as_float(((unsigned)(unsigned short)s) << 16);
}

// ---------------------------------------------------------------------------
// Prep: fold BN into weight layouts; MFMA-fragment-order bf16 weights for
// offset convs (wBs), fused deform (wBd), down conv (wdB, hi/lo split) and
// davg 1x1 conv (c1B). Also zeroes the gate-mean accumulator.
// Frag layout: B[k=chunk*32+(lane>>4)*8+j][oc=nt*16+(lane&15)].
// ---------------------------------------------------------------------------
__global__ void k_prep(
    const float* __restrict__ w_down, const float* __restrict__ b_down,
    const float* __restrict__ bn1_g, const float* __restrict__ bn1_b,
    const float* __restrict__ bn1_m, const float* __restrict__ bn1_v,
    const float* __restrict__ tconv_w, const float* __restrict__ tconv_b,
    const float* __restrict__ bnt_g, const float* __restrict__ bnt_b,
    const float* __restrict__ bnt_m, const float* __restrict__ bnt_v,
    const float* __restrict__ off3_w, const float* __restrict__ def3_w,
    const float* __restrict__ off5_w, const float* __restrict__ def5_w,
    const float* __restrict__ conv1_w, const float* __restrict__ conv1_b,
    const float* __restrict__ bn3_g, const float* __restrict__ bn3_b,
    const float* __restrict__ bn3_m, const float* __restrict__ bn3_v,
    const float* __restrict__ conv_w, const float* __restrict__ conv_b,
    const float* __restrict__ bn2_g, const float* __restrict__ bn2_b,
    const float* __restrict__ bn2_m, const float* __restrict__ bn2_v,
    __hip_bfloat16* __restrict__ wdB, float* __restrict__ bias1,
    float* __restrict__ wtT, float* __restrict__ AtBt,
    __hip_bfloat16* __restrict__ wBs3, __hip_bfloat16* __restrict__ wBs5,
    __hip_bfloat16* __restrict__ wBd, __hip_bfloat16* __restrict__ c1B,
    float* __restrict__ B3,
    float* __restrict__ gwT, float* __restrict__ Bg,
    float* __restrict__ gacc)
{
  const int tid = blockIdx.x * blockDim.x + threadIdx.x;
  const int nth = gridDim.x * blockDim.x;
  for (int i = tid; i < 64 * 64; i += nth) gacc[i] = 0.f;
  // down-conv MFMA B-frags, hi/lo split: chunks 0-7 = hi(w), 8-15 = lo(w)
  for (int i = tid; i < 16 * 4 * 512; i += nth) {
    int j = i & 7; int lane = (i >> 3) & 63;
    int rest = i >> 9; int nt = rest & 3; int ch = rest >> 2;
    int c = (ch & 7) * 32 + ((lane >> 4) << 3) + j;
    int oc = nt * 16 + (lane & 15);
    float s = bn1_g[oc] / sqrtf(bn1_v[oc] + 1e-5f);
    float wv = w_down[oc * 256 + c] * s;
    __hip_bfloat16 h = __float2bfloat16(wv);
    float hi = b2f(*(short*)&h);
    wdB[i] = (ch < 8) ? h : __float2bfloat16(wv - hi);
  }
  for (int i = tid; i < 64; i += nth) {
    float s = bn1_g[i] / sqrtf(bn1_v[i] + 1e-5f);
    bias1[i] = (b_down[i] - bn1_m[i]) * s + bn1_b[i];
  }
  for (int i = tid; i < 192 * 9 * 64; i += nth) {
    int cc = i / (9 * 64); int tap = (i / 64) % 9; int o = i & 63;
    int dt = cc >> 6, c = cc & 63;
    wtT[i] = tconv_w[o * 1728 + c * 27 + dt * 9 + tap];
  }
  for (int i = tid; i < 64; i += nth) {
    float s = bnt_g[i] / sqrtf(bnt_v[i] + 1e-5f);
    AtBt[i] = s * 0.125f;
    AtBt[64 + i] = (tconv_b[i] - bnt_m[i]) * s + bnt_b[i];
  }
  // off3 MFMA B-frags: K2=9, NT=2 (ocpad 32)
  for (int i = tid; i < 9 * 2 * 2 * 512; i += nth) {
    int j = i & 7; int lane = (i >> 3) & 63;
    int rest = i >> 9; int nt = rest % 2; rest /= 2;
    int chunk = rest & 1; int tap = rest >> 1;
    int c = chunk * 32 + ((lane >> 4) << 3) + j;
    int oc = nt * 16 + (lane & 15);
    float v = (oc < 18) ? off3_w[oc * 576 + c * 9 + tap] : 0.f;
    wBs3[i] = __float2bfloat16(v);
  }
  // off5 MFMA B-frags: K2=25, NT=4 (ocpad 64)
  for (int i = tid; i < 25 * 2 * 4 * 512; i += nth) {
    int j = i & 7; int lane = (i >> 3) & 63;
    int rest = i >> 9; int nt = rest % 4; rest /= 4;
    int chunk = rest & 1; int tap = rest >> 1;
    int c = chunk * 32 + ((lane >> 4) << 3) + j;
    int oc = nt * 16 + (lane & 15);
    float v = (oc < 50) ? off5_w[oc * 1600 + c * 25 + tap] : 0.f;
    wBs5[i] = __float2bfloat16(v);
  }
  // fused deform B-frags: 34 taps (0..8 def3, 9..33 def5), NT=4
  for (int i = tid; i < 34 * 2 * 4 * 512; i += nth) {
    int j = i & 7; int lane = (i >> 3) & 63;
    int rest = i >> 9; int nt = rest & 3; rest >>= 2;
    int chunk = rest & 1; int tap = rest >> 1;
    int c = chunk * 32 + ((lane >> 4) << 3) + j;
    int oc = nt * 16 + (lane & 15);
    float v = (tap < 9) ? def3_w[oc * 576 + c * 9 + tap]
                        : def5_w[oc * 1600 + c * 25 + (tap - 9)];
    wBd[i] = __float2bfloat16(v);
  }
  // davg 1x1 conv MFMA B-frags: K=64 (2 chunks), NT=4, BN folded
  for (int i = tid; i < 2 * 4 * 512; i += nth) {
    int j = i & 7; int lane = (i >> 3) & 63;
    int rest = i >> 9; int nt = rest & 3; int chunk = rest >> 2;
    int c = chunk * 32 + ((lane >> 4) << 3) + j;
    int oc = nt * 16 + (lane & 15);
    float s = bn3_g[oc] / sqrtf(bn3_v[oc] + 1e-5f);
    c1B[i] = __float2bfloat16(conv1_w[oc * 64 + c] * s);
  }
  for (int i = tid; i < 64; i += nth) {
    float s = bn3_g[i] / sqrtf(bn3_v[i] + 1e-5f);
    B3[i] = (conv1_b[i] - bn3_m[i]) * s + bn3_b[i];
  }
  for (int i = tid; i < 64 * 256; i += nth) {
    int c = i >> 8, co = i & 255;
    float s = bn2_g[co] / sqrtf(bn2_v[co] + 1e-5f);
    gwT[i] = conv_w[co * 64 + c] * s;
  }
  for (int i = tid; i < 256; i += nth) {
    float s = bn2_g[i] / sqrtf(bn2_v[i] + 1e-5f);
    Bg[i] = (conv_b[i] - bn2_m[i]) * s + bn2_b[i];
  }
}

// ---------------------------------------------------------------------------
// Zero ONLY the halo of the padded bf16 image (interior is fully overwritten
// by k_down's epilogue every call). 56 frames x 240 halo slots x 128 B.
// ---------------------------------------------------------------------------
__global__ void k_zerohalo(float4* __restrict__ p)
{
  const int i = blockIdx.x * 256 + threadIdx.x;   // < 107520 = 56*240*8
  const int n = i / 1920, rem = i % 1920;
  const int sl = rem >> 3, q = rem & 7;
  int row, col;
  if (sl < 128) {
    int r = sl >> 5;
    row = (r & 1) + ((r >> 1) * 30);
    col = sl & 31;
  } else {
    int t2 = sl - 128;
    row = 2 + (t2 >> 2);
    int qq = t2 & 3;
    col = (qq & 1) + ((qq >> 1) * 30);
  }
  p[((size_t)n * 1024 + row * 32 + col) * 8 + q] =
      make_float4(0.f, 0.f, 0.f, 0.f);
}

// ---------------------------------------------------------------------------
// 1x1 down conv 256->64 as bf16 MFMA implicit GEMM with hi/lo split
// precision. Epilogue: f32 out_b + padded bf16 xTbP (fused xpose).
// ---------------------------------------------------------------------------
__global__ __launch_bounds__(256) void k_down(
    const float* __restrict__ x, const __hip_bfloat16* __restrict__ wdB,
    const float* __restrict__ bias1, float* __restrict__ out,
    __hip_bfloat16* __restrict__ xTbP)
{
  __shared__ float ct[64 * 65];
  const int tid = threadIdx.x;
  const int w = tid >> 6, lane = tid & 63;
  const int quad = lane >> 4, mrow = lane & 15;
  const int gpx = blockIdx.x * 64 + w * 16 + mrow;  // tiles never cross frames
  const int f = gpx / HW, px = gpx % HW;
  const float* xp = x + (size_t)f * 256 * HW + px;
  f32x4 acc[4];
#pragma unroll
  for (int nt = 0; nt < 4; nt++) acc[nt] = (f32x4){0.f, 0.f, 0.f, 0.f};

#pragma unroll
  for (int ch = 0; ch < 8; ch++) {
    short8 aH, aL;
#pragma unroll
    for (int j = 0; j < 8; j++) {
      float xv = xp[(ch * 32 + quad * 8 + j) * HW];
      __hip_bfloat16 h = __float2bfloat16(xv);
      aH[j] = *(short*)&h;
      __hip_bfloat16 l = __float2bfloat16(xv - b2f(aH[j]));
      aL[j] = *(short*)&l;
    }
    const short* bwH = (const short*)wdB + (size_t)(ch * 4) * 512 + lane * 8;
    const short* bwL = bwH + 16384;          // chunks 8..15 = lo(w)
#pragma unroll
    for (int nt = 0; nt < 4; nt++) {
      short8 bH = *(const short8*)(bwH + nt * 512);
      short8 bL = *(const short8*)(bwL + nt * 512);
      acc[nt] = __builtin_amdgcn_mfma_f32_16x16x32_bf16(aH, bH, acc[nt], 0, 0, 0);
      acc[nt] = __builtin_amdgcn_mfma_f32_16x16x32_bf16(aL, bH, acc[nt], 0, 0, 0);
      acc[nt] = __builtin_amdgcn_mfma_f32_16x16x32_bf16(aH, bL, acc[nt], 0, 0, 0);
    }
  }
  // C/D frag: col(oc) = lane&15, row(px) = quad*4 + reg
#pragma unroll
  for (int nt = 0; nt < 4; nt++) {
    int oc_l = nt * 16 + mrow;
#pragma unroll
    for (int reg = 0; reg < 4; reg++)
      ct[oc_l * 65 + w * 16 + quad * 4 + reg] = acc[nt][reg];
  }
  __syncthreads();
  for (int i = tid; i < 4096; i += 256) {        // out_b: [f][oc][px]
    int oc = i >> 6, p2 = i & 63;
    int g2 = blockIdx.x * 64 + p2;
    int f2 = g2 / HW, px2 = g2 % HW;
    out[((size_t)f2 * 64 + oc) * HW + px2] = ct[oc * 65 + p2] + bias1[oc];
  }
  for (int i = tid; i < 4096; i += 256) {        // xTbP: post frames only
    int p2 = i >> 6, oc = i & 63;
    int g2 = blockIdx.x * 64 + p2;
    int f2 = g2 / HW, px2 = g2 % HW;
    if (f2 & 7) {
      int n = (f2 >> 3) * 7 + (f2 & 7) - 1;
      int py = px2 / WD, pxc = px2 % WD;
      __hip_bfloat16 q = __float2bfloat16(ct[oc * 65 + p2] + bias1[oc]);
      ((short*)xTbP)[((size_t)n * PADPX + (py + 2) * 32 + (pxc + 2)) * 64 + oc] =
          *(short*)&q;
    }
  }
}

// ---------------------------------------------------------------------------
// Rectangle sums per (frame, channel) of out_b: 9 classes (ry,cx) with
// Ry(0)=rows 0..26, Ry(1)=all, Ry(2)=rows 1..27 (cols likewise). These are
// exactly sum_px of the 3x3-conv's masked shifted inputs — mean(tconv) is a
// linear contraction of them (k_tmean). Replaces k_makeU + k_tconv.
// ---------------------------------------------------------------------------
__global__ __launch_bounds__(256) void k_rsum(
    const float* __restrict__ out_b, float* __restrict__ Rm)
{
  const int w = threadIdx.x >> 6, lane = threadIdx.x & 63;
  const int idx = blockIdx.x * 4 + w;        // (f,c): 4096 total
  const float* p = out_b + (size_t)idx * HW;
  float a[9];
#pragma unroll
  for (int k = 0; k < 9; k++) a[k] = 0.f;
  for (int i = lane; i < HW; i += 64) {
    float v = p[i];
    int row = i / WD, col = i % WD;
    float mr0 = (row < WD - 1) ? 1.f : 0.f, mr2 = (row > 0) ? 1.f : 0.f;
    float mc0 = (col < WD - 1) ? 1.f : 0.f, mc2 = (col > 0) ? 1.f : 0.f;
    float v0 = v * mc0, v2 = v * mc2;
    a[0] += v0 * mr0; a[1] += v * mr0; a[2] += v2 * mr0;
    a[3] += v0;       a[4] += v;       a[5] += v2;
    a[6] += v0 * mr2; a[7] += v * mr2; a[8] += v2 * mr2;
  }
#pragma unroll
  for (int k = 0; k < 9; k++) {
#pragma unroll
    for (int o = 32; o > 0; o >>= 1) a[k] += __shfl_down(a[k], o, 64);
  }
  if (lane == 0) {
#pragma unroll
    for (int k = 0; k < 9; k++) Rm[(size_t)idx * 9 + k] = a[k];
  }
}

// ---------------------------------------------------------------------------
// t_out spatial SUM per (b, oc) from rect sums: U rects are linear combos of
// frame rects; contract with wtT; write At*tot + 784*Bt into gacc[b*8+7].
// ---------------------------------------------------------------------------
__global__ __launch_bounds__(256) void k_tmean(
    const float* __restrict__ Rm, const float* __restrict__ wtT,
    const float* __restrict__ AtBt, float* __restrict__ gacc)
{
  __shared__ float U[3 * 576];
  __shared__ float ps[4][64];
  const int b = blockIdx.x, tid = threadIdx.x;
  for (int i = tid; i < 576; i += 256) {
    float s = 0.f;
#pragma unroll
    for (int t = 0; t < 8; t++) s += Rm[(size_t)(b * 8 + t) * 576 + i];
    U[0 * 576 + i] = s - Rm[(size_t)(b * 8 + 7) * 576 + i];
    U[1 * 576 + i] = s;
    U[2 * 576 + i] = s - Rm[(size_t)(b * 8 + 0) * 576 + i];
  }
  __syncthreads();
  const int oc = tid & 63, part = tid >> 6;
  float acc = 0.f;
  for (int dt = 0; dt < 3; dt++)
    for (int cL = 0; cL < 16; cL++) {
      int cc = dt * 64 + part * 16 + cL;
      const float* wr = wtT + (size_t)cc * 9 * 64 + oc;
      const float* ur = U + dt * 576 + (part * 16 + cL) * 9;
#pragma unroll
      for (int t = 0; t < 9; t++) acc += wr[t * 64] * ur[t];
    }
  ps[part][oc] = acc;
  __syncthreads();
  if (tid < 64) {
    float tot = ps[0][tid] + ps[1][tid] + ps[2][tid] + ps[3][tid];
    gacc[(b * 8 + 7) * 64 + tid] = AtBt[tid] * tot + 784.f * AtBt[64 + tid];
  }
}

// ---------------------------------------------------------------------------
// Offset convs as implicit-GEMM bf16 MFMA (16x16x32). B-frags from global
// (L2-hot), no LDS staging, no mid-kernel barriers.
// ---------------------------------------------------------------------------
template <int KS, int PAD, int OC, int NT>
__global__ __launch_bounds__(256) void k_offconv_mfma(
    const __hip_bfloat16* __restrict__ xTbP,
    const __hip_bfloat16* __restrict__ wBs,
    const float* __restrict__ bias, float* __restrict__ dst)
{
  constexpr int K2 = KS * KS;
  __shared__ float ct[NT * 16 * 65];         // C tile [ocpad][px(64)+pad]
  const int tid = threadIdx.x;
  const int w = tid >> 6, lane = tid & 63;
  const int quad = lane >> 4, mrow = lane & 15;
  const int gpx = blockIdx.x * 64 + w * 16 + mrow;   // A-row pixel
  const int n = gpx / HW, px = gpx % HW;
  const int y = px / WD, x = px % WD;
  const short* xb = (const short*)xTbP + ((size_t)n * PADPX) * 64;
  f32x4 acc[NT];
#pragma unroll
  for (int nt = 0; nt < NT; nt++) acc[nt] = (f32x4){0.f, 0.f, 0.f, 0.f};

  for (int tap = 0; tap < K2; tap++) {
    const short* bw = (const short*)wBs + (size_t)tap * NT * 1024 + lane * 8;
    short8 bf[2 * NT];
#pragma unroll
    for (int q = 0; q < 2 * NT; q++) bf[q] = *(const short8*)(bw + q * 512);
    int ty = tap / KS, tx = tap % KS;
    int sp = (y + ty + (2 - PAD)) * 32 + (x + tx + (2 - PAD));
    const short* ap = xb + sp * 64 + quad * 8;
    short8 a0 = *(const short8*)(ap);
    short8 a1 = *(const short8*)(ap + 32);
#pragma unroll
    for (int nt = 0; nt < NT; nt++)
      acc[nt] = __builtin_amdgcn_mfma_f32_16x16x32_bf16(a0, bf[nt], acc[nt], 0, 0, 0);
#pragma unroll
    for (int nt = 0; nt < NT; nt++)
      acc[nt] = __builtin_amdgcn_mfma_f32_16x16x32_bf16(a1, bf[NT + nt], acc[nt], 0, 0, 0);
  }
  // C/D frag: col(oc) = lane&15, row(px) = quad*4 + reg
#pragma unroll
  for (int nt = 0; nt < NT; nt++) {
    int oc_l = nt * 16 + mrow;
#pragma unroll
    for (int reg = 0; reg < 4; reg++) {
      int pxr = w * 16 + quad * 4 + reg;
      ct[oc_l * 65 + pxr] = acc[nt][reg];
    }
  }
  __syncthreads();
  for (int i = tid; i < OC * 64; i += 256) {
    int oc = i >> 6, p2 = i & 63;
    int g2 = blockIdx.x * 64 + p2;
    int n2 = g2 / HW, px2 = g2 % HW;
    dst[((size_t)n2 * OC + oc) * HW + px2] = ct[oc * 65 + p2] + bias[oc];
  }
}

// ---------------------------------------------------------------------------
// FUSED deformable conv (def3 + def5): LDS half-frame gather + bf16 MFMA,
// c-split x2. R4 layout restored (simple XOR swizzle slot = s^(px&3)):
// R5's parity interleave cut conflicts 2x but cost more VALU than it saved.
// ---------------------------------------------------------------------------
__global__ __launch_bounds__(448, 6) void k_deform_mfma(
    const __hip_bfloat16* __restrict__ xTbP,
    const float* __restrict__ off3b, const float* __restrict__ off5b,
    const __hip_bfloat16* __restrict__ wBd,
    float* __restrict__ dsum, float* __restrict__ pext)
{
  __shared__ __align__(16) short Fr[784 * 32];   // swizzled bf16 half-frame
  const int tid = threadIdx.x;
  const int w = tid >> 6, lane = tid & 63;
  const int quad = lane >> 4, mrow = lane & 15;
  const int part = blockIdx.x, n = blockIdx.y, csel = blockIdx.z;

  // stage half-frame (channels csel*32..+32): slot s of row px at s^(px&3)
  {
    const short* xb = (const short*)xTbP + (size_t)n * PADPX * 64;
    for (int idx = tid; idx < 784 * 4; idx += 448) {
      int px = idx >> 2, s = idx & 3;
      int py = px / WD, pxc = px % WD;
      float4 v = ((const float4*)(xb + ((py + 2) * 32 + (pxc + 2)) * 64))[csel * 4 + s];
      ((float4*)Fr)[px * 4 + (s ^ (px & 3))] = v;
    }
  }
  __syncthreads();

  const char* F = (const char*)Fr;
  const int px0 = (part * 7 + w) * 16;
  const int pxg = px0 + mrow;
  const int y_g = pxg / WD, x_g = pxg % WD;
  const float* ob3 = off3b + (size_t)n * 18 * HW + pxg;
  const float* ob5 = off5b + (size_t)n * 50 * HW + pxg;

  f32x4 acc[4];
#pragma unroll
  for (int nt = 0; nt < 4; nt++) acc[nt] = (f32x4){0.f, 0.f, 0.f, 0.f};

#pragma unroll 2
  for (int tap = 0; tap < 34; tap++) {
    // B frags for this tap & c-half (L2-resident)
    const short* bw = (const short*)wBd +
        ((size_t)(tap * 2 + csel) * 4) * 512 + lane * 8;
    short8 bfrag[4];
#pragma unroll
    for (int nt = 0; nt < 4; nt++) bfrag[nt] = *(const short8*)(bw + nt * 512);

    int kk, ty, tx, PADl; const float* obp;
    if (tap < 9) { kk = tap; ty = kk / 3; tx = kk % 3; PADl = 1; obp = ob3; }
    else { kk = tap - 9; ty = kk / 5; tx = kk % 5; PADl = 2; obp = ob5; }
    float offy = obp[(2 * kk) * HW];
    float offx = obp[(2 * kk + 1) * HW];
    float py = (float)(y_g + ty - PADl) + offy;
    float pxx = (float)(x_g + tx - PADl) + offx;
    float fy = floorf(py), fx = floorf(pxx);
    int y0 = (int)fy, x0 = (int)fx;
    float ly = py - fy, lx = pxx - fx;
    int y1 = y0 + 1, x1 = x0 + 1;
    float vy0 = (y0 >= 0 && y0 < WD) ? 1.f : 0.f;
    float vy1 = (y1 >= 0 && y1 < WD) ? 1.f : 0.f;
    float vx0 = (x0 >= 0 && x0 < WD) ? 1.f : 0.f;
    float vx1 = (x1 >= 0 && x1 < WD) ? 1.f : 0.f;
    float w00 = (1.f - ly) * (1.f - lx) * vy0 * vx0;
    float w01 = (1.f - ly) * lx * vy0 * vx1;
    float w10 = ly * (1.f - lx) * vy1 * vx0;
    float w11 = ly * lx * vy1 * vx1;
    int cy0 = min(max(y0, 0), WD - 1), cy1 = min(max(y1, 0), WD - 1);
    int cx0 = min(max(x0, 0), WD - 1), cx1 = min(max(x1, 0), WD - 1);
    int r00 = cy0 * WD + cx0, r01 = cy0 * WD + cx1;
    int r10 = cy1 * WD + cx0, r11 = cy1 * WD + cx1;
    short8 c00 = *(const short8*)(F + r00 * 64 + ((quad ^ (r00 & 3)) << 4));
    short8 c01 = *(const short8*)(F + r01 * 64 + ((quad ^ (r01 & 3)) << 4));
    short8 c10 = *(const short8*)(F + r10 * 64 + ((quad ^ (r10 & 3)) << 4));
    short8 c11 = *(const short8*)(F + r11 * 64 + ((quad ^ (r11 & 3)) << 4));
    short8 a0;
#pragma unroll
    for (int j = 0; j < 8; j++) {
      float g0 = b2f(c00[j]) * w00 + b2f(c01[j]) * w01 +
                 b2f(c10[j]) * w10 + b2f(c11[j]) * w11;
      __hip_bfloat16 q0 = __float2bfloat16(g0);
      a0[j] = *(short*)&q0;
    }
#pragma unroll
    for (int nt = 0; nt < 4; nt++)
      acc[nt] = __builtin_amdgcn_mfma_f32_16x16x32_bf16(a0, bfrag[nt], acc[nt], 0, 0, 0);
  }

  // C/D frag: col(oc) = lane&15 (+nt*16), row(px) = quad*4 + reg
  float* P = csel ? pext : dsum;
#pragma unroll
  for (int nt = 0; nt < 4; nt++)
    *(f32x4*)(P + ((size_t)n * 64 + nt * 16 + mrow) * HW + px0 + quad * 4) =
        acc[nt];
}

// ---------------------------------------------------------------------------
// maxpool 3x3 + 1x1 conv (MFMA) + diff + IN-KERNEL spatial-sum reduction.
// The diff |d3+d5+d_avg-3*xpre| is consumed ONLY by the gate's spatial mean,
// so it is never written back: per wave (16 px, one frame), shfl-reduce over
// the 4 px-quads and atomicAdd one partial per oc into gacc[n -> b*8+t].
// Saves the 11 MB dsum write + 11 MB gmean re-read and kills k_gmean.
// ---------------------------------------------------------------------------
__global__ __launch_bounds__(256) void k_davg_diff(
    const float* __restrict__ frames, const __hip_bfloat16* __restrict__ c1B,
    const float* __restrict__ B3, const float* __restrict__ dsum,
    const float* __restrict__ pext, float* __restrict__ gacc)
{
  const int tid = threadIdx.x;
  const int w = tid >> 6, lane = tid & 63;
  const int quad = lane >> 4, mrow = lane & 15;
  const int gpx = blockIdx.x * 64 + w * 16 + mrow;  // wave tiles don't cross n
  const int n = gpx / HW, px = gpx % HW;
  const int fpost = (n / 7) * 8 + (n % 7) + 1;
  const int fpre = fpost - 1;
  const int y = px / WD, x = px % WD;
  int lin[9]; bool okm[9];
#pragma unroll
  for (int t2 = 0; t2 < 9; t2++) {
    int iy = y + t2 / 3 - 1, ix = x + t2 % 3 - 1;
    okm[t2] = iy >= 0 && iy < WD && ix >= 0 && ix < WD;
    lin[t2] = min(max(iy, 0), WD - 1) * WD + min(max(ix, 0), WD - 1);
  }
  const float* sb = frames + (size_t)fpost * 64 * HW;
  f32x4 acc[4];
#pragma unroll
  for (int nt = 0; nt < 4; nt++) acc[nt] = (f32x4){0.f, 0.f, 0.f, 0.f};

#pragma unroll
  for (int chunk = 0; chunk < 2; chunk++) {
    short8 aM;
#pragma unroll
    for (int j = 0; j < 8; j++) {
      const float* p = sb + (chunk * 32 + quad * 8 + j) * HW;
      float m = -1e30f;
#pragma unroll
      for (int t2 = 0; t2 < 9; t2++) {
        float v = okm[t2] ? p[lin[t2]] : -1e30f;
        m = fmaxf(m, v);
      }
      __hip_bfloat16 h = __float2bfloat16(m);
      aM[j] = *(short*)&h;
    }
    const short* bw = (const short*)c1B + (size_t)(chunk * 4) * 512 + lane * 8;
#pragma unroll
    for (int nt = 0; nt < 4; nt++) {
      short8 bf = *(const short8*)(bw + nt * 512);
      acc[nt] = __builtin_amdgcn_mfma_f32_16x16x32_bf16(aM, bf, acc[nt], 0, 0, 0);
    }
  }
  // D-frag row(px) = quad*4+reg, col(oc) = nt*16+mrow. Reduce |diff| over px.
  const int pxb = (px - mrow) + quad * 4;
  const int gi = ((n / 7) * 8 + (n % 7)) * 64;
#pragma unroll
  for (int nt = 0; nt < 4; nt++) {
    int oc = nt * 16 + mrow;
    size_t base = ((size_t)n * 64 + oc) * HW + pxb;
    f32x4 ds = *(const f32x4*)(dsum + base);
    f32x4 pe = *(const f32x4*)(pext + base);
    f32x4 xp4 = *(const f32x4*)(frames + ((size_t)fpre * 64 + oc) * HW + pxb);
    float b3 = B3[oc];
    float s = 0.f;
#pragma unroll
    for (int r = 0; r < 4; r++)
      s += fabsf(ds[r] + pe[r] + acc[nt][r] + b3 - 3.f * xp4[r]);
    s += __shfl_xor(s, 16, 64);
    s += __shfl_xor(s, 32, 64);
    if (quad == 0) atomicAdd(&gacc[gi + oc], s);
  }
}

// ---------------------------------------------------------------------------
// Gate: 1x1 conv 64->256 + sigmoid; gacc holds spatial SUMS (scale 1/784).
// ---------------------------------------------------------------------------
__global__ __launch_bounds__(256) void k_gate(
    const float* __restrict__ gacc, const float* __restrict__ gwT,
    const float* __restrict__ Bg, float* __restrict__ mult)
{
  __shared__ float gm[64];
  const int nt = blockIdx.x, co = threadIdx.x;
  if (co < 64) gm[co] = gacc[nt * 64 + co] * (1.f / 784.f);
  __syncthreads();
  float a = 0.f;
#pragma unroll 8
  for (int c = 0; c < 64; c++) a += gm[c] * gwT[c * 256 + co];
  float pre = a + Bg[co];
  mult[nt * 256 + co] = 0.5f + 1.f / (1.f + expf(-pre));
}

// ---------------------------------------------------------------------------
// out = x * mult[nt,co]
// ---------------------------------------------------------------------------
__global__ void k_apply(const float* __restrict__ x,
                        const float* __restrict__ mult,
                        float* __restrict__ outp)
{
  const int i = blockIdx.x * 256 + threadIdx.x;
  const int plane = i / 196;
  const float m = mult[plane];
  float4 v = ((const float4*)x)[i];
  v.x *= m; v.y *= m; v.z *= m; v.w *= m;
  ((float4*)outp)[i] = v;
}

// ---------------------------------------------------------------------------
extern "C" void kernel_launch(void* const* d_in, const int* in_sizes, int n_in,
                              void* d_out, int out_size, void* d_ws, size_t ws_size,
                              hipStream_t stream)
{
  const float* x       = (const float*)d_in[0];
  const float* w_down  = (const float*)d_in[1];
  const float* b_down  = (const float*)d_in[2];
  const float* bn1_g   = (const float*)d_in[3];
  const float* bn1_b   = (const float*)d_in[4];
  const float* bn1_m   = (const float*)d_in[5];
  const float* bn1_v   = (const float*)d_in[6];
  const float* tconv_w = (const float*)d_in[7];
  const float* tconv_b = (const float*)d_in[8];
  const float* bnt_g   = (const float*)d_in[9];
  const float* bnt_b   = (const float*)d_in[10];
  const float* bnt_m   = (const float*)d_in[11];
  const float* bnt_v   = (const float*)d_in[12];
  const float* off3_w  = (const float*)d_in[13];
  const float* off3_b  = (const float*)d_in[14];
  const float* def3_w  = (const float*)d_in[15];
  const float* off5_w  = (const float*)d_in[16];
  const float* off5_b  = (const float*)d_in[17];
  const float* def5_w  = (const float*)d_in[18];
  const float* conv1_w = (const float*)d_in[19];
  const float* conv1_b = (const float*)d_in[20];
  const float* bn3_g   = (const float*)d_in[21];
  const float* bn3_b   = (const float*)d_in[22];
  const float* bn3_m   = (const float*)d_in[23];
  const float* bn3_v   = (const float*)d_in[24];
  const float* conv_w  = (const float*)d_in[25];
  const float* conv_b  = (const float*)d_in[26];
  const float* bn2_g   = (const float*)d_in[27];
  const float* bn2_b   = (const float*)d_in[28];
  const float* bn2_m   = (const float*)d_in[29];
  const float* bn2_v   = (const float*)d_in[30];

  float* ws = (float*)d_ws;
  float* out_b  = ws; ws += 64 * 64 * HW;
  float* off3b  = ws; ws += 56 * 18 * HW;
  float* off5b  = ws; ws += 56 * 50 * HW;
  float* dsum   = ws; ws += PLANE;
  float* pext   = ws; ws += PLANE;
  float* Rm     = ws; ws += 64 * 64 * 9;
  float* gacc   = ws; ws += 64 * 64;
  float* multb  = ws; ws += 64 * 256;
  float* bias1  = ws; ws += 64;
  float* wtT    = ws; ws += 192 * 9 * 64;
  float* AtBt   = ws; ws += 128;
  float* B3     = ws; ws += 64;
  float* gwT    = ws; ws += 64 * 256;
  float* Bg     = ws; ws += 256;
  __hip_bfloat16* wdB  = (__hip_bfloat16*)ws; ws += 16384;   // 32768 bf16
  __hip_bfloat16* wBs3 = (__hip_bfloat16*)ws; ws += 9216;    // 18432 bf16
  __hip_bfloat16* wBs5 = (__hip_bfloat16*)ws; ws += 51200;   // 102400 bf16
  __hip_bfloat16* wBd  = (__hip_bfloat16*)ws; ws += 69632;   // 139264 bf16
  __hip_bfloat16* c1B  = (__hip_bfloat16*)ws; ws += 2048;    // 4096 bf16
  __hip_bfloat16* xTbP = (__hip_bfloat16*)ws; ws += 56 * PADPX * 64 / 2;

  k_prep<<<256, 256, 0, stream>>>(
      w_down, b_down, bn1_g, bn1_b, bn1_m, bn1_v,
      tconv_w, tconv_b, bnt_g, bnt_b, bnt_m, bnt_v,
      off3_w, def3_w, off5_w, def5_w,
      conv1_w, conv1_b, bn3_g, bn3_b, bn3_m, bn3_v,
      conv_w, conv_b, bn2_g, bn2_b, bn2_m, bn2_v,
      wdB, bias1, wtT, AtBt, wBs3, wBs5, wBd, c1B,
      B3, gwT, Bg, gacc);
  k_zerohalo<<<420, 256, 0, stream>>>((float4*)xTbP);

  k_down<<<784, 256, 0, stream>>>(x, wdB, bias1, out_b, xTbP);
  k_rsum<<<1024, 256, 0, stream>>>(out_b, Rm);
  k_tmean<<<8, 256, 0, stream>>>(Rm, wtT, AtBt, gacc);
  // 686 blocks of 64 px each (43904 = 686*64 exact)
  k_offconv_mfma<3, 1, 18, 2><<<686, 256, 0, stream>>>(xTbP, wBs3, off3_b, off3b);
  k_offconv_mfma<5, 2, 50, 4><<<686, 256, 0, stream>>>(xTbP, wBs5, off5_b, off5b);
  // 7 parts x 56 frames x 2 c-halves, 7 waves/block, half-frame in LDS
  k_deform_mfma<<<dim3(7, 56, 2), 448, 0, stream>>>(xTbP, off3b, off5b, wBd,
                                                    dsum, pext);
  k_davg_diff<<<686, 256, 0, stream>>>(out_b, c1B, B3, dsum, pext, gacc);
  k_gate<<<64, 256, 0, stream>>>(gacc, gwT, Bg, multb);
  k_apply<<<12544, 256, 0, stream>>>(x, multb, (float*)d_out);
}

// Round 8
// 333.322 us; speedup vs baseline: 1.7770x; 1.0398x over previous
//
#include <hip/hip_runtime.h>
#include <hip/hip_bf16.h>

#define HW 784
#define WD 28
#define NPX (56 * 784)         // 43904 deform/offconv pixels
#define PLANE (56 * 64 * 784)  // 2,809,856 floats: one full plane
#define PADPX 1024             // 32x32 padded spatial (halo 2)

using short8 = __attribute__((ext_vector_type(8))) short;
using f32x4  = __attribute__((ext_vector_type(4))) float;

__device__ __forceinline__ float b2f(short s)
{
  return __uint_as_float(((unsigned)(unsigned short)s) << 16);
}

// ---------------------------------------------------------------------------
// Prep: fold BN into weight layouts; MFMA-fragment-order bf16 weights for
// offset convs (wBs), fused deform (wBd), down conv (wdB, hi/lo split) and
// davg 1x1 conv (c1B). Zeroes gacc and the xTbP halo (fused k_zerohalo).
// Frag layout: B[k=chunk*32+(lane>>4)*8+j][oc=nt*16+(lane&15)].
// ---------------------------------------------------------------------------
__global__ void k_prep(
    const float* __restrict__ w_down, const float* __restrict__ b_down,
    const float* __restrict__ bn1_g, const float* __restrict__ bn1_b,
    const float* __restrict__ bn1_m, const float* __restrict__ bn1_v,
    const float* __restrict__ tconv_w, const float* __restrict__ tconv_b,
    const float* __restrict__ bnt_g, const float* __restrict__ bnt_b,
    const float* __restrict__ bnt_m, const float* __restrict__ bnt_v,
    const float* __restrict__ off3_w, const float* __restrict__ def3_w,
    const float* __restrict__ off5_w, const float* __restrict__ def5_w,
    const float* __restrict__ conv1_w, const float* __restrict__ conv1_b,
    const float* __restrict__ bn3_g, const float* __restrict__ bn3_b,
    const float* __restrict__ bn3_m, const float* __restrict__ bn3_v,
    const float* __restrict__ conv_w, const float* __restrict__ conv_b,
    const float* __restrict__ bn2_g, const float* __restrict__ bn2_b,
    const float* __restrict__ bn2_m, const float* __restrict__ bn2_v,
    __hip_bfloat16* __restrict__ wdB, float* __restrict__ bias1,
    float* __restrict__ wtT, float* __restrict__ AtBt,
    __hip_bfloat16* __restrict__ wBs3, __hip_bfloat16* __restrict__ wBs5,
    __hip_bfloat16* __restrict__ wBd, __hip_bfloat16* __restrict__ c1B,
    float* __restrict__ B3,
    float* __restrict__ gwT, float* __restrict__ Bg,
    float* __restrict__ gacc, float4* __restrict__ xTbP4)
{
  const int tid = blockIdx.x * blockDim.x + threadIdx.x;
  const int nth = gridDim.x * blockDim.x;
  // xTbP halo zero: 56 frames x 240 halo slots x 8 float4
  for (int i = tid; i < 107520; i += nth) {
    const int n = i / 1920, rem = i % 1920;
    const int sl = rem >> 3, q = rem & 7;
    int row, col;
    if (sl < 128) {
      int r = sl >> 5;
      row = (r & 1) + ((r >> 1) * 30);
      col = sl & 31;
    } else {
      int t2 = sl - 128;
      row = 2 + (t2 >> 2);
      int qq = t2 & 3;
      col = (qq & 1) + ((qq >> 1) * 30);
    }
    xTbP4[((size_t)n * 1024 + row * 32 + col) * 8 + q] =
        make_float4(0.f, 0.f, 0.f, 0.f);
  }
  for (int i = tid; i < 64 * 64; i += nth) gacc[i] = 0.f;
  // down-conv MFMA B-frags, hi/lo split: chunks 0-7 = hi(w), 8-15 = lo(w)
  for (int i = tid; i < 16 * 4 * 512; i += nth) {
    int j = i & 7; int lane = (i >> 3) & 63;
    int rest = i >> 9; int nt = rest & 3; int ch = rest >> 2;
    int c = (ch & 7) * 32 + ((lane >> 4) << 3) + j;
    int oc = nt * 16 + (lane & 15);
    float s = bn1_g[oc] / sqrtf(bn1_v[oc] + 1e-5f);
    float wv = w_down[oc * 256 + c] * s;
    __hip_bfloat16 h = __float2bfloat16(wv);
    float hi = b2f(*(short*)&h);
    wdB[i] = (ch < 8) ? h : __float2bfloat16(wv - hi);
  }
  for (int i = tid; i < 64; i += nth) {
    float s = bn1_g[i] / sqrtf(bn1_v[i] + 1e-5f);
    bias1[i] = (b_down[i] - bn1_m[i]) * s + bn1_b[i];
  }
  for (int i = tid; i < 192 * 9 * 64; i += nth) {
    int cc = i / (9 * 64); int tap = (i / 64) % 9; int o = i & 63;
    int dt = cc >> 6, c = cc & 63;
    wtT[i] = tconv_w[o * 1728 + c * 27 + dt * 9 + tap];
  }
  for (int i = tid; i < 64; i += nth) {
    float s = bnt_g[i] / sqrtf(bnt_v[i] + 1e-5f);
    AtBt[i] = s * 0.125f;
    AtBt[64 + i] = (tconv_b[i] - bnt_m[i]) * s + bnt_b[i];
  }
  // off3 MFMA B-frags: K2=9, NT=2 (ocpad 32)
  for (int i = tid; i < 9 * 2 * 2 * 512; i += nth) {
    int j = i & 7; int lane = (i >> 3) & 63;
    int rest = i >> 9; int nt = rest % 2; rest /= 2;
    int chunk = rest & 1; int tap = rest >> 1;
    int c = chunk * 32 + ((lane >> 4) << 3) + j;
    int oc = nt * 16 + (lane & 15);
    float v = (oc < 18) ? off3_w[oc * 576 + c * 9 + tap] : 0.f;
    wBs3[i] = __float2bfloat16(v);
  }
  // off5 MFMA B-frags: K2=25, NT=4 (ocpad 64)
  for (int i = tid; i < 25 * 2 * 4 * 512; i += nth) {
    int j = i & 7; int lane = (i >> 3) & 63;
    int rest = i >> 9; int nt = rest % 4; rest /= 4;
    int chunk = rest & 1; int tap = rest >> 1;
    int c = chunk * 32 + ((lane >> 4) << 3) + j;
    int oc = nt * 16 + (lane & 15);
    float v = (oc < 50) ? off5_w[oc * 1600 + c * 25 + tap] : 0.f;
    wBs5[i] = __float2bfloat16(v);
  }
  // fused deform B-frags: 34 taps (0..8 def3, 9..33 def5), NT=4
  for (int i = tid; i < 34 * 2 * 4 * 512; i += nth) {
    int j = i & 7; int lane = (i >> 3) & 63;
    int rest = i >> 9; int nt = rest & 3; rest >>= 2;
    int chunk = rest & 1; int tap = rest >> 1;
    int c = chunk * 32 + ((lane >> 4) << 3) + j;
    int oc = nt * 16 + (lane & 15);
    float v = (tap < 9) ? def3_w[oc * 576 + c * 9 + tap]
                        : def5_w[oc * 1600 + c * 25 + (tap - 9)];
    wBd[i] = __float2bfloat16(v);
  }
  // davg 1x1 conv MFMA B-frags: K=64 (2 chunks), NT=4, BN folded
  for (int i = tid; i < 2 * 4 * 512; i += nth) {
    int j = i & 7; int lane = (i >> 3) & 63;
    int rest = i >> 9; int nt = rest & 3; int chunk = rest >> 2;
    int c = chunk * 32 + ((lane >> 4) << 3) + j;
    int oc = nt * 16 + (lane & 15);
    float s = bn3_g[oc] / sqrtf(bn3_v[oc] + 1e-5f);
    c1B[i] = __float2bfloat16(conv1_w[oc * 64 + c] * s);
  }
  for (int i = tid; i < 64; i += nth) {
    float s = bn3_g[i] / sqrtf(bn3_v[i] + 1e-5f);
    B3[i] = (conv1_b[i] - bn3_m[i]) * s + bn3_b[i];
  }
  for (int i = tid; i < 64 * 256; i += nth) {
    int c = i >> 8, co = i & 255;
    float s = bn2_g[co] / sqrtf(bn2_v[co] + 1e-5f);
    gwT[i] = conv_w[co * 64 + c] * s;
  }
  for (int i = tid; i < 256; i += nth) {
    float s = bn2_g[i] / sqrtf(bn2_v[i] + 1e-5f);
    Bg[i] = (conv_b[i] - bn2_m[i]) * s + bn2_b[i];
  }
}

// ---------------------------------------------------------------------------
// 1x1 down conv 256->64 as bf16 MFMA implicit GEMM with hi/lo split
// precision. Epilogue: f32 out_b + padded bf16 xTbP (fused xpose).
// ---------------------------------------------------------------------------
__global__ __launch_bounds__(256) void k_down(
    const float* __restrict__ x, const __hip_bfloat16* __restrict__ wdB,
    const float* __restrict__ bias1, float* __restrict__ out,
    __hip_bfloat16* __restrict__ xTbP)
{
  __shared__ float ct[64 * 65];
  const int tid = threadIdx.x;
  const int w = tid >> 6, lane = tid & 63;
  const int quad = lane >> 4, mrow = lane & 15;
  const int gpx = blockIdx.x * 64 + w * 16 + mrow;  // tiles never cross frames
  const int f = gpx / HW, px = gpx % HW;
  const float* xp = x + (size_t)f * 256 * HW + px;
  f32x4 acc[4];
#pragma unroll
  for (int nt = 0; nt < 4; nt++) acc[nt] = (f32x4){0.f, 0.f, 0.f, 0.f};

#pragma unroll
  for (int ch = 0; ch < 8; ch++) {
    short8 aH, aL;
#pragma unroll
    for (int j = 0; j < 8; j++) {
      float xv = xp[(ch * 32 + quad * 8 + j) * HW];
      __hip_bfloat16 h = __float2bfloat16(xv);
      aH[j] = *(short*)&h;
      __hip_bfloat16 l = __float2bfloat16(xv - b2f(aH[j]));
      aL[j] = *(short*)&l;
    }
    const short* bwH = (const short*)wdB + (size_t)(ch * 4) * 512 + lane * 8;
    const short* bwL = bwH + 16384;          // chunks 8..15 = lo(w)
#pragma unroll
    for (int nt = 0; nt < 4; nt++) {
      short8 bH = *(const short8*)(bwH + nt * 512);
      short8 bL = *(const short8*)(bwL + nt * 512);
      acc[nt] = __builtin_amdgcn_mfma_f32_16x16x32_bf16(aH, bH, acc[nt], 0, 0, 0);
      acc[nt] = __builtin_amdgcn_mfma_f32_16x16x32_bf16(aL, bH, acc[nt], 0, 0, 0);
      acc[nt] = __builtin_amdgcn_mfma_f32_16x16x32_bf16(aH, bL, acc[nt], 0, 0, 0);
    }
  }
  // C/D frag: col(oc) = lane&15, row(px) = quad*4 + reg
#pragma unroll
  for (int nt = 0; nt < 4; nt++) {
    int oc_l = nt * 16 + mrow;
#pragma unroll
    for (int reg = 0; reg < 4; reg++)
      ct[oc_l * 65 + w * 16 + quad * 4 + reg] = acc[nt][reg];
  }
  __syncthreads();
  for (int i = tid; i < 4096; i += 256) {        // out_b: [f][oc][px]
    int oc = i >> 6, p2 = i & 63;
    int g2 = blockIdx.x * 64 + p2;
    int f2 = g2 / HW, px2 = g2 % HW;
    out[((size_t)f2 * 64 + oc) * HW + px2] = ct[oc * 65 + p2] + bias1[oc];
  }
  for (int i = tid; i < 4096; i += 256) {        // xTbP: post frames only
    int p2 = i >> 6, oc = i & 63;
    int g2 = blockIdx.x * 64 + p2;
    int f2 = g2 / HW, px2 = g2 % HW;
    if (f2 & 7) {
      int n = (f2 >> 3) * 7 + (f2 & 7) - 1;
      int py = px2 / WD, pxc = px2 % WD;
      __hip_bfloat16 q = __float2bfloat16(ct[oc * 65 + p2] + bias1[oc]);
      ((short*)xTbP)[((size_t)n * PADPX + (py + 2) * 32 + (pxc + 2)) * 64 + oc] =
          *(short*)&q;
    }
  }
}

// ---------------------------------------------------------------------------
// Rectangle sums per (frame, channel) of out_b: 9 border classes. These are
// sum_px of the 3x3 conv's masked shifted inputs; mean(tconv) is a linear
// contraction of them (k_tmean).
// ---------------------------------------------------------------------------
__global__ __launch_bounds__(256) void k_rsum(
    const float* __restrict__ out_b, float* __restrict__ Rm)
{
  const int w = threadIdx.x >> 6, lane = threadIdx.x & 63;
  const int idx = blockIdx.x * 4 + w;        // (f,c): 4096 total
  const float* p = out_b + (size_t)idx * HW;
  float a[9];
#pragma unroll
  for (int k = 0; k < 9; k++) a[k] = 0.f;
  for (int i = lane; i < HW; i += 64) {
    float v = p[i];
    int row = i / WD, col = i % WD;
    float mr0 = (row < WD - 1) ? 1.f : 0.f, mr2 = (row > 0) ? 1.f : 0.f;
    float mc0 = (col < WD - 1) ? 1.f : 0.f, mc2 = (col > 0) ? 1.f : 0.f;
    float v0 = v * mc0, v2 = v * mc2;
    a[0] += v0 * mr0; a[1] += v * mr0; a[2] += v2 * mr0;
    a[3] += v0;       a[4] += v;       a[5] += v2;
    a[6] += v0 * mr2; a[7] += v * mr2; a[8] += v2 * mr2;
  }
#pragma unroll
  for (int k = 0; k < 9; k++) {
#pragma unroll
    for (int o = 32; o > 0; o >>= 1) a[k] += __shfl_down(a[k], o, 64);
  }
  if (lane == 0) {
#pragma unroll
    for (int k = 0; k < 9; k++) Rm[(size_t)idx * 9 + k] = a[k];
  }
}

// ---------------------------------------------------------------------------
// t_out spatial SUM per (b, oc) from rect sums -> gacc[b*8+7].
// ---------------------------------------------------------------------------
__global__ __launch_bounds__(256) void k_tmean(
    const float* __restrict__ Rm, const float* __restrict__ wtT,
    const float* __restrict__ AtBt, float* __restrict__ gacc)
{
  __shared__ float U[3 * 576];
  __shared__ float ps[4][64];
  const int b = blockIdx.x, tid = threadIdx.x;
  for (int i = tid; i < 576; i += 256) {
    float s = 0.f;
#pragma unroll
    for (int t = 0; t < 8; t++) s += Rm[(size_t)(b * 8 + t) * 576 + i];
    U[0 * 576 + i] = s - Rm[(size_t)(b * 8 + 7) * 576 + i];
    U[1 * 576 + i] = s;
    U[2 * 576 + i] = s - Rm[(size_t)(b * 8 + 0) * 576 + i];
  }
  __syncthreads();
  const int oc = tid & 63, part = tid >> 6;
  float acc = 0.f;
  for (int dt = 0; dt < 3; dt++)
    for (int cL = 0; cL < 16; cL++) {
      int cc = dt * 64 + part * 16 + cL;
      const float* wr = wtT + (size_t)cc * 9 * 64 + oc;
      const float* ur = U + dt * 576 + (part * 16 + cL) * 9;
#pragma unroll
      for (int t = 0; t < 9; t++) acc += wr[t * 64] * ur[t];
    }
  ps[part][oc] = acc;
  __syncthreads();
  if (tid < 64) {
    float tot = ps[0][tid] + ps[1][tid] + ps[2][tid] + ps[3][tid];
    gacc[(b * 8 + 7) * 64 + tid] = AtBt[tid] * tot + 784.f * AtBt[64 + tid];
  }
}

// ---------------------------------------------------------------------------
// FUSED offset convs (3x3 pad1 + 5x5 pad2) as implicit-GEMM bf16 MFMA.
// The 3x3 window is exactly the inner 3x3 of the 5x5 (sp3 == sp5 for
// ty,tx in [1,3]), so ONE pass over the A-tiles serves both: per 5x5 tap
// 8 off5 MFMAs; on the 9 inner taps additionally 4 off3 MFMAs. B-frags
// from global (L1/L2-hot), no staging barriers in the main loop.
// ---------------------------------------------------------------------------
__global__ __launch_bounds__(256) void k_offconv(
    const __hip_bfloat16* __restrict__ xTbP,
    const __hip_bfloat16* __restrict__ wBs3,
    const __hip_bfloat16* __restrict__ wBs5,
    const float* __restrict__ bias3, const float* __restrict__ bias5,
    float* __restrict__ off3b, float* __restrict__ off5b)
{
  __shared__ float ct[64 * 65];
  const int tid = threadIdx.x;
  const int w = tid >> 6, lane = tid & 63;
  const int quad = lane >> 4, mrow = lane & 15;
  const int gpx = blockIdx.x * 64 + w * 16 + mrow;   // A-row pixel
  const int n = gpx / HW, px = gpx % HW;
  const int y = px / WD, x = px % WD;
  const short* xb = (const short*)xTbP + ((size_t)n * PADPX) * 64;
  f32x4 acc5[4], acc3[2];
#pragma unroll
  for (int nt = 0; nt < 4; nt++) acc5[nt] = (f32x4){0.f, 0.f, 0.f, 0.f};
#pragma unroll
  for (int nt = 0; nt < 2; nt++) acc3[nt] = (f32x4){0.f, 0.f, 0.f, 0.f};

  for (int tap = 0; tap < 25; tap++) {
    const int ty = tap / 5, tx = tap % 5;
    const short* bw5 = (const short*)wBs5 + (size_t)tap * 4096 + lane * 8;
    short8 bf5[8];
#pragma unroll
    for (int q = 0; q < 8; q++) bf5[q] = *(const short8*)(bw5 + q * 512);
    int sp = (y + ty) * 32 + (x + tx);
    const short* ap = xb + sp * 64 + quad * 8;
    short8 a0 = *(const short8*)(ap);
    short8 a1 = *(const short8*)(ap + 32);
#pragma unroll
    for (int nt = 0; nt < 4; nt++)
      acc5[nt] = __builtin_amdgcn_mfma_f32_16x16x32_bf16(a0, bf5[nt], acc5[nt], 0, 0, 0);
#pragma unroll
    for (int nt = 0; nt < 4; nt++)
      acc5[nt] = __builtin_amdgcn_mfma_f32_16x16x32_bf16(a1, bf5[4 + nt], acc5[nt], 0, 0, 0);
    if (ty >= 1 && ty <= 3 && tx >= 1 && tx <= 3) {
      const int tap3 = (ty - 1) * 3 + (tx - 1);
      const short* bw3 = (const short*)wBs3 + (size_t)tap3 * 2048 + lane * 8;
      short8 bf3[4];
#pragma unroll
      for (int q = 0; q < 4; q++) bf3[q] = *(const short8*)(bw3 + q * 512);
#pragma unroll
      for (int nt = 0; nt < 2; nt++)
        acc3[nt] = __builtin_amdgcn_mfma_f32_16x16x32_bf16(a0, bf3[nt], acc3[nt], 0, 0, 0);
#pragma unroll
      for (int nt = 0; nt < 2; nt++)
        acc3[nt] = __builtin_amdgcn_mfma_f32_16x16x32_bf16(a1, bf3[2 + nt], acc3[nt], 0, 0, 0);
    }
  }
  // C/D frag: col(oc) = lane&15, row(px) = quad*4 + reg
#pragma unroll
  for (int nt = 0; nt < 4; nt++) {
    int oc_l = nt * 16 + mrow;
#pragma unroll
    for (int reg = 0; reg < 4; reg++)
      ct[oc_l * 65 + w * 16 + quad * 4 + reg] = acc5[nt][reg];
  }
  __syncthreads();
  for (int i = tid; i < 50 * 64; i += 256) {
    int oc = i >> 6, p2 = i & 63;
    int g2 = blockIdx.x * 64 + p2;
    int n2 = g2 / HW, px2 = g2 % HW;
    off5b[((size_t)n2 * 50 + oc) * HW + px2] = ct[oc * 65 + p2] + bias5[oc];
  }
  __syncthreads();
#pragma unroll
  for (int nt = 0; nt < 2; nt++) {
    int oc_l = nt * 16 + mrow;
#pragma unroll
    for (int reg = 0; reg < 4; reg++)
      ct[oc_l * 65 + w * 16 + quad * 4 + reg] = acc3[nt][reg];
  }
  __syncthreads();
  for (int i = tid; i < 18 * 64; i += 256) {
    int oc = i >> 6, p2 = i & 63;
    int g2 = blockIdx.x * 64 + p2;
    int n2 = g2 / HW, px2 = g2 % HW;
    off3b[((size_t)n2 * 18 + oc) * HW + px2] = ct[oc * 65 + p2] + bias3[oc];
  }
}

// ---------------------------------------------------------------------------
// FUSED deformable conv (def3 + def5): LDS half-frame gather + bf16 MFMA,
// c-split x2 (R4 layout, slot = s^(px&3)). Bilinear weights factored as
// wy*wx products (-4 VALU/tap vs R6).
// ---------------------------------------------------------------------------
__global__ __launch_bounds__(448, 6) void k_deform_mfma(
    const __hip_bfloat16* __restrict__ xTbP,
    const float* __restrict__ off3b, const float* __restrict__ off5b,
    const __hip_bfloat16* __restrict__ wBd,
    float* __restrict__ dsum, float* __restrict__ pext)
{
  __shared__ __align__(16) short Fr[784 * 32];   // swizzled bf16 half-frame
  const int tid = threadIdx.x;
  const int w = tid >> 6, lane = tid & 63;
  const int quad = lane >> 4, mrow = lane & 15;
  const int part = blockIdx.x, n = blockIdx.y, csel = blockIdx.z;

  // stage half-frame (channels csel*32..+32): slot s of row px at s^(px&3)
  {
    const short* xb = (const short*)xTbP + (size_t)n * PADPX * 64;
    for (int idx = tid; idx < 784 * 4; idx += 448) {
      int px = idx >> 2, s = idx & 3;
      int py = px / WD, pxc = px % WD;
      float4 v = ((const float4*)(xb + ((py + 2) * 32 + (pxc + 2)) * 64))[csel * 4 + s];
      ((float4*)Fr)[px * 4 + (s ^ (px & 3))] = v;
    }
  }
  __syncthreads();

  const char* F = (const char*)Fr;
  const int px0 = (part * 7 + w) * 16;
  const int pxg = px0 + mrow;
  const int y_g = pxg / WD, x_g = pxg % WD;
  const float* ob3 = off3b + (size_t)n * 18 * HW + pxg;
  const float* ob5 = off5b + (size_t)n * 50 * HW + pxg;

  f32x4 acc[4];
#pragma unroll
  for (int nt = 0; nt < 4; nt++) acc[nt] = (f32x4){0.f, 0.f, 0.f, 0.f};

#pragma unroll 2
  for (int tap = 0; tap < 34; tap++) {
    // B frags for this tap & c-half (L2-resident)
    const short* bw = (const short*)wBd +
        ((size_t)(tap * 2 + csel) * 4) * 512 + lane * 8;
    short8 bfrag[4];
#pragma unroll
    for (int nt = 0; nt < 4; nt++) bfrag[nt] = *(const short8*)(bw + nt * 512);

    int kk, ty, tx, PADl; const float* obp;
    if (tap < 9) { kk = tap; ty = kk / 3; tx = kk % 3; PADl = 1; obp = ob3; }
    else { kk = tap - 9; ty = kk / 5; tx = kk % 5; PADl = 2; obp = ob5; }
    float offy = obp[(2 * kk) * HW];
    float offx = obp[(2 * kk + 1) * HW];
    float py = (float)(y_g + ty - PADl) + offy;
    float pxx = (float)(x_g + tx - PADl) + offx;
    float fy = floorf(py), fx = floorf(pxx);
    int y0 = (int)fy, x0 = (int)fx;
    float ly = py - fy, lx = pxx - fx;
    int y1 = y0 + 1, x1 = x0 + 1;
    float vy0 = (y0 >= 0 && y0 < WD) ? 1.f : 0.f;
    float vy1 = (y1 >= 0 && y1 < WD) ? 1.f : 0.f;
    float vx0 = (x0 >= 0 && x0 < WD) ? 1.f : 0.f;
    float vx1 = (x1 >= 0 && x1 < WD) ? 1.f : 0.f;
    float wy0 = (1.f - ly) * vy0, wy1 = ly * vy1;
    float wx0 = (1.f - lx) * vx0, wx1 = lx * vx1;
    float w00 = wy0 * wx0, w01 = wy0 * wx1;
    float w10 = wy1 * wx0, w11 = wy1 * wx1;
    int cy0 = min(max(y0, 0), WD - 1), cy1 = min(max(y1, 0), WD - 1);
    int cx0 = min(max(x0, 0), WD - 1), cx1 = min(max(x1, 0), WD - 1);
    int r00 = cy0 * WD + cx0, r01 = cy0 * WD + cx1;
    int r10 = cy1 * WD + cx0, r11 = cy1 * WD + cx1;
    short8 c00 = *(const short8*)(F + r00 * 64 + ((quad ^ (r00 & 3)) << 4));
    short8 c01 = *(const short8*)(F + r01 * 64 + ((quad ^ (r01 & 3)) << 4));
    short8 c10 = *(const short8*)(F + r10 * 64 + ((quad ^ (r10 & 3)) << 4));
    short8 c11 = *(const short8*)(F + r11 * 64 + ((quad ^ (r11 & 3)) << 4));
    short8 a0;
#pragma unroll
    for (int j = 0; j < 8; j++) {
      float g0 = b2f(c00[j]) * w00 + b2f(c01[j]) * w01 +
                 b2f(c10[j]) * w10 + b2f(c11[j]) * w11;
      __hip_bfloat16 q0 = __float2bfloat16(g0);
      a0[j] = *(short*)&q0;
    }
#pragma unroll
    for (int nt = 0; nt < 4; nt++)
      acc[nt] = __builtin_amdgcn_mfma_f32_16x16x32_bf16(a0, bfrag[nt], acc[nt], 0, 0, 0);
  }

  // C/D frag: col(oc) = lane&15 (+nt*16), row(px) = quad*4 + reg
  float* P = csel ? pext : dsum;
#pragma unroll
  for (int nt = 0; nt < 4; nt++)
    *(f32x4*)(P + ((size_t)n * 64 + nt * 16 + mrow) * HW + px0 + quad * 4) =
        acc[nt];
}

// ---------------------------------------------------------------------------
// maxpool 3x3 + 1x1 conv (MFMA) + diff + in-kernel spatial-sum reduction
// into gacc (diff is consumed only by the gate's mean; never written back).
// ---------------------------------------------------------------------------
__global__ __launch_bounds__(256) void k_davg_diff(
    const float* __restrict__ frames, const __hip_bfloat16* __restrict__ c1B,
    const float* __restrict__ B3, const float* __restrict__ dsum,
    const float* __restrict__ pext, float* __restrict__ gacc)
{
  const int tid = threadIdx.x;
  const int w = tid >> 6, lane = tid & 63;
  const int quad = lane >> 4, mrow = lane & 15;
  const int gpx = blockIdx.x * 64 + w * 16 + mrow;  // wave tiles don't cross n
  const int n = gpx / HW, px = gpx % HW;
  const int fpost = (n / 7) * 8 + (n % 7) + 1;
  const int fpre = fpost - 1;
  const int y = px / WD, x = px % WD;
  int lin[9]; bool okm[9];
#pragma unroll
  for (int t2 = 0; t2 < 9; t2++) {
    int iy = y + t2 / 3 - 1, ix = x + t2 % 3 - 1;
    okm[t2] = iy >= 0 && iy < WD && ix >= 0 && ix < WD;
    lin[t2] = min(max(iy, 0), WD - 1) * WD + min(max(ix, 0), WD - 1);
  }
  const float* sb = frames + (size_t)fpost * 64 * HW;
  f32x4 acc[4];
#pragma unroll
  for (int nt = 0; nt < 4; nt++) acc[nt] = (f32x4){0.f, 0.f, 0.f, 0.f};

#pragma unroll
  for (int chunk = 0; chunk < 2; chunk++) {
    short8 aM;
#pragma unroll
    for (int j = 0; j < 8; j++) {
      const float* p = sb + (chunk * 32 + quad * 8 + j) * HW;
      float m = -1e30f;
#pragma unroll
      for (int t2 = 0; t2 < 9; t2++) {
        float v = okm[t2] ? p[lin[t2]] : -1e30f;
        m = fmaxf(m, v);
      }
      __hip_bfloat16 h = __float2bfloat16(m);
      aM[j] = *(short*)&h;
    }
    const short* bw = (const short*)c1B + (size_t)(chunk * 4) * 512 + lane * 8;
#pragma unroll
    for (int nt = 0; nt < 4; nt++) {
      short8 bf = *(const short8*)(bw + nt * 512);
      acc[nt] = __builtin_amdgcn_mfma_f32_16x16x32_bf16(aM, bf, acc[nt], 0, 0, 0);
    }
  }
  // D-frag row(px) = quad*4+reg, col(oc) = nt*16+mrow. Reduce |diff| over px.
  const int pxb = (px - mrow) + quad * 4;
  const int gi = ((n / 7) * 8 + (n % 7)) * 64;
#pragma unroll
  for (int nt = 0; nt < 4; nt++) {
    int oc = nt * 16 + mrow;
    size_t base = ((size_t)n * 64 + oc) * HW + pxb;
    f32x4 ds = *(const f32x4*)(dsum + base);
    f32x4 pe = *(const f32x4*)(pext + base);
    f32x4 xp4 = *(const f32x4*)(frames + ((size_t)fpre * 64 + oc) * HW + pxb);
    float b3 = B3[oc];
    float s = 0.f;
#pragma unroll
    for (int r = 0; r < 4; r++)
      s += fabsf(ds[r] + pe[r] + acc[nt][r] + b3 - 3.f * xp4[r]);
    s += __shfl_xor(s, 16, 64);
    s += __shfl_xor(s, 32, 64);
    if (quad == 0) atomicAdd(&gacc[gi + oc], s);
  }
}

// ---------------------------------------------------------------------------
// Gate: 1x1 conv 64->256 + sigmoid; gacc holds spatial SUMS (scale 1/784).
// ---------------------------------------------------------------------------
__global__ __launch_bounds__(256) void k_gate(
    const float* __restrict__ gacc, const float* __restrict__ gwT,
    const float* __restrict__ Bg, float* __restrict__ mult)
{
  __shared__ float gm[64];
  const int nt = blockIdx.x, co = threadIdx.x;
  if (co < 64) gm[co] = gacc[nt * 64 + co] * (1.f / 784.f);
  __syncthreads();
  float a = 0.f;
#pragma unroll 8
  for (int c = 0; c < 64; c++) a += gm[c] * gwT[c * 256 + co];
  float pre = a + Bg[co];
  mult[nt * 256 + co] = 0.5f + 1.f / (1.f + expf(-pre));
}

// ---------------------------------------------------------------------------
// out = x * mult[nt,co]
// ---------------------------------------------------------------------------
__global__ void k_apply(const float* __restrict__ x,
                        const float* __restrict__ mult,
                        float* __restrict__ outp)
{
  const int i = blockIdx.x * 256 + threadIdx.x;
  const int plane = i / 196;
  const float m = mult[plane];
  float4 v = ((const float4*)x)[i];
  v.x *= m; v.y *= m; v.z *= m; v.w *= m;
  ((float4*)outp)[i] = v;
}

// ---------------------------------------------------------------------------
extern "C" void kernel_launch(void* const* d_in, const int* in_sizes, int n_in,
                              void* d_out, int out_size, void* d_ws, size_t ws_size,
                              hipStream_t stream)
{
  const float* x       = (const float*)d_in[0];
  const float* w_down  = (const float*)d_in[1];
  const float* b_down  = (const float*)d_in[2];
  const float* bn1_g   = (const float*)d_in[3];
  const float* bn1_b   = (const float*)d_in[4];
  const float* bn1_m   = (const float*)d_in[5];
  const float* bn1_v   = (const float*)d_in[6];
  const float* tconv_w = (const float*)d_in[7];
  const float* tconv_b = (const float*)d_in[8];
  const float* bnt_g   = (const float*)d_in[9];
  const float* bnt_b   = (const float*)d_in[10];
  const float* bnt_m   = (const float*)d_in[11];
  const float* bnt_v   = (const float*)d_in[12];
  const float* off3_w  = (const float*)d_in[13];
  const float* off3_b  = (const float*)d_in[14];
  const float* def3_w  = (const float*)d_in[15];
  const float* off5_w  = (const float*)d_in[16];
  const float* off5_b  = (const float*)d_in[17];
  const float* def5_w  = (const float*)d_in[18];
  const float* conv1_w = (const float*)d_in[19];
  const float* conv1_b = (const float*)d_in[20];
  const float* bn3_g   = (const float*)d_in[21];
  const float* bn3_b   = (const float*)d_in[22];
  const float* bn3_m   = (const float*)d_in[23];
  const float* bn3_v   = (const float*)d_in[24];
  const float* conv_w  = (const float*)d_in[25];
  const float* conv_b  = (const float*)d_in[26];
  const float* bn2_g   = (const float*)d_in[27];
  const float* bn2_b   = (const float*)d_in[28];
  const float* bn2_m   = (const float*)d_in[29];
  const float* bn2_v   = (const float*)d_in[30];

  float* ws = (float*)d_ws;
  float* out_b  = ws; ws += 64 * 64 * HW;
  float* off3b  = ws; ws += 56 * 18 * HW;
  float* off5b  = ws; ws += 56 * 50 * HW;
  float* dsum   = ws; ws += PLANE;
  float* pext   = ws; ws += PLANE;
  float* Rm     = ws; ws += 64 * 64 * 9;
  float* gacc   = ws; ws += 64 * 64;
  float* multb  = ws; ws += 64 * 256;
  float* bias1  = ws; ws += 64;
  float* wtT    = ws; ws += 192 * 9 * 64;
  float* AtBt   = ws; ws += 128;
  float* B3     = ws; ws += 64;
  float* gwT    = ws; ws += 64 * 256;
  float* Bg     = ws; ws += 256;
  __hip_bfloat16* wdB  = (__hip_bfloat16*)ws; ws += 16384;   // 32768 bf16
  __hip_bfloat16* wBs3 = (__hip_bfloat16*)ws; ws += 9216;    // 18432 bf16
  __hip_bfloat16* wBs5 = (__hip_bfloat16*)ws; ws += 51200;   // 102400 bf16
  __hip_bfloat16* wBd  = (__hip_bfloat16*)ws; ws += 69632;   // 139264 bf16
  __hip_bfloat16* c1B  = (__hip_bfloat16*)ws; ws += 2048;    // 4096 bf16
  __hip_bfloat16* xTbP = (__hip_bfloat16*)ws; ws += 56 * PADPX * 64 / 2;

  k_prep<<<1024, 256, 0, stream>>>(
      w_down, b_down, bn1_g, bn1_b, bn1_m, bn1_v,
      tconv_w, tconv_b, bnt_g, bnt_b, bnt_m, bnt_v,
      off3_w, def3_w, off5_w, def5_w,
      conv1_w, conv1_b, bn3_g, bn3_b, bn3_m, bn3_v,
      conv_w, conv_b, bn2_g, bn2_b, bn2_m, bn2_v,
      wdB, bias1, wtT, AtBt, wBs3, wBs5, wBd, c1B,
      B3, gwT, Bg, gacc, (float4*)xTbP);

  k_down<<<784, 256, 0, stream>>>(x, wdB, bias1, out_b, xTbP);
  k_rsum<<<1024, 256, 0, stream>>>(out_b, Rm);
  k_tmean<<<8, 256, 0, stream>>>(Rm, wtT, AtBt, gacc);
  // fused offset convs: 686 blocks of 64 px (43904 = 686*64 exact)
  k_offconv<<<686, 256, 0, stream>>>(xTbP, wBs3, wBs5, off3_b, off5_b,
                                     off3b, off5b);
  // 7 parts x 56 frames x 2 c-halves, 7 waves/block, half-frame in LDS
  k_deform_mfma<<<dim3(7, 56, 2), 448, 0, stream>>>(xTbP, off3b, off5b, wBd,
                                                    dsum, pext);
  k_davg_diff<<<686, 256, 0, stream>>>(out_b, c1B, B3, dsum, pext, gacc);
  k_gate<<<64, 256, 0, stream>>>(gacc, gwT, Bg, multb);
  k_apply<<<12544, 256, 0, stream>>>(x, multb, (float*)d_out);
}